// Round 1
// baseline (3298.265 us; speedup 1.0000x reference)
//
#include <hip/hip_runtime.h>
#include <math.h>

#define NLAYERS 6
#define HD 256
#define NS 32
#define NCLS 50
#define BB 16
#define LL 2048
#define TT 64
#define CC 32

// ---- static device workspaces (~161 MB total) ----
__device__ __attribute__((aligned(16))) float g_x [8388608];   // [B][L][H] residual stream
__device__ __attribute__((aligned(16))) float g_yb[8388608];   // [B][H][L] conv+gelu output
__device__ __attribute__((aligned(16))) float g_zS[16777216];  // z [B][H][L] | S_end/G [B][C][H][N][2]; overlaid by v [B*L][512]
__device__ __attribute__((aligned(16))) float g_Vt[6389760];   // [l][h][n][65][2] : w^t, t=0..64
__device__ __attribute__((aligned(16))) float g_Kt[98304];     // [l][h][64] kernel taps
__device__ __attribute__((aligned(16))) float g_E0[98304];     // [l][h][n][2] : C*dB
__device__ __attribute__((aligned(16))) float g_pp[65536];     // [B][16][H] pool partials

#define SEND_OFF 8388608

__device__ __forceinline__ float sigf(float x) { return 1.0f / (1.0f + __expf(-x)); }
__device__ __forceinline__ float geluf(float x) {
  float t = 0.7978845608028654f * (x + 0.044715f * x * x * x);
  float e = __expf(2.0f * t);
  float th = 1.0f - 2.0f / (e + 1.0f);   // tanh(t); saturates correctly at +/-inf
  return 0.5f * x * (1.0f + th);
}

// ---------- precompute: w, E0 = C*dB, and power table w^t ----------
__global__ void k_precomp(const float* __restrict__ log_dt,
                          const float* __restrict__ A_re, const float* __restrict__ A_im,
                          const float* __restrict__ B_re, const float* __restrict__ B_im,
                          const float* __restrict__ C_re, const float* __restrict__ C_im) {
  int id = blockIdx.x * 256 + threadIdx.x;      // over NLAYERS*HD*NS = 49152
  if (id >= NLAYERS * HD * NS) return;
  int h = (id / NS) % HD;
  int i = id / (NS * HD);
  float dt = expf(log_dt[i * HD + h]);
  float ar = A_re[id], ai = A_im[id];
  float dr = dt * ar, di = dt * ai;
  float er = expf(dr);
  float wr = er * cosf(di), wi = er * sinf(di); // w = exp(dt*A)
  float inv = 1.0f / (ar * ar + ai * ai);
  float mr = wr - 1.0f, mi = wi;                // exp(dtA) - 1
  float qr = (mr * ar + mi * ai) * inv;         // (exp(dtA)-1)/A
  float qi = (mi * ar - mr * ai) * inv;
  float br = B_re[id], bi = B_im[id];
  float dbr = br * qr - bi * qi, dbi = br * qi + bi * qr;   // dB
  float cr = C_re[id], ci = C_im[id];
  g_E0[id * 2 + 0] = cr * dbr - ci * dbi;       // E0 = C*dB
  g_E0[id * 2 + 1] = cr * dbi + ci * dbr;
  float pr = 1.0f, pi = 0.0f;
  long base = (long)id * 65;
  for (int t = 0; t <= 64; ++t) {
    g_Vt[(base + t) * 2 + 0] = pr;
    g_Vt[(base + t) * 2 + 1] = pi;
    float nr = pr * wr - pi * wi;
    pi = pr * wi + pi * wr;
    pr = nr;
  }
}

// K[h,t] = 2*Re(sum_n E0*w^t), t<64
__global__ void k_precompK() {
  int id = blockIdx.x * 256 + threadIdx.x;      // over NLAYERS*HD*64 = 98304
  if (id >= NLAYERS * HD * TT) return;
  int t = id % TT;
  int lh = id / TT;                              // i*HD + h
  float acc = 0.f;
  const float* e = g_E0 + (long)lh * NS * 2;
  const float* v = g_Vt + ((long)lh * NS * 65 + t) * 2;
  for (int n = 0; n < NS; ++n)
    acc += e[n * 2] * v[n * 130] - e[n * 2 + 1] * v[n * 130 + 1];
  g_Kt[id] = 2.0f * acc;
}

// ---------- fp32 tiled GEMM: 128x128 tile, 8x8 per thread ----------
// IN=true : C[32768,256] = A[32768,128](K-major) * W_in[128,256] + b  -> g_x
// IN=false: C[32768,512] = y^T[32768,256] (from g_yb [B][H][L]) * W_out[256,512] + b -> g_zS (v)
template<bool IN>
__global__ __launch_bounds__(256) void k_gemm(const float* __restrict__ Aext,
                                              const float* __restrict__ Bw,
                                              const float* __restrict__ bias) {
  constexpr int KD  = IN ? 128 : 256;
  constexpr int LDA = IN ? 128 : LL;
  constexpr int LDB = IN ? 256 : 512;
  constexpr int LDC = IN ? 256 : 512;
  __shared__ float As[16][128];
  __shared__ float Bs[16][128];
  const int tid = threadIdx.x;
  const int m0 = blockIdx.x * 128, n0 = blockIdx.y * 128;
  const float* Ab;
  float* Cm;
  if constexpr (IN) { Ab = Aext + (long)m0 * LDA; Cm = g_x; }
  else              { Ab = g_yb + (long)(m0 >> 11) * HD * LL + (m0 & 2047); Cm = g_zS; }
  const float* Bb = Bw + n0;
  const int tx = tid & 15, ty = tid >> 4;
  float acc[8][8];
  #pragma unroll
  for (int r = 0; r < 8; ++r)
    #pragma unroll
    for (int c = 0; c < 8; ++c) acc[r][c] = 0.f;
  for (int k0 = 0; k0 < KD; k0 += 16) {
    __syncthreads();
    if constexpr (IN) {
      #pragma unroll
      for (int j = 0; j < 2; ++j) {
        int idx = tid + j * 256;
        int m = idx & 127, kq = idx >> 7;
        float4 v = *(const float4*)(Ab + (long)m * LDA + k0 + kq * 4);
        As[kq * 4 + 0][m] = v.x; As[kq * 4 + 1][m] = v.y;
        As[kq * 4 + 2][m] = v.z; As[kq * 4 + 3][m] = v.w;
      }
    } else {
      #pragma unroll
      for (int j = 0; j < 2; ++j) {
        int idx = tid + j * 256;
        int k = idx >> 5, mq = idx & 31;
        *(float4*)&As[k][mq * 4] = *(const float4*)(Ab + (long)(k0 + k) * LDA + mq * 4);
      }
    }
    #pragma unroll
    for (int j = 0; j < 2; ++j) {
      int idx = tid + j * 256;
      int k = idx >> 5, nq = idx & 31;
      *(float4*)&Bs[k][nq * 4] = *(const float4*)(Bb + (long)(k0 + k) * LDB + nq * 4);
    }
    __syncthreads();
    #pragma unroll
    for (int kk = 0; kk < 16; ++kk) {
      float a[8], bq[8];
      *(float4*)&a[0]  = *(float4*)&As[kk][ty * 8];
      *(float4*)&a[4]  = *(float4*)&As[kk][ty * 8 + 4];
      *(float4*)&bq[0] = *(float4*)&Bs[kk][tx * 8];
      *(float4*)&bq[4] = *(float4*)&Bs[kk][tx * 8 + 4];
      #pragma unroll
      for (int r = 0; r < 8; ++r)
        #pragma unroll
        for (int c = 0; c < 8; ++c) acc[r][c] += a[r] * bq[c];
    }
  }
  #pragma unroll
  for (int r = 0; r < 8; ++r) {
    long m = m0 + ty * 8 + r;
    #pragma unroll
    for (int c4 = 0; c4 < 2; ++c4) {
      int n = n0 + tx * 8 + c4 * 4;
      float4 bv = *(const float4*)(bias + n);
      float4 o;
      o.x = acc[r][c4 * 4 + 0] + bv.x;
      o.y = acc[r][c4 * 4 + 1] + bv.y;
      o.z = acc[r][c4 * 4 + 2] + bv.z;
      o.w = acc[r][c4 * 4 + 3] + bv.w;
      *(float4*)(Cm + m * LDC + n) = o;
    }
  }
}

// ---------- LayerNorm over H, write transposed z[B][H][L] ----------
__global__ __launch_bounds__(256) void k_ln(const float* __restrict__ gam,
                                            const float* __restrict__ bet) {
  __shared__ float S[16][256];
  const int bid = blockIdx.x;                 // B*L/16 = 2048
  const int b = bid >> 7, l0 = (bid & 127) << 4;
  const int tid = threadIdx.x;
  const int w = tid >> 6, lane = tid & 63;
  float4 gv = *(const float4*)(gam + lane * 4);
  float4 bv = *(const float4*)(bet + lane * 4);
  for (int r = 0; r < 4; ++r) {
    int l = l0 + w * 4 + r;
    float4 v = *(const float4*)(g_x + ((long)b * LL + l) * HD + lane * 4);
    float s1 = v.x + v.y + v.z + v.w;
    float s2 = v.x * v.x + v.y * v.y + v.z * v.z + v.w * v.w;
    #pragma unroll
    for (int off = 32; off; off >>= 1) { s1 += __shfl_xor(s1, off); s2 += __shfl_xor(s2, off); }
    float mu = s1 * (1.0f / HD);
    float var = s2 * (1.0f / HD) - mu * mu;
    float rs = rsqrtf(var + 1e-5f);
    int rr = w * 4 + r;
    S[rr][lane * 4 + 0] = (v.x - mu) * rs * gv.x + bv.x;
    S[rr][lane * 4 + 1] = (v.y - mu) * rs * gv.y + bv.y;
    S[rr][lane * 4 + 2] = (v.z - mu) * rs * gv.z + bv.z;
    S[rr][lane * 4 + 3] = (v.w - mu) * rs * gv.w + bv.w;
  }
  __syncthreads();
  float o[16];
  #pragma unroll
  for (int r = 0; r < 16; ++r) o[r] = S[r][tid];
  float* zp = g_zS + ((long)b * HD + tid) * LL + l0;
  #pragma unroll
  for (int q = 0; q < 4; ++q)
    *(float4*)(zp + q * 4) = make_float4(o[q * 4], o[q * 4 + 1], o[q * 4 + 2], o[q * 4 + 3]);
}

// ---------- Phase A: chunk-end states S_end[b,c,h,n] = sum_t z[cT+t]*w^(T-1-t) ----------
__global__ __launch_bounds__(128) void k_phaseA(int layer) {
  __shared__ float2 Vs[2 * 32 * 65];   // [hh][n][j] = w^(63-j), pad 65 (2-way max)
  __shared__ float zs[2][64];
  const int h0 = blockIdx.x * 2;
  const int slice = blockIdx.y;        // 8 slices of 64 (b,c) pairs
  const int tid = threadIdx.x;
  {
    int p = tid >> 1, half = tid & 1;
    int sh = p >> 5, sn = p & 31;
    const float2* src = (const float2*)g_Vt + ((long)(layer * HD + h0 + sh) * NS + sn) * 65;
    float2* dst = Vs + (sh * 32 + sn) * 65 + half * 32;
    #pragma unroll
    for (int t = 0; t < 32; ++t) dst[t] = src[63 - (half * 32 + t)];
  }
  const int hh = tid >> 6, lane = tid & 63, tb = lane >> 5, n = lane & 31;
  const float2* vrow = Vs + (hh * 32 + n) * 65 + tb * 32;
  float* Send = g_zS + SEND_OFF;
  for (int j = 0; j < 64; ++j) {
    int bc = slice * 64 + j;
    int b = bc >> 5, c = bc & 31;
    __syncthreads();
    zs[hh][lane] = g_zS[((long)b * HD + h0 + hh) * LL + c * 64 + lane];
    __syncthreads();
    float sr = 0.f, si = 0.f;
    #pragma unroll
    for (int it = 0; it < 32; ++it) {
      float zv = zs[hh][tb * 32 + it];
      float2 v = vrow[it];
      sr += zv * v.x; si += zv * v.y;
    }
    sr += __shfl_xor(sr, 32);
    si += __shfl_xor(si, 32);
    if (tb == 0) {
      float2* d = (float2*)(Send + (((long)(b * CC + c) * HD + h0 + hh) * NS + n) * 2);
      *d = make_float2(sr, si);
    }
  }
}

// ---------- Phase B: combine chunks, G[c] = E0 .* S_prev[c] (in-place over S_end) ----------
__global__ void k_phaseB(int layer) {
  int id = blockIdx.x * 256 + threadIdx.x;     // B*H*N = 131072
  int n = id & 31, h = (id >> 5) & 255, b = id >> 13;
  long vb = ((long)(layer * HD + h) * NS + n) * 65;
  float wtr = g_Vt[(vb + 64) * 2], wti = g_Vt[(vb + 64) * 2 + 1];   // w^T
  long eb = ((long)(layer * HD + h) * NS + n) * 2;
  float e0r = g_E0[eb], e0i = g_E0[eb + 1];
  float sr = 0.f, si = 0.f;
  float* Send = g_zS + SEND_OFF;
  for (int c = 0; c < CC; ++c) {
    float* p = Send + (((long)(b * CC + c) * HD + h) * NS + n) * 2;
    float er = p[0], ei = p[1];
    p[0] = e0r * sr - e0i * si;                 // G = E0 * S_prev
    p[1] = e0r * si + e0i * sr;
    float nr = er + wtr * sr - wti * si;        // S_prev' = S_end + w^T * S_prev
    si      = ei + wtr * si + wti * sr;
    sr = nr;
  }
}

// ---------- Phase C: y = local 64-tap conv + correction + D*z, then GELU ----------
__global__ __launch_bounds__(128) void k_phaseC(int layer, const float* __restrict__ Dp) {
  __shared__ float2 Vc[2 * 64 * 33];   // [hh][t][n] = w^(t+1), n-pad 33 (2-way max)
  __shared__ float zsl[2][64];
  __shared__ float Ks[2][64];
  __shared__ float2 Gs[64];            // [hh][n]
  const int h0 = blockIdx.x * 2;
  const int slice = blockIdx.y;
  const int tid = threadIdx.x;
  const int hh = tid >> 6, t = tid & 63;
  {
    const float2* src = (const float2*)g_Vt + (long)(layer * HD + h0 + hh) * NS * 65 + (t + 1);
    float2* dst = Vc + (hh * 64 + t) * 33;
    #pragma unroll
    for (int n = 0; n < NS; ++n) dst[n] = src[n * 65];
    Ks[hh][t] = g_Kt[(long)(layer * HD + h0 + hh) * 64 + t];
  }
  const float Dv = Dp[h0 + hh];
  const float2* vrow = Vc + (hh * 64 + t) * 33;
  const float* Send = g_zS + SEND_OFF;
  for (int j = 0; j < 64; ++j) {
    int bc = slice * 64 + j;
    int b = bc >> 5, c = bc & 31;
    __syncthreads();
    zsl[hh][t] = g_zS[((long)b * HD + h0 + hh) * LL + c * 64 + t];
    ((float*)Gs)[tid] = Send[((long)(b * CC + c) * HD + h0) * NS * 2 + tid];
    __syncthreads();
    float ac = 0.f;                    // correction: 2*Re(sum_n G * w^(t+1))
    const float2* gp = Gs + hh * 32;
    #pragma unroll
    for (int n = 0; n < NS; ++n) {
      float2 v = vrow[n];
      float2 g = gp[n];
      ac += g.x * v.x - g.y * v.y;
    }
    float al = 0.f;                    // local causal conv within chunk
    #pragma unroll
    for (int m = 0; m < 64; ++m) {
      int idx = t - m;
      float kv = (idx >= 0) ? Ks[hh][m] : 0.f;
      float zv = zsl[hh][idx >= 0 ? idx : 0];
      al += kv * zv;
    }
    float yv = 2.0f * ac + al + Dv * zsl[hh][t];
    g_yb[((long)b * HD + h0 + hh) * LL + c * 64 + t] = geluf(yv);
  }
}

// ---------- GLU + residual: x += a*sigmoid(g) ----------
__global__ void k_glu() {
  long id = (long)blockIdx.x * 256 + threadIdx.x;   // B*L*H = 8388608
  long m = id >> 8;
  int h = (int)(id & 255);
  float a = g_zS[m * 512 + h];
  float g = g_zS[m * 512 + 256 + h];
  g_x[id] += a * sigf(g);
}

// ---------- final LN + partial pool ----------
__global__ __launch_bounds__(256) void k_lnpool(const float* __restrict__ gam,
                                                const float* __restrict__ bet) {
  __shared__ float red[4][256];
  const int bid = blockIdx.x;          // b*16 + s
  const int b = bid >> 4, s = bid & 15;
  const int tid = threadIdx.x, w = tid >> 6, lane = tid & 63;
  float4 gv = *(const float4*)(gam + lane * 4);
  float4 bv = *(const float4*)(bet + lane * 4);
  float a0 = 0, a1 = 0, a2 = 0, a3 = 0;
  for (int r = 0; r < 32; ++r) {
    int l = s * 128 + w * 32 + r;
    float4 v = *(const float4*)(g_x + ((long)b * LL + l) * HD + lane * 4);
    float s1 = v.x + v.y + v.z + v.w;
    float s2 = v.x * v.x + v.y * v.y + v.z * v.z + v.w * v.w;
    #pragma unroll
    for (int off = 32; off; off >>= 1) { s1 += __shfl_xor(s1, off); s2 += __shfl_xor(s2, off); }
    float mu = s1 * (1.0f / HD);
    float rs = rsqrtf(s2 * (1.0f / HD) - mu * mu + 1e-5f);
    a0 += (v.x - mu) * rs * gv.x + bv.x;
    a1 += (v.y - mu) * rs * gv.y + bv.y;
    a2 += (v.z - mu) * rs * gv.z + bv.z;
    a3 += (v.w - mu) * rs * gv.w + bv.w;
  }
  red[w][lane * 4 + 0] = a0; red[w][lane * 4 + 1] = a1;
  red[w][lane * 4 + 2] = a2; red[w][lane * 4 + 3] = a3;
  __syncthreads();
  g_pp[(long)bid * HD + tid] = red[0][tid] + red[1][tid] + red[2][tid] + red[3][tid];
}

// ---------- classifier ----------
__global__ __launch_bounds__(256) void k_cls(const float* __restrict__ Wc,
                                             const float* __restrict__ bc,
                                             float* __restrict__ out) {
  __shared__ float pl[256];
  const int b = blockIdx.x, tid = threadIdx.x;
  float p = 0.f;
  #pragma unroll
  for (int s = 0; s < 16; ++s) p += g_pp[((long)b * 16 + s) * HD + tid];
  pl[tid] = p * (1.0f / LL);
  __syncthreads();
  if (tid < NCLS) {
    float acc = bc[tid];
    for (int h = 0; h < HD; ++h) acc += pl[h] * Wc[h * NCLS + tid];
    out[b * NCLS + tid] = acc;
  }
}

extern "C" void kernel_launch(void* const* d_in, const int* in_sizes, int n_in,
                              void* d_out, int out_size, void* d_ws, size_t ws_size,
                              hipStream_t stream) {
  (void)in_sizes; (void)n_in; (void)d_ws; (void)ws_size; (void)out_size;
  const float* x_in   = (const float*)d_in[0];
  const float* W_in   = (const float*)d_in[1];
  const float* b_in   = (const float*)d_in[2];
  const float* log_dt = (const float*)d_in[3];
  const float* A_re   = (const float*)d_in[4];
  const float* A_im   = (const float*)d_in[5];
  const float* B_re   = (const float*)d_in[6];
  const float* B_im   = (const float*)d_in[7];
  const float* C_re   = (const float*)d_in[8];
  const float* C_im   = (const float*)d_in[9];
  const float* Dd     = (const float*)d_in[10];
  const float* W_out  = (const float*)d_in[11];
  const float* b_out  = (const float*)d_in[12];
  const float* ln_s   = (const float*)d_in[13];
  const float* ln_b   = (const float*)d_in[14];
  const float* lnf_s  = (const float*)d_in[15];
  const float* lnf_b  = (const float*)d_in[16];
  const float* W_cls  = (const float*)d_in[17];
  const float* b_cl   = (const float*)d_in[18];
  float* out = (float*)d_out;

  k_precomp<<<192, 256, 0, stream>>>(log_dt, A_re, A_im, B_re, B_im, C_re, C_im);
  k_precompK<<<384, 256, 0, stream>>>();
  k_gemm<true><<<dim3(256, 2), 256, 0, stream>>>(x_in, W_in, b_in);
  for (int i = 0; i < NLAYERS; ++i) {
    k_ln<<<2048, 256, 0, stream>>>(ln_s + i * HD, ln_b + i * HD);
    k_phaseA<<<dim3(128, 8), 128, 0, stream>>>(i);
    k_phaseB<<<512, 256, 0, stream>>>(i);
    k_phaseC<<<dim3(128, 8), 128, 0, stream>>>(i, Dd + i * HD);
    k_gemm<false><<<dim3(256, 4), 256, 0, stream>>>(nullptr, W_out + (long)i * HD * 2 * HD,
                                                    b_out + i * 2 * HD);
    k_glu<<<32768, 256, 0, stream>>>();
  }
  k_lnpool<<<256, 256, 0, stream>>>(lnf_s, lnf_b);
  k_cls<<<16, 256, 0, stream>>>(W_cls, b_cl, out);
}

// Round 2
// 1661.504 us; speedup vs baseline: 1.9851x; 1.9851x over previous
//
#include <hip/hip_runtime.h>
#include <math.h>

#define NLAYERS 6
#define HD 256
#define NS 32
#define NCLS 50
#define BB 16
#define LL 2048
#define TT 64
#define CC 32

// ---- static device workspaces (~236 MB total) ----
__device__ __attribute__((aligned(16))) float g_x [8388608];   // [B][L][H] residual stream
__device__ __attribute__((aligned(16))) float g_yb[8388608];   // [B][H][L] conv+gelu output
__device__ __attribute__((aligned(16))) float g_zS[16777216];  // z [B][H][L] | S_end/G [B][C][H][64]; overlaid by v [B*L][512]
__device__ __attribute__((aligned(16))) float g_Vt[6389760];   // [l][h][n][65][2] : w^t, t=0..64
__device__ __attribute__((aligned(16))) float g_Kt[98304];     // [l][h][64] kernel taps
__device__ __attribute__((aligned(16))) float g_E0[98304];     // [l][h][n][2] : C*dB
__device__ __attribute__((aligned(16))) float g_pp[65536];     // [B][16][H] pool partials
// broadcast-matvec tables, one 64x64 fp32 matrix per (layer,h) each:
__device__ __attribute__((aligned(16))) float g_TA[6291456];   // [l][h][t][p]: p=2n -> Re w^(63-t), 2n+1 -> Im
__device__ __attribute__((aligned(16))) float g_TK[6291456];   // [l][h][s][t]: t>=s ? K[t-s] : 0
__device__ __attribute__((aligned(16))) float g_TC[6291456];   // [l][h][p][t]: p=2n -> 2 Re w^(t+1), 2n+1 -> -2 Im w^(t+1)

#define SEND_OFF 8388608

__device__ __forceinline__ float sigf(float x) { return 1.0f / (1.0f + __expf(-x)); }
__device__ __forceinline__ float geluf(float x) {
  float t = 0.7978845608028654f * (x + 0.044715f * x * x * x);
  float e = __expf(2.0f * t);
  float th = 1.0f - 2.0f / (e + 1.0f);   // tanh(t); saturates correctly at +/-inf
  return 0.5f * x * (1.0f + th);
}

// ---------- precompute: w, E0 = C*dB, and power table w^t ----------
__global__ void k_precomp(const float* __restrict__ log_dt,
                          const float* __restrict__ A_re, const float* __restrict__ A_im,
                          const float* __restrict__ B_re, const float* __restrict__ B_im,
                          const float* __restrict__ C_re, const float* __restrict__ C_im) {
  int id = blockIdx.x * 256 + threadIdx.x;      // over NLAYERS*HD*NS = 49152
  if (id >= NLAYERS * HD * NS) return;
  int h = (id / NS) % HD;
  int i = id / (NS * HD);
  float dt = expf(log_dt[i * HD + h]);
  float ar = A_re[id], ai = A_im[id];
  float dr = dt * ar, di = dt * ai;
  float er = expf(dr);
  float wr = er * cosf(di), wi = er * sinf(di); // w = exp(dt*A)
  float inv = 1.0f / (ar * ar + ai * ai);
  float mr = wr - 1.0f, mi = wi;                // exp(dtA) - 1
  float qr = (mr * ar + mi * ai) * inv;         // (exp(dtA)-1)/A
  float qi = (mi * ar - mr * ai) * inv;
  float br = B_re[id], bi = B_im[id];
  float dbr = br * qr - bi * qi, dbi = br * qi + bi * qr;   // dB
  float cr = C_re[id], ci = C_im[id];
  g_E0[id * 2 + 0] = cr * dbr - ci * dbi;       // E0 = C*dB
  g_E0[id * 2 + 1] = cr * dbi + ci * dbr;
  float pr = 1.0f, pi = 0.0f;
  long base = (long)id * 65;
  for (int t = 0; t <= 64; ++t) {
    g_Vt[(base + t) * 2 + 0] = pr;
    g_Vt[(base + t) * 2 + 1] = pi;
    float nr = pr * wr - pi * wi;
    pi = pr * wi + pi * wr;
    pr = nr;
  }
}

// K[h,t] = 2*Re(sum_n E0*w^t), t<64
__global__ void k_precompK() {
  int id = blockIdx.x * 256 + threadIdx.x;      // over NLAYERS*HD*64 = 98304
  if (id >= NLAYERS * HD * TT) return;
  int t = id % TT;
  int lh = id / TT;                              // i*HD + h
  float acc = 0.f;
  const float* e = g_E0 + (long)lh * NS * 2;
  const float* v = g_Vt + ((long)lh * NS * 65 + t) * 2;
  for (int n = 0; n < NS; ++n)
    acc += e[n * 2] * v[n * 130] - e[n * 2 + 1] * v[n * 130 + 1];
  g_Kt[id] = 2.0f * acc;
}

// build the three 64x64 per-(l,h) tables
__global__ void k_precompT() {
  int id = blockIdx.x * 256 + threadIdx.x;      // over 6*256*64*64 = 6291456
  int b2 = id & 63;
  int a  = (id >> 6) & 63;
  int lh = id >> 12;
  const float2* Vt2 = (const float2*)g_Vt;
  // TK[lh][s=a][t=b2]
  g_TK[id] = (b2 >= a) ? g_Kt[(long)lh * 64 + (b2 - a)] : 0.f;
  // TC[lh][p=a][t=b2]
  {
    int n = a >> 1;
    float2 v = Vt2[((long)lh * NS + n) * 65 + (b2 + 1)];
    g_TC[id] = (a & 1) ? (-2.f * v.y) : (2.f * v.x);
  }
  // TA[lh][t=a][p=b2]
  {
    int n = b2 >> 1;
    float2 v = Vt2[((long)lh * NS + n) * 65 + (63 - a)];
    g_TA[id] = (b2 & 1) ? v.y : v.x;
  }
}

// ---------- fp32 tiled GEMM: 128x128 tile, 8x8 per thread ----------
template<bool IN>
__global__ __launch_bounds__(256) void k_gemm(const float* __restrict__ Aext,
                                              const float* __restrict__ Bw,
                                              const float* __restrict__ bias) {
  constexpr int KD  = IN ? 128 : 256;
  constexpr int LDA = IN ? 128 : LL;
  constexpr int LDB = IN ? 256 : 512;
  constexpr int LDC = IN ? 256 : 512;
  __shared__ float As[16][128];
  __shared__ float Bs[16][128];
  const int tid = threadIdx.x;
  const int m0 = blockIdx.x * 128, n0 = blockIdx.y * 128;
  const float* Ab;
  float* Cm;
  if constexpr (IN) { Ab = Aext + (long)m0 * LDA; Cm = g_x; }
  else              { Ab = g_yb + (long)(m0 >> 11) * HD * LL + (m0 & 2047); Cm = g_zS; }
  const float* Bb = Bw + n0;
  const int tx = tid & 15, ty = tid >> 4;
  float acc[8][8];
  #pragma unroll
  for (int r = 0; r < 8; ++r)
    #pragma unroll
    for (int c = 0; c < 8; ++c) acc[r][c] = 0.f;
  for (int k0 = 0; k0 < KD; k0 += 16) {
    __syncthreads();
    if constexpr (IN) {
      #pragma unroll
      for (int j = 0; j < 2; ++j) {
        int idx = tid + j * 256;
        int m = idx & 127, kq = idx >> 7;
        float4 v = *(const float4*)(Ab + (long)m * LDA + k0 + kq * 4);
        As[kq * 4 + 0][m] = v.x; As[kq * 4 + 1][m] = v.y;
        As[kq * 4 + 2][m] = v.z; As[kq * 4 + 3][m] = v.w;
      }
    } else {
      #pragma unroll
      for (int j = 0; j < 2; ++j) {
        int idx = tid + j * 256;
        int k = idx >> 5, mq = idx & 31;
        *(float4*)&As[k][mq * 4] = *(const float4*)(Ab + (long)(k0 + k) * LDA + mq * 4);
      }
    }
    #pragma unroll
    for (int j = 0; j < 2; ++j) {
      int idx = tid + j * 256;
      int k = idx >> 5, nq = idx & 31;
      *(float4*)&Bs[k][nq * 4] = *(const float4*)(Bb + (long)(k0 + k) * LDB + nq * 4);
    }
    __syncthreads();
    #pragma unroll
    for (int kk = 0; kk < 16; ++kk) {
      float a[8], bq[8];
      *(float4*)&a[0]  = *(float4*)&As[kk][ty * 8];
      *(float4*)&a[4]  = *(float4*)&As[kk][ty * 8 + 4];
      *(float4*)&bq[0] = *(float4*)&Bs[kk][tx * 8];
      *(float4*)&bq[4] = *(float4*)&Bs[kk][tx * 8 + 4];
      #pragma unroll
      for (int r = 0; r < 8; ++r)
        #pragma unroll
        for (int c = 0; c < 8; ++c) acc[r][c] += a[r] * bq[c];
    }
  }
  #pragma unroll
  for (int r = 0; r < 8; ++r) {
    long m = m0 + ty * 8 + r;
    #pragma unroll
    for (int c4 = 0; c4 < 2; ++c4) {
      int n = n0 + tx * 8 + c4 * 4;
      float4 bv = *(const float4*)(bias + n);
      float4 o;
      o.x = acc[r][c4 * 4 + 0] + bv.x;
      o.y = acc[r][c4 * 4 + 1] + bv.y;
      o.z = acc[r][c4 * 4 + 2] + bv.z;
      o.w = acc[r][c4 * 4 + 3] + bv.w;
      *(float4*)(Cm + m * LDC + n) = o;
    }
  }
}

// ---------- LayerNorm over H, write transposed z[B][H][L] ----------
__global__ __launch_bounds__(256) void k_ln(const float* __restrict__ gam,
                                            const float* __restrict__ bet) {
  __shared__ float S[16][256];
  const int bid = blockIdx.x;                 // B*L/16 = 2048
  const int b = bid >> 7, l0 = (bid & 127) << 4;
  const int tid = threadIdx.x;
  const int w = tid >> 6, lane = tid & 63;
  float4 gv = *(const float4*)(gam + lane * 4);
  float4 bv = *(const float4*)(bet + lane * 4);
  for (int r = 0; r < 4; ++r) {
    int l = l0 + w * 4 + r;
    float4 v = *(const float4*)(g_x + ((long)b * LL + l) * HD + lane * 4);
    float s1 = v.x + v.y + v.z + v.w;
    float s2 = v.x * v.x + v.y * v.y + v.z * v.z + v.w * v.w;
    #pragma unroll
    for (int off = 32; off; off >>= 1) { s1 += __shfl_xor(s1, off); s2 += __shfl_xor(s2, off); }
    float mu = s1 * (1.0f / HD);
    float var = s2 * (1.0f / HD) - mu * mu;
    float rs = rsqrtf(var + 1e-5f);
    int rr = w * 4 + r;
    S[rr][lane * 4 + 0] = (v.x - mu) * rs * gv.x + bv.x;
    S[rr][lane * 4 + 1] = (v.y - mu) * rs * gv.y + bv.y;
    S[rr][lane * 4 + 2] = (v.z - mu) * rs * gv.z + bv.z;
    S[rr][lane * 4 + 3] = (v.w - mu) * rs * gv.w + bv.w;
  }
  __syncthreads();
  float o[16];
  #pragma unroll
  for (int r = 0; r < 16; ++r) o[r] = S[r][tid];
  float* zp = g_zS + ((long)b * HD + tid) * LL + l0;
  #pragma unroll
  for (int q = 0; q < 4; ++q)
    *(float4*)(zp + q * 4) = make_float4(o[q * 4], o[q * 4 + 1], o[q * 4 + 2], o[q * 4 + 3]);
}

// ---------- Phase A (broadcast matvec): S_end[b,c,h,p] = sum_t TA[t][p] z[t] ----------
// one wave per (h, slice); 16 jobs per wave; no barriers, LDS slot private per wave
__global__ __launch_bounds__(256) void k_phaseA(int layer) {
  __shared__ float zs[4][64];
  const int tid = threadIdx.x, wid = tid >> 6, lane = tid & 63;
  const int h = blockIdx.x;
  const int slice = blockIdx.y * 4 + wid;          // 0..31
  const long lh = (long)layer * HD + h;
  float va[64];
  #pragma unroll
  for (int t = 0; t < 64; ++t) va[t] = g_TA[(lh * 64 + t) * 64 + lane];
  float* Send = g_zS + SEND_OFF;
  const float* zb = g_zS;
  for (int j = 0; j < 16; ++j) {
    int bc = slice * 16 + j;
    int b = bc >> 5, c = bc & 31;
    float zv = zb[((long)(b * HD + h)) * LL + c * 64 + lane];
    zs[wid][lane] = zv;
    float acc = 0.f;
    #pragma unroll
    for (int t = 0; t < 64; ++t) acc = fmaf(va[t], zs[wid][t], acc);
    Send[(((long)(b * CC + c)) * HD + h) * 64 + lane] = acc;
  }
}

// ---------- Phase B: combine chunks, G[c] = E0 .* S_prev[c] (in-place over S_end) ----------
__global__ void k_phaseB(int layer) {
  int id = blockIdx.x * 256 + threadIdx.x;     // B*H*N = 131072
  int n = id & 31, h = (id >> 5) & 255, b = id >> 13;
  long vb = ((long)(layer * HD + h) * NS + n) * 65;
  float wtr = g_Vt[(vb + 64) * 2], wti = g_Vt[(vb + 64) * 2 + 1];   // w^T
  long eb = ((long)(layer * HD + h) * NS + n) * 2;
  float e0r = g_E0[eb], e0i = g_E0[eb + 1];
  float sr = 0.f, si = 0.f;
  float* Send = g_zS + SEND_OFF;
  for (int c = 0; c < CC; ++c) {
    float* p = Send + (((long)(b * CC + c) * HD + h) * NS + n) * 2;
    float er = p[0], ei = p[1];
    p[0] = e0r * sr - e0i * si;                 // G = E0 * S_prev
    p[1] = e0r * si + e0i * sr;
    float nr = er + wtr * sr - wti * si;        // S_prev' = S_end + w^T * S_prev
    si      = ei + wtr * si + wti * sr;
    sr = nr;
  }
}

// ---------- Phase C (broadcast matvec): y[t] = sum_s TK[s][t] z[s] + sum_p TC[p][t] G[p] + D z[t]; gelu ----------
__global__ __launch_bounds__(256) void k_phaseC(int layer, const float* __restrict__ Dp) {
  __shared__ float zs[4][64];
  __shared__ float gs[4][64];
  const int tid = threadIdx.x, wid = tid >> 6, lane = tid & 63;
  const int h = blockIdx.x;
  const int slice = blockIdx.y * 4 + wid;          // 0..31
  const long lh = (long)layer * HD + h;
  float tk[64], vc[64];
  #pragma unroll
  for (int s = 0; s < 64; ++s) tk[s] = g_TK[(lh * 64 + s) * 64 + lane];
  #pragma unroll
  for (int p = 0; p < 64; ++p) vc[p] = g_TC[(lh * 64 + p) * 64 + lane];
  const float Dv = Dp[h];
  const float* Send = g_zS + SEND_OFF;
  for (int j = 0; j < 16; ++j) {
    int bc = slice * 16 + j;
    int b = bc >> 5, c = bc & 31;
    float zv = g_zS[((long)(b * HD + h)) * LL + c * 64 + lane];
    float gv = Send[(((long)(b * CC + c)) * HD + h) * 64 + lane];
    zs[wid][lane] = zv;
    gs[wid][lane] = gv;
    float acc = Dv * zv;
    #pragma unroll
    for (int s = 0; s < 64; ++s) acc = fmaf(tk[s], zs[wid][s], acc);
    #pragma unroll
    for (int p = 0; p < 64; ++p) acc = fmaf(vc[p], gs[wid][p], acc);
    g_yb[((long)(b * HD + h)) * LL + c * 64 + lane] = geluf(acc);
  }
}

// ---------- GLU + residual: x += a*sigmoid(g) ----------
__global__ void k_glu() {
  long id = (long)blockIdx.x * 256 + threadIdx.x;   // B*L*H = 8388608
  long m = id >> 8;
  int h = (int)(id & 255);
  float a = g_zS[m * 512 + h];
  float g = g_zS[m * 512 + 256 + h];
  g_x[id] += a * sigf(g);
}

// ---------- final LN + partial pool ----------
__global__ __launch_bounds__(256) void k_lnpool(const float* __restrict__ gam,
                                                const float* __restrict__ bet) {
  __shared__ float red[4][256];
  const int bid = blockIdx.x;          // b*16 + s
  const int b = bid >> 4, s = bid & 15;
  const int tid = threadIdx.x, w = tid >> 6, lane = tid & 63;
  float4 gv = *(const float4*)(gam + lane * 4);
  float4 bv = *(const float4*)(bet + lane * 4);
  float a0 = 0, a1 = 0, a2 = 0, a3 = 0;
  for (int r = 0; r < 32; ++r) {
    int l = s * 128 + w * 32 + r;
    float4 v = *(const float4*)(g_x + ((long)b * LL + l) * HD + lane * 4);
    float s1 = v.x + v.y + v.z + v.w;
    float s2 = v.x * v.x + v.y * v.y + v.z * v.z + v.w * v.w;
    #pragma unroll
    for (int off = 32; off; off >>= 1) { s1 += __shfl_xor(s1, off); s2 += __shfl_xor(s2, off); }
    float mu = s1 * (1.0f / HD);
    float rs = rsqrtf(s2 * (1.0f / HD) - mu * mu + 1e-5f);
    a0 += (v.x - mu) * rs * gv.x + bv.x;
    a1 += (v.y - mu) * rs * gv.y + bv.y;
    a2 += (v.z - mu) * rs * gv.z + bv.z;
    a3 += (v.w - mu) * rs * gv.w + bv.w;
  }
  red[w][lane * 4 + 0] = a0; red[w][lane * 4 + 1] = a1;
  red[w][lane * 4 + 2] = a2; red[w][lane * 4 + 3] = a3;
  __syncthreads();
  g_pp[(long)bid * HD + tid] = red[0][tid] + red[1][tid] + red[2][tid] + red[3][tid];
}

// ---------- classifier ----------
__global__ __launch_bounds__(256) void k_cls(const float* __restrict__ Wc,
                                             const float* __restrict__ bc,
                                             float* __restrict__ out) {
  __shared__ float pl[256];
  const int b = blockIdx.x, tid = threadIdx.x;
  float p = 0.f;
  #pragma unroll
  for (int s = 0; s < 16; ++s) p += g_pp[((long)b * 16 + s) * HD + tid];
  pl[tid] = p * (1.0f / LL);
  __syncthreads();
  if (tid < NCLS) {
    float acc = bc[tid];
    for (int h = 0; h < HD; ++h) acc += pl[h] * Wc[h * NCLS + tid];
    out[b * NCLS + tid] = acc;
  }
}

extern "C" void kernel_launch(void* const* d_in, const int* in_sizes, int n_in,
                              void* d_out, int out_size, void* d_ws, size_t ws_size,
                              hipStream_t stream) {
  (void)in_sizes; (void)n_in; (void)d_ws; (void)ws_size; (void)out_size;
  const float* x_in   = (const float*)d_in[0];
  const float* W_in   = (const float*)d_in[1];
  const float* b_in   = (const float*)d_in[2];
  const float* log_dt = (const float*)d_in[3];
  const float* A_re   = (const float*)d_in[4];
  const float* A_im   = (const float*)d_in[5];
  const float* B_re   = (const float*)d_in[6];
  const float* B_im   = (const float*)d_in[7];
  const float* C_re   = (const float*)d_in[8];
  const float* C_im   = (const float*)d_in[9];
  const float* Dd     = (const float*)d_in[10];
  const float* W_out  = (const float*)d_in[11];
  const float* b_out  = (const float*)d_in[12];
  const float* ln_s   = (const float*)d_in[13];
  const float* ln_b   = (const float*)d_in[14];
  const float* lnf_s  = (const float*)d_in[15];
  const float* lnf_b  = (const float*)d_in[16];
  const float* W_cls  = (const float*)d_in[17];
  const float* b_cl   = (const float*)d_in[18];
  float* out = (float*)d_out;

  k_precomp<<<192, 256, 0, stream>>>(log_dt, A_re, A_im, B_re, B_im, C_re, C_im);
  k_precompK<<<384, 256, 0, stream>>>();
  k_precompT<<<24576, 256, 0, stream>>>();
  k_gemm<true><<<dim3(256, 2), 256, 0, stream>>>(x_in, W_in, b_in);
  for (int i = 0; i < NLAYERS; ++i) {
    k_ln<<<2048, 256, 0, stream>>>(ln_s + i * HD, ln_b + i * HD);
    k_phaseA<<<dim3(256, 8), 256, 0, stream>>>(i);
    k_phaseB<<<512, 256, 0, stream>>>(i);
    k_phaseC<<<dim3(256, 8), 256, 0, stream>>>(i, Dd + i * HD);
    k_gemm<false><<<dim3(256, 4), 256, 0, stream>>>(nullptr, W_out + (long)i * HD * 2 * HD,
                                                    b_out + i * 2 * HD);
    k_glu<<<32768, 256, 0, stream>>>();
  }
  k_lnpool<<<256, 256, 0, stream>>>(lnf_s, lnf_b);
  k_cls<<<16, 256, 0, stream>>>(W_cls, b_cl, out);
}

// Round 3
// 1193.455 us; speedup vs baseline: 2.7636x; 1.3922x over previous
//
#include <hip/hip_runtime.h>
#include <math.h>

#define NLAYERS 6
#define HD 256
#define NS 32
#define NCLS 50
#define BB 16
#define LL 2048
#define TT 64
#define CC 32

typedef __attribute__((ext_vector_type(8))) short bf16x8;
typedef __attribute__((ext_vector_type(4))) float f32x4;

// ---- static device workspaces ----
__device__ __attribute__((aligned(16))) float g_x [8388608];   // [B][L][H] residual stream
__device__ __attribute__((aligned(16))) float g_zS[16777216];  // z [B][H][L] | S_end/G [B][C][H][64]
__device__ __attribute__((aligned(16))) float g_Vt[6389760];   // [l][h][n][65][2] : w^t, t=0..64
__device__ __attribute__((aligned(16))) float g_Kt[98304];     // [l][h][64] kernel taps
__device__ __attribute__((aligned(16))) float g_E0[98304];     // [l][h][n][2] : C*dB
__device__ __attribute__((aligned(16))) float g_pp[65536];     // [B][16][H] pool partials
__device__ __attribute__((aligned(16))) float g_TA[6291456];   // [l][h][t][p]
__device__ __attribute__((aligned(16))) float g_TK[6291456];   // [l][h][s][t]
__device__ __attribute__((aligned(16))) float g_TC[6291456];   // [l][h][p][t]
__device__ __attribute__((aligned(16))) unsigned short g_ybh[8388608]; // y bf16 [B][H][L]
__device__ __attribute__((aligned(16))) unsigned short g_yt [8388608]; // y bf16 [B][L][H]
__device__ __attribute__((aligned(16))) unsigned short g_Wt [786432];  // Wt bf16 [l][n=512][k=256]

#define SEND_OFF 8388608

__device__ __forceinline__ float sigf(float x) { return 1.0f / (1.0f + __expf(-x)); }
__device__ __forceinline__ float geluf(float x) {
  float t = 0.7978845608028654f * (x + 0.044715f * x * x * x);
  float e = __expf(2.0f * t);
  float th = 1.0f - 2.0f / (e + 1.0f);
  return 0.5f * x * (1.0f + th);
}
__device__ __forceinline__ unsigned short f2bf(float f) {
  unsigned u = __float_as_uint(f);
  unsigned r = (u + 0x7FFFu + ((u >> 16) & 1u)) >> 16;
  return (unsigned short)r;
}

// ---------- precompute: w, E0 = C*dB, and power table w^t ----------
__global__ void k_precomp(const float* __restrict__ log_dt,
                          const float* __restrict__ A_re, const float* __restrict__ A_im,
                          const float* __restrict__ B_re, const float* __restrict__ B_im,
                          const float* __restrict__ C_re, const float* __restrict__ C_im) {
  int id = blockIdx.x * 256 + threadIdx.x;
  if (id >= NLAYERS * HD * NS) return;
  int h = (id / NS) % HD;
  int i = id / (NS * HD);
  float dt = expf(log_dt[i * HD + h]);
  float ar = A_re[id], ai = A_im[id];
  float dr = dt * ar, di = dt * ai;
  float er = expf(dr);
  float wr = er * cosf(di), wi = er * sinf(di);
  float inv = 1.0f / (ar * ar + ai * ai);
  float mr = wr - 1.0f, mi = wi;
  float qr = (mr * ar + mi * ai) * inv;
  float qi = (mi * ar - mr * ai) * inv;
  float br = B_re[id], bi = B_im[id];
  float dbr = br * qr - bi * qi, dbi = br * qi + bi * qr;
  float cr = C_re[id], ci = C_im[id];
  g_E0[id * 2 + 0] = cr * dbr - ci * dbi;
  g_E0[id * 2 + 1] = cr * dbi + ci * dbr;
  float pr = 1.0f, pi = 0.0f;
  long base = (long)id * 65;
  for (int t = 0; t <= 64; ++t) {
    g_Vt[(base + t) * 2 + 0] = pr;
    g_Vt[(base + t) * 2 + 1] = pi;
    float nr = pr * wr - pi * wi;
    pi = pr * wi + pi * wr;
    pr = nr;
  }
}

__global__ void k_precompK() {
  int id = blockIdx.x * 256 + threadIdx.x;
  if (id >= NLAYERS * HD * TT) return;
  int t = id % TT;
  int lh = id / TT;
  float acc = 0.f;
  const float* e = g_E0 + (long)lh * NS * 2;
  const float* v = g_Vt + ((long)lh * NS * 65 + t) * 2;
  for (int n = 0; n < NS; ++n)
    acc += e[n * 2] * v[n * 130] - e[n * 2 + 1] * v[n * 130 + 1];
  g_Kt[id] = 2.0f * acc;
}

__global__ void k_precompT() {
  int id = blockIdx.x * 256 + threadIdx.x;
  int b2 = id & 63;
  int a  = (id >> 6) & 63;
  int lh = id >> 12;
  const float2* Vt2 = (const float2*)g_Vt;
  g_TK[id] = (b2 >= a) ? g_Kt[(long)lh * 64 + (b2 - a)] : 0.f;
  {
    int n = a >> 1;
    float2 v = Vt2[((long)lh * NS + n) * 65 + (b2 + 1)];
    g_TC[id] = (a & 1) ? (-2.f * v.y) : (2.f * v.x);
  }
  {
    int n = b2 >> 1;
    float2 v = Vt2[((long)lh * NS + n) * 65 + (63 - a)];
    g_TA[id] = (b2 & 1) ? v.y : v.x;
  }
}

// ---------- W_out -> Wt bf16 [l][n][k] (LDS tile transpose) ----------
__global__ __launch_bounds__(256) void k_prepW(const float* __restrict__ W_out) {
  __shared__ float T[32][33];
  int bid = blockIdx.x;                 // l*128 + kt*16 + nt
  int nt = bid & 15, kt = (bid >> 4) & 7, l = bid >> 7;
  int t = threadIdx.x;
  int tr = t >> 3, tc = t & 7;
  const float* src = W_out + (long)l * 131072 + (long)(kt * 32) * 512 + nt * 32;
  float4 v = *(const float4*)(src + (long)tr * 512 + tc * 4);
  T[tr][tc * 4 + 0] = v.x; T[tr][tc * 4 + 1] = v.y;
  T[tr][tc * 4 + 2] = v.z; T[tr][tc * 4 + 3] = v.w;
  __syncthreads();
  ushort4 o;
  o.x = f2bf(T[tc * 4 + 0][tr]); o.y = f2bf(T[tc * 4 + 1][tr]);
  o.z = f2bf(T[tc * 4 + 2][tr]); o.w = f2bf(T[tc * 4 + 3][tr]);
  *(ushort4*)(g_Wt + ((long)l * 512 + nt * 32 + tr) * 256 + kt * 32 + tc * 4) = o;
}

// ---------- input GEMM (fp32): x[32768,256] = A[32768,128] * W_in + b ----------
__global__ __launch_bounds__(256) void k_gemmin(const float* __restrict__ Aext,
                                                const float* __restrict__ Bw,
                                                const float* __restrict__ bias) {
  __shared__ float As[16][128];
  __shared__ float Bs[16][128];
  const int tid = threadIdx.x;
  const int m0 = blockIdx.x * 128, n0 = blockIdx.y * 128;
  const float* Ab = Aext + (long)m0 * 128;
  const float* Bb = Bw + n0;
  const int tx = tid & 15, ty = tid >> 4;
  float acc[8][8];
  #pragma unroll
  for (int r = 0; r < 8; ++r)
    #pragma unroll
    for (int c = 0; c < 8; ++c) acc[r][c] = 0.f;
  for (int k0 = 0; k0 < 128; k0 += 16) {
    __syncthreads();
    #pragma unroll
    for (int j = 0; j < 2; ++j) {
      int idx = tid + j * 256;
      int m = idx & 127, kq = idx >> 7;
      float4 v = *(const float4*)(Ab + (long)m * 128 + k0 + kq * 4);
      As[kq * 4 + 0][m] = v.x; As[kq * 4 + 1][m] = v.y;
      As[kq * 4 + 2][m] = v.z; As[kq * 4 + 3][m] = v.w;
    }
    #pragma unroll
    for (int j = 0; j < 2; ++j) {
      int idx = tid + j * 256;
      int k = idx >> 5, nq = idx & 31;
      *(float4*)&Bs[k][nq * 4] = *(const float4*)(Bb + (long)(k0 + k) * 256 + nq * 4);
    }
    __syncthreads();
    #pragma unroll
    for (int kk = 0; kk < 16; ++kk) {
      float a[8], bq[8];
      *(float4*)&a[0]  = *(float4*)&As[kk][ty * 8];
      *(float4*)&a[4]  = *(float4*)&As[kk][ty * 8 + 4];
      *(float4*)&bq[0] = *(float4*)&Bs[kk][tx * 8];
      *(float4*)&bq[4] = *(float4*)&Bs[kk][tx * 8 + 4];
      #pragma unroll
      for (int r = 0; r < 8; ++r)
        #pragma unroll
        for (int c = 0; c < 8; ++c) acc[r][c] += a[r] * bq[c];
    }
  }
  #pragma unroll
  for (int r = 0; r < 8; ++r) {
    long m = m0 + ty * 8 + r;
    #pragma unroll
    for (int c4 = 0; c4 < 2; ++c4) {
      int n = n0 + tx * 8 + c4 * 4;
      float4 bv = *(const float4*)(bias + n);
      float4 o;
      o.x = acc[r][c4 * 4 + 0] + bv.x;
      o.y = acc[r][c4 * 4 + 1] + bv.y;
      o.z = acc[r][c4 * 4 + 2] + bv.z;
      o.w = acc[r][c4 * 4 + 3] + bv.w;
      *(float4*)(g_x + m * 256 + n) = o;
    }
  }
}

// ---------- LayerNorm over H, write transposed z[B][H][L] ----------
__global__ __launch_bounds__(256) void k_ln(const float* __restrict__ gam,
                                            const float* __restrict__ bet) {
  __shared__ float S[16][256];
  const int bid = blockIdx.x;
  const int b = bid >> 7, l0 = (bid & 127) << 4;
  const int tid = threadIdx.x;
  const int w = tid >> 6, lane = tid & 63;
  float4 gv = *(const float4*)(gam + lane * 4);
  float4 bv = *(const float4*)(bet + lane * 4);
  for (int r = 0; r < 4; ++r) {
    int l = l0 + w * 4 + r;
    float4 v = *(const float4*)(g_x + ((long)b * LL + l) * HD + lane * 4);
    float s1 = v.x + v.y + v.z + v.w;
    float s2 = v.x * v.x + v.y * v.y + v.z * v.z + v.w * v.w;
    #pragma unroll
    for (int off = 32; off; off >>= 1) { s1 += __shfl_xor(s1, off); s2 += __shfl_xor(s2, off); }
    float mu = s1 * (1.0f / HD);
    float var = s2 * (1.0f / HD) - mu * mu;
    float rs = rsqrtf(var + 1e-5f);
    int rr = w * 4 + r;
    S[rr][lane * 4 + 0] = (v.x - mu) * rs * gv.x + bv.x;
    S[rr][lane * 4 + 1] = (v.y - mu) * rs * gv.y + bv.y;
    S[rr][lane * 4 + 2] = (v.z - mu) * rs * gv.z + bv.z;
    S[rr][lane * 4 + 3] = (v.w - mu) * rs * gv.w + bv.w;
  }
  __syncthreads();
  float o[16];
  #pragma unroll
  for (int r = 0; r < 16; ++r) o[r] = S[r][tid];
  float* zp = g_zS + ((long)b * HD + tid) * LL + l0;
  #pragma unroll
  for (int q = 0; q < 4; ++q)
    *(float4*)(zp + q * 4) = make_float4(o[q * 4], o[q * 4 + 1], o[q * 4 + 2], o[q * 4 + 3]);
}

// ---------- Phase A (broadcast matvec) ----------
__global__ __launch_bounds__(256) void k_phaseA(int layer) {
  __shared__ float zs[4][64];
  const int tid = threadIdx.x, wid = tid >> 6, lane = tid & 63;
  const int h = blockIdx.x;
  const int slice = blockIdx.y * 4 + wid;
  const long lh = (long)layer * HD + h;
  float va[64];
  #pragma unroll
  for (int t = 0; t < 64; ++t) va[t] = g_TA[(lh * 64 + t) * 64 + lane];
  float* Send = g_zS + SEND_OFF;
  const float* zb = g_zS;
  for (int j = 0; j < 16; ++j) {
    int bc = slice * 16 + j;
    int b = bc >> 5, c = bc & 31;
    float zv = zb[((long)(b * HD + h)) * LL + c * 64 + lane];
    zs[wid][lane] = zv;
    float acc = 0.f;
    #pragma unroll
    for (int t = 0; t < 64; ++t) acc = fmaf(va[t], zs[wid][t], acc);
    Send[(((long)(b * CC + c)) * HD + h) * 64 + lane] = acc;
  }
}

// ---------- Phase B: scan chunks ----------
__global__ void k_phaseB(int layer) {
  int id = blockIdx.x * 256 + threadIdx.x;
  int n = id & 31, h = (id >> 5) & 255, b = id >> 13;
  long vb = ((long)(layer * HD + h) * NS + n) * 65;
  float wtr = g_Vt[(vb + 64) * 2], wti = g_Vt[(vb + 64) * 2 + 1];
  long eb = ((long)(layer * HD + h) * NS + n) * 2;
  float e0r = g_E0[eb], e0i = g_E0[eb + 1];
  float sr = 0.f, si = 0.f;
  float* Send = g_zS + SEND_OFF;
  for (int c = 0; c < CC; ++c) {
    float* p = Send + (((long)(b * CC + c) * HD + h) * NS + n) * 2;
    float er = p[0], ei = p[1];
    p[0] = e0r * sr - e0i * si;
    p[1] = e0r * si + e0i * sr;
    float nr = er + wtr * sr - wti * si;
    si      = ei + wtr * si + wti * sr;
    sr = nr;
  }
}

// ---------- Phase C: conv + correction + D*z, gelu -> bf16 [B][H][L] ----------
__global__ __launch_bounds__(256) void k_phaseC(int layer, const float* __restrict__ Dp) {
  __shared__ float zs[4][64];
  __shared__ float gs[4][64];
  const int tid = threadIdx.x, wid = tid >> 6, lane = tid & 63;
  const int h = blockIdx.x;
  const int slice = blockIdx.y * 4 + wid;
  const long lh = (long)layer * HD + h;
  float tk[64], vc[64];
  #pragma unroll
  for (int s = 0; s < 64; ++s) tk[s] = g_TK[(lh * 64 + s) * 64 + lane];
  #pragma unroll
  for (int p = 0; p < 64; ++p) vc[p] = g_TC[(lh * 64 + p) * 64 + lane];
  const float Dv = Dp[h];
  const float* Send = g_zS + SEND_OFF;
  for (int j = 0; j < 16; ++j) {
    int bc = slice * 16 + j;
    int b = bc >> 5, c = bc & 31;
    float zv = g_zS[((long)(b * HD + h)) * LL + c * 64 + lane];
    float gv = Send[(((long)(b * CC + c)) * HD + h) * 64 + lane];
    zs[wid][lane] = zv;
    gs[wid][lane] = gv;
    float acc = Dv * zv;
    #pragma unroll
    for (int s = 0; s < 64; ++s) acc = fmaf(tk[s], zs[wid][s], acc);
    #pragma unroll
    for (int p = 0; p < 64; ++p) acc = fmaf(vc[p], gs[wid][p], acc);
    g_ybh[((long)(b * HD + h)) * LL + c * 64 + lane] = f2bf(geluf(acc));
  }
}

// ---------- transpose y: [B][H][L] bf16 -> [B][L][H] bf16 ----------
__global__ __launch_bounds__(256) void k_transp() {
  __shared__ unsigned short T[64][65];
  int bid = blockIdx.x;                 // b*128 + lt*4 + ht
  int ht = bid & 3, lt = (bid >> 2) & 31, b = bid >> 7;
  int t = threadIdx.x;
  int r = t >> 4, c = t & 15;
  #pragma unroll
  for (int i = 0; i < 4; ++i) {
    int hh = r + i * 16;
    ushort4 v = *(const ushort4*)(g_ybh + ((long)(b * 256 + ht * 64 + hh)) * 2048 + lt * 64 + c * 4);
    T[hh][c * 4 + 0] = v.x; T[hh][c * 4 + 1] = v.y;
    T[hh][c * 4 + 2] = v.z; T[hh][c * 4 + 3] = v.w;
  }
  __syncthreads();
  #pragma unroll
  for (int i = 0; i < 4; ++i) {
    int ll = r + i * 16;
    ushort4 o;
    o.x = T[c * 4 + 0][ll]; o.y = T[c * 4 + 1][ll];
    o.z = T[c * 4 + 2][ll]; o.w = T[c * 4 + 3][ll];
    *(ushort4*)(g_yt + ((long)(b * 2048 + lt * 64 + ll)) * 256 + ht * 64 + c * 4) = o;
  }
}

// ---------- bf16 MFMA GEMM + fused GLU + residual ----------
// v[m,n] = sum_k yt[m,k] W[k,n];  x[m, c] += (v[m,c]+ba) * sigmoid(v[m,c+256]+bg)
__global__ __launch_bounds__(256) void k_gemmglu(int layer, const float* __restrict__ bias) {
  __shared__ __attribute__((aligned(16))) unsigned short As[128 * 32]; // [m][k] 64B rows
  __shared__ __attribute__((aligned(16))) unsigned short Bs[256 * 32]; // [n'][k]
  const int tid = threadIdx.x;
  const int wave = tid >> 6, lane = tid & 63;
  const int m0 = blockIdx.x * 128;
  const int gg = blockIdx.y;
  const int wm = wave & 1, wn = wave >> 1;
  const unsigned short* Ag = g_yt + (long)m0 * 256;
  const unsigned short* Wt = g_Wt + (long)layer * 131072;
  f32x4 acc[4][8];
  #pragma unroll
  for (int a = 0; a < 4; ++a)
    #pragma unroll
    for (int b2 = 0; b2 < 8; ++b2) acc[a][b2] = (f32x4){0.f, 0.f, 0.f, 0.f};
  for (int k0 = 0; k0 < 256; k0 += 32) {
    __syncthreads();
    #pragma unroll
    for (int it = 0; it < 2; ++it) {
      int slot = it * 256 + wave * 64 + lane;
      int m = slot >> 2, ko = (slot & 3) * 8;
      __builtin_amdgcn_global_load_lds(
        (const __attribute__((address_space(1))) unsigned int*)(Ag + (long)m * 256 + k0 + ko),
        (__attribute__((address_space(3))) unsigned int*)(As + (it * 256 + wave * 64) * 8),
        16, 0, 0);
    }
    #pragma unroll
    for (int it = 0; it < 4; ++it) {
      int slot = it * 256 + wave * 64 + lane;
      int np = slot >> 2, ko = (slot & 3) * 8;
      int n = gg * 128 + (np < 128 ? np : np + 128);
      __builtin_amdgcn_global_load_lds(
        (const __attribute__((address_space(1))) unsigned int*)(Wt + (long)n * 256 + k0 + ko),
        (__attribute__((address_space(3))) unsigned int*)(Bs + (it * 256 + wave * 64) * 8),
        16, 0, 0);
    }
    __syncthreads();
    bf16x8 af[4], bfa[4], bfg[4];
    const int q2 = (lane >> 4) * 8;
    #pragma unroll
    for (int mt = 0; mt < 4; ++mt)
      af[mt] = *(const bf16x8*)&As[(wm * 64 + mt * 16 + (lane & 15)) * 32 + q2];
    #pragma unroll
    for (int j = 0; j < 4; ++j)
      bfa[j] = *(const bf16x8*)&Bs[(wn * 64 + j * 16 + (lane & 15)) * 32 + q2];
    #pragma unroll
    for (int j = 0; j < 4; ++j)
      bfg[j] = *(const bf16x8*)&Bs[(128 + wn * 64 + j * 16 + (lane & 15)) * 32 + q2];
    #pragma unroll
    for (int mt = 0; mt < 4; ++mt)
      #pragma unroll
      for (int j = 0; j < 4; ++j) {
        acc[mt][j]     = __builtin_amdgcn_mfma_f32_16x16x32_bf16(af[mt], bfa[j], acc[mt][j], 0, 0, 0);
        acc[mt][4 + j] = __builtin_amdgcn_mfma_f32_16x16x32_bf16(af[mt], bfg[j], acc[mt][4 + j], 0, 0, 0);
      }
  }
  #pragma unroll
  for (int j = 0; j < 4; ++j) {
    int col = gg * 128 + wn * 64 + j * 16 + (lane & 15);
    float ba = bias[col], bg = bias[col + 256];
    #pragma unroll
    for (int mt = 0; mt < 4; ++mt) {
      #pragma unroll
      for (int r = 0; r < 4; ++r) {
        int row = m0 + wm * 64 + mt * 16 + (lane >> 4) * 4 + r;
        float a = acc[mt][j][r] + ba;
        float g = acc[mt][4 + j][r] + bg;
        float* xp = g_x + (long)row * 256 + col;
        *xp += a * sigf(g);
      }
    }
  }
}

// ---------- final LN + partial pool ----------
__global__ __launch_bounds__(256) void k_lnpool(const float* __restrict__ gam,
                                                const float* __restrict__ bet) {
  __shared__ float red[4][256];
  const int bid = blockIdx.x;
  const int b = bid >> 4, s = bid & 15;
  const int tid = threadIdx.x, w = tid >> 6, lane = tid & 63;
  float4 gv = *(const float4*)(gam + lane * 4);
  float4 bv = *(const float4*)(bet + lane * 4);
  float a0 = 0, a1 = 0, a2 = 0, a3 = 0;
  for (int r = 0; r < 32; ++r) {
    int l = s * 128 + w * 32 + r;
    float4 v = *(const float4*)(g_x + ((long)b * LL + l) * HD + lane * 4);
    float s1 = v.x + v.y + v.z + v.w;
    float s2 = v.x * v.x + v.y * v.y + v.z * v.z + v.w * v.w;
    #pragma unroll
    for (int off = 32; off; off >>= 1) { s1 += __shfl_xor(s1, off); s2 += __shfl_xor(s2, off); }
    float mu = s1 * (1.0f / HD);
    float rs = rsqrtf(s2 * (1.0f / HD) - mu * mu + 1e-5f);
    a0 += (v.x - mu) * rs * gv.x + bv.x;
    a1 += (v.y - mu) * rs * gv.y + bv.y;
    a2 += (v.z - mu) * rs * gv.z + bv.z;
    a3 += (v.w - mu) * rs * gv.w + bv.w;
  }
  red[w][lane * 4 + 0] = a0; red[w][lane * 4 + 1] = a1;
  red[w][lane * 4 + 2] = a2; red[w][lane * 4 + 3] = a3;
  __syncthreads();
  g_pp[(long)bid * HD + tid] = red[0][tid] + red[1][tid] + red[2][tid] + red[3][tid];
}

// ---------- classifier ----------
__global__ __launch_bounds__(256) void k_cls(const float* __restrict__ Wc,
                                             const float* __restrict__ bc,
                                             float* __restrict__ out) {
  __shared__ float pl[256];
  const int b = blockIdx.x, tid = threadIdx.x;
  float p = 0.f;
  #pragma unroll
  for (int s = 0; s < 16; ++s) p += g_pp[((long)b * 16 + s) * HD + tid];
  pl[tid] = p * (1.0f / LL);
  __syncthreads();
  if (tid < NCLS) {
    float acc = bc[tid];
    for (int h = 0; h < HD; ++h) acc += pl[h] * Wc[h * NCLS + tid];
    out[b * NCLS + tid] = acc;
  }
}

extern "C" void kernel_launch(void* const* d_in, const int* in_sizes, int n_in,
                              void* d_out, int out_size, void* d_ws, size_t ws_size,
                              hipStream_t stream) {
  (void)in_sizes; (void)n_in; (void)d_ws; (void)ws_size; (void)out_size;
  const float* x_in   = (const float*)d_in[0];
  const float* W_in   = (const float*)d_in[1];
  const float* b_in   = (const float*)d_in[2];
  const float* log_dt = (const float*)d_in[3];
  const float* A_re   = (const float*)d_in[4];
  const float* A_im   = (const float*)d_in[5];
  const float* B_re   = (const float*)d_in[6];
  const float* B_im   = (const float*)d_in[7];
  const float* C_re   = (const float*)d_in[8];
  const float* C_im   = (const float*)d_in[9];
  const float* Dd     = (const float*)d_in[10];
  const float* W_out  = (const float*)d_in[11];
  const float* b_out  = (const float*)d_in[12];
  const float* ln_s   = (const float*)d_in[13];
  const float* ln_b   = (const float*)d_in[14];
  const float* lnf_s  = (const float*)d_in[15];
  const float* lnf_b  = (const float*)d_in[16];
  const float* W_cls  = (const float*)d_in[17];
  const float* b_cl   = (const float*)d_in[18];
  float* out = (float*)d_out;

  k_precomp<<<192, 256, 0, stream>>>(log_dt, A_re, A_im, B_re, B_im, C_re, C_im);
  k_precompK<<<384, 256, 0, stream>>>();
  k_precompT<<<24576, 256, 0, stream>>>();
  k_prepW<<<768, 256, 0, stream>>>(W_out);
  k_gemmin<<<dim3(256, 2), 256, 0, stream>>>(x_in, W_in, b_in);
  for (int i = 0; i < NLAYERS; ++i) {
    k_ln<<<2048, 256, 0, stream>>>(ln_s + i * HD, ln_b + i * HD);
    k_phaseA<<<dim3(256, 8), 256, 0, stream>>>(i);
    k_phaseB<<<512, 256, 0, stream>>>(i);
    k_phaseC<<<dim3(256, 8), 256, 0, stream>>>(i, Dd + i * HD);
    k_transp<<<2048, 256, 0, stream>>>();
    k_gemmglu<<<dim3(256, 2), 256, 0, stream>>>(i, b_out + i * 2 * HD);
  }
  k_lnpool<<<256, 256, 0, stream>>>(lnf_s, lnf_b);
  k_cls<<<16, 256, 0, stream>>>(W_cls, b_cl, out);
}

// Round 4
// 827.264 us; speedup vs baseline: 3.9870x; 1.4427x over previous
//
#include <hip/hip_runtime.h>
#include <math.h>

#define NLAYERS 6
#define HD 256
#define NS 32
#define NCLS 50
#define BB 16
#define LL 2048
#define TT 64
#define CC 32

typedef __attribute__((ext_vector_type(8))) short bf16x8;
typedef __attribute__((ext_vector_type(4))) float f32x4;

// ---- static device workspaces (~200 MB) ----
__device__ __attribute__((aligned(16))) float g_x [8388608];   // [B][L][H] residual stream (fp32)
__device__ __attribute__((aligned(16))) float g_Se[8388608];   // S_end fp32 [job=512][H][64]
__device__ __attribute__((aligned(16))) float g_Vt[6389760];   // [l][h][n][65][2] : w^t, t=0..64
__device__ __attribute__((aligned(16))) float g_Kt[98304];     // [l][h][64] kernel taps
__device__ __attribute__((aligned(16))) float g_E0[98304];     // [l][h][n][2] : C*dB
__device__ __attribute__((aligned(16))) float g_pp[65536];     // [B][16][H] pool partials
__device__ __attribute__((aligned(16))) unsigned short g_zbh[8388608]; // z bf16 [B][H][L]
__device__ __attribute__((aligned(16))) unsigned short g_Gb [8388608]; // G bf16 [job][H][64]
__device__ __attribute__((aligned(16))) unsigned short g_Mt [12582912];// [l][h][t=64][k=128] bf16 (TK;TC)^T, D folded
__device__ __attribute__((aligned(16))) unsigned short g_TAt[6291456]; // [l][h][p=64][t=64] bf16 TA^T
__device__ __attribute__((aligned(16))) unsigned short g_ybh[8388608]; // y bf16 [B][H][L]
__device__ __attribute__((aligned(16))) unsigned short g_yt [8388608]; // y bf16 [B][L][H]
__device__ __attribute__((aligned(16))) unsigned short g_Wt [786432];  // Wt bf16 [l][n=512][k=256]

__device__ __forceinline__ float sigf(float x) { return 1.0f / (1.0f + __expf(-x)); }
__device__ __forceinline__ float geluf(float x) {
  float t = 0.7978845608028654f * (x + 0.044715f * x * x * x);
  float e = __expf(2.0f * t);
  float th = 1.0f - 2.0f / (e + 1.0f);
  return 0.5f * x * (1.0f + th);
}
__device__ __forceinline__ unsigned short f2bf(float f) {
  unsigned u = __float_as_uint(f);
  unsigned r = (u + 0x7FFFu + ((u >> 16) & 1u)) >> 16;
  return (unsigned short)r;
}

// ---------- precompute: w, E0 = C*dB, power table w^t ----------
__global__ void k_precomp(const float* __restrict__ log_dt,
                          const float* __restrict__ A_re, const float* __restrict__ A_im,
                          const float* __restrict__ B_re, const float* __restrict__ B_im,
                          const float* __restrict__ C_re, const float* __restrict__ C_im) {
  int id = blockIdx.x * 256 + threadIdx.x;
  if (id >= NLAYERS * HD * NS) return;
  int h = (id / NS) % HD;
  int i = id / (NS * HD);
  float dt = expf(log_dt[i * HD + h]);
  float ar = A_re[id], ai = A_im[id];
  float dr = dt * ar, di = dt * ai;
  float er = expf(dr);
  float wr = er * cosf(di), wi = er * sinf(di);
  float inv = 1.0f / (ar * ar + ai * ai);
  float mr = wr - 1.0f, mi = wi;
  float qr = (mr * ar + mi * ai) * inv;
  float qi = (mi * ar - mr * ai) * inv;
  float br = B_re[id], bi = B_im[id];
  float dbr = br * qr - bi * qi, dbi = br * qi + bi * qr;
  float cr = C_re[id], ci = C_im[id];
  g_E0[id * 2 + 0] = cr * dbr - ci * dbi;
  g_E0[id * 2 + 1] = cr * dbi + ci * dbr;
  float pr = 1.0f, pi = 0.0f;
  long base = (long)id * 65;
  for (int t = 0; t <= 64; ++t) {
    g_Vt[(base + t) * 2 + 0] = pr;
    g_Vt[(base + t) * 2 + 1] = pi;
    float nr = pr * wr - pi * wi;
    pi = pr * wi + pi * wr;
    pr = nr;
  }
}

__global__ void k_precompK() {
  int id = blockIdx.x * 256 + threadIdx.x;
  if (id >= NLAYERS * HD * TT) return;
  int t = id % TT;
  int lh = id / TT;
  float acc = 0.f;
  const float* e = g_E0 + (long)lh * NS * 2;
  const float* v = g_Vt + ((long)lh * NS * 65 + t) * 2;
  for (int n = 0; n < NS; ++n)
    acc += e[n * 2] * v[n * 130] - e[n * 2 + 1] * v[n * 130 + 1];
  g_Kt[id] = 2.0f * acc;
}

// build Mt[l][h][t][k] bf16: k<64 -> TK[s=k][t] (+D at k==t); k>=64 -> TC[p=k-64][t]
__global__ void k_precompM(const float* __restrict__ Dd) {
  int id = blockIdx.x * 256 + threadIdx.x;     // 6*256*64*128 = 12582912
  int k = id & 127;
  int t = (id >> 7) & 63;
  int lh = id >> 13;
  float v;
  if (k < 64) {
    v = (t >= k) ? g_Kt[(long)lh * 64 + (t - k)] : 0.f;
    if (k == t) v += Dd[lh];
  } else {
    int p = k - 64, n = p >> 1;
    const float2 w = ((const float2*)g_Vt)[((long)lh * NS + n) * 65 + (t + 1)];
    v = (p & 1) ? (-2.f * w.y) : (2.f * w.x);
  }
  g_Mt[id] = f2bf(v);
}

// build TAt[l][h][p][t] = TA[t][p] bf16
__global__ void k_precompA2() {
  int id = blockIdx.x * 256 + threadIdx.x;     // 6*256*64*64 = 6291456
  int t = id & 63;
  int p = (id >> 6) & 63;
  int lh = id >> 12;
  int n = p >> 1;
  const float2 w = ((const float2*)g_Vt)[((long)lh * NS + n) * 65 + (63 - t)];
  g_TAt[id] = f2bf((p & 1) ? w.y : w.x);
}

// ---------- W_out -> Wt bf16 [l][n][k] ----------
__global__ __launch_bounds__(256) void k_prepW(const float* __restrict__ W_out) {
  __shared__ float T[32][33];
  int bid = blockIdx.x;
  int nt = bid & 15, kt = (bid >> 4) & 7, l = bid >> 7;
  int t = threadIdx.x;
  int tr = t >> 3, tc = t & 7;
  const float* src = W_out + (long)l * 131072 + (long)(kt * 32) * 512 + nt * 32;
  float4 v = *(const float4*)(src + (long)tr * 512 + tc * 4);
  T[tr][tc * 4 + 0] = v.x; T[tr][tc * 4 + 1] = v.y;
  T[tr][tc * 4 + 2] = v.z; T[tr][tc * 4 + 3] = v.w;
  __syncthreads();
  ushort4 o;
  o.x = f2bf(T[tc * 4 + 0][tr]); o.y = f2bf(T[tc * 4 + 1][tr]);
  o.z = f2bf(T[tc * 4 + 2][tr]); o.w = f2bf(T[tc * 4 + 3][tr]);
  *(ushort4*)(g_Wt + ((long)l * 512 + nt * 32 + tr) * 256 + kt * 32 + tc * 4) = o;
}

// ---------- input GEMM (fp32) ----------
__global__ __launch_bounds__(256) void k_gemmin(const float* __restrict__ Aext,
                                                const float* __restrict__ Bw,
                                                const float* __restrict__ bias) {
  __shared__ float As[16][128];
  __shared__ float Bs[16][128];
  const int tid = threadIdx.x;
  const int m0 = blockIdx.x * 128, n0 = blockIdx.y * 128;
  const float* Ab = Aext + (long)m0 * 128;
  const float* Bb = Bw + n0;
  const int tx = tid & 15, ty = tid >> 4;
  float acc[8][8];
  #pragma unroll
  for (int r = 0; r < 8; ++r)
    #pragma unroll
    for (int c = 0; c < 8; ++c) acc[r][c] = 0.f;
  for (int k0 = 0; k0 < 128; k0 += 16) {
    __syncthreads();
    #pragma unroll
    for (int j = 0; j < 2; ++j) {
      int idx = tid + j * 256;
      int m = idx & 127, kq = idx >> 7;
      float4 v = *(const float4*)(Ab + (long)m * 128 + k0 + kq * 4);
      As[kq * 4 + 0][m] = v.x; As[kq * 4 + 1][m] = v.y;
      As[kq * 4 + 2][m] = v.z; As[kq * 4 + 3][m] = v.w;
    }
    #pragma unroll
    for (int j = 0; j < 2; ++j) {
      int idx = tid + j * 256;
      int k = idx >> 5, nq = idx & 31;
      *(float4*)&Bs[k][nq * 4] = *(const float4*)(Bb + (long)(k0 + k) * 256 + nq * 4);
    }
    __syncthreads();
    #pragma unroll
    for (int kk = 0; kk < 16; ++kk) {
      float a[8], bq[8];
      *(float4*)&a[0]  = *(float4*)&As[kk][ty * 8];
      *(float4*)&a[4]  = *(float4*)&As[kk][ty * 8 + 4];
      *(float4*)&bq[0] = *(float4*)&Bs[kk][tx * 8];
      *(float4*)&bq[4] = *(float4*)&Bs[kk][tx * 8 + 4];
      #pragma unroll
      for (int r = 0; r < 8; ++r)
        #pragma unroll
        for (int c = 0; c < 8; ++c) acc[r][c] += a[r] * bq[c];
    }
  }
  #pragma unroll
  for (int r = 0; r < 8; ++r) {
    long m = m0 + ty * 8 + r;
    #pragma unroll
    for (int c4 = 0; c4 < 2; ++c4) {
      int n = n0 + tx * 8 + c4 * 4;
      float4 bv = *(const float4*)(bias + n);
      float4 o;
      o.x = acc[r][c4 * 4 + 0] + bv.x;
      o.y = acc[r][c4 * 4 + 1] + bv.y;
      o.z = acc[r][c4 * 4 + 2] + bv.z;
      o.w = acc[r][c4 * 4 + 3] + bv.w;
      *(float4*)(g_x + m * 256 + n) = o;
    }
  }
}

// ---------- LayerNorm over H, write transposed z bf16 [B][H][L] ----------
__global__ __launch_bounds__(256) void k_ln(const float* __restrict__ gam,
                                            const float* __restrict__ bet) {
  __shared__ float S[16][256];
  const int bid = blockIdx.x;
  const int b = bid >> 7, l0 = (bid & 127) << 4;
  const int tid = threadIdx.x;
  const int w = tid >> 6, lane = tid & 63;
  float4 gv = *(const float4*)(gam + lane * 4);
  float4 bv = *(const float4*)(bet + lane * 4);
  for (int r = 0; r < 4; ++r) {
    int l = l0 + w * 4 + r;
    float4 v = *(const float4*)(g_x + ((long)b * LL + l) * HD + lane * 4);
    float s1 = v.x + v.y + v.z + v.w;
    float s2 = v.x * v.x + v.y * v.y + v.z * v.z + v.w * v.w;
    #pragma unroll
    for (int off = 32; off; off >>= 1) { s1 += __shfl_xor(s1, off); s2 += __shfl_xor(s2, off); }
    float mu = s1 * (1.0f / HD);
    float var = s2 * (1.0f / HD) - mu * mu;
    float rs = rsqrtf(var + 1e-5f);
    int rr = w * 4 + r;
    S[rr][lane * 4 + 0] = (v.x - mu) * rs * gv.x + bv.x;
    S[rr][lane * 4 + 1] = (v.y - mu) * rs * gv.y + bv.y;
    S[rr][lane * 4 + 2] = (v.z - mu) * rs * gv.z + bv.z;
    S[rr][lane * 4 + 3] = (v.w - mu) * rs * gv.w + bv.w;
  }
  __syncthreads();
  ushort4 o[4];
  #pragma unroll
  for (int q = 0; q < 4; ++q) {
    o[q].x = f2bf(S[q * 4 + 0][tid]); o[q].y = f2bf(S[q * 4 + 1][tid]);
    o[q].z = f2bf(S[q * 4 + 2][tid]); o[q].w = f2bf(S[q * 4 + 3][tid]);
  }
  unsigned short* zp = g_zbh + ((long)b * HD + tid) * LL + l0;
  #pragma unroll
  for (int q = 0; q < 4; ++q) *(ushort4*)(zp + q * 4) = o[q];
}

// ---------- Phase A (MFMA): S_end[job][p] = sum_t z[job][t] TA[t][p] ----------
__global__ __launch_bounds__(256) void k_phaseA(int layer) {
  __shared__ __attribute__((aligned(16))) unsigned short Ts[64 * 72];
  const int tid = threadIdx.x, wave = tid >> 6, lane = tid & 63;
  const int h = blockIdx.x;
  const long lh = (long)layer * HD + h;
  const unsigned short* Tg = g_TAt + lh * 4096;
  #pragma unroll
  for (int i = 0; i < 2; ++i) {
    int seg = tid + i * 256;            // 512 segs: row = seg>>3, sc = (seg&7)*8
    int row = seg >> 3, sc = (seg & 7) * 8;
    *(ulonglong2*)&Ts[row * 72 + sc] = *(const ulonglong2*)(Tg + row * 64 + sc);
  }
  __syncthreads();
  const int n15 = lane & 15, kg = lane >> 4;
  bf16x8 bf[4][2];
  #pragma unroll
  for (int j = 0; j < 4; ++j)
    #pragma unroll
    for (int kk = 0; kk < 2; ++kk)
      bf[j][kk] = *(const bf16x8*)&Ts[(j * 16 + n15) * 72 + kk * 32 + kg * 8];
  const int jobbase = blockIdx.y * 256 + wave * 64;
  #pragma unroll
  for (int mt = 0; mt < 4; ++mt) {
    int job = jobbase + mt * 16 + n15;
    int b = job >> 5, c = job & 31;
    const unsigned short* zp = g_zbh + ((long)(b * HD + h)) * LL + c * 64;
    bf16x8 a0 = *(const bf16x8*)(zp + kg * 8);
    bf16x8 a1 = *(const bf16x8*)(zp + 32 + kg * 8);
    f32x4 acc[4];
    #pragma unroll
    for (int j = 0; j < 4; ++j) {
      acc[j] = (f32x4){0.f, 0.f, 0.f, 0.f};
      acc[j] = __builtin_amdgcn_mfma_f32_16x16x32_bf16(a0, bf[j][0], acc[j], 0, 0, 0);
      acc[j] = __builtin_amdgcn_mfma_f32_16x16x32_bf16(a1, bf[j][1], acc[j], 0, 0, 0);
    }
    #pragma unroll
    for (int j = 0; j < 4; ++j)
      #pragma unroll
      for (int r = 0; r < 4; ++r) {
        int jobd = jobbase + mt * 16 + kg * 4 + r;
        g_Se[((long)jobd * HD + h) * 64 + j * 16 + n15] = acc[j][r];
      }
  }
}

// ---------- Phase B: fp32 scan over chunks, emit G bf16 ----------
__global__ void k_phaseB(int layer) {
  int id = blockIdx.x * 256 + threadIdx.x;     // B*H*N = 131072
  int n = id & 31, h = (id >> 5) & 255, b = id >> 13;
  long vb = ((long)(layer * HD + h) * NS + n) * 65;
  float wtr = g_Vt[vb * 2 + 128], wti = g_Vt[vb * 2 + 129];   // w^64
  long eb = ((long)(layer * HD + h) * NS + n) * 2;
  float e0r = g_E0[eb], e0i = g_E0[eb + 1];
  float sr = 0.f, si = 0.f;
  for (int c = 0; c < CC; ++c) {
    long job = b * CC + c;
    const float* p = g_Se + (job * HD + h) * 64 + n * 2;
    float er = p[0], ei = p[1];
    unsigned short* gp = g_Gb + (job * HD + h) * 64 + n * 2;
    gp[0] = f2bf(e0r * sr - e0i * si);          // G = E0 * S_prev
    gp[1] = f2bf(e0r * si + e0i * sr);
    float nr = er + wtr * sr - wti * si;        // S_prev' = S_end + w^64 * S_prev
    si      = ei + wtr * si + wti * sr;
    sr = nr;
  }
}

// ---------- Phase C (MFMA): Y[job][t] = [z|G][job][k] . Mt[t][k], gelu -> y bf16 ----------
__global__ __launch_bounds__(256) void k_phaseC(int layer) {
  __shared__ __attribute__((aligned(16))) unsigned short Ms[64 * 136];
  const int tid = threadIdx.x, wave = tid >> 6, lane = tid & 63;
  const int h = blockIdx.x;
  const long lh = (long)layer * HD + h;
  const unsigned short* Mg = g_Mt + lh * 8192;
  #pragma unroll
  for (int i = 0; i < 4; ++i) {
    int seg = tid + i * 256;            // 1024 segs: row = seg>>4, sc = (seg&15)*8
    int row = seg >> 4, sc = (seg & 15) * 8;
    *(ulonglong2*)&Ms[row * 136 + sc] = *(const ulonglong2*)(Mg + row * 128 + sc);
  }
  __syncthreads();
  const int n15 = lane & 15, kg = lane >> 4;
  bf16x8 bf[4][4];
  #pragma unroll
  for (int j = 0; j < 4; ++j)
    #pragma unroll
    for (int kk = 0; kk < 4; ++kk)
      bf[j][kk] = *(const bf16x8*)&Ms[(j * 16 + n15) * 136 + kk * 32 + kg * 8];
  const int jobbase = blockIdx.y * 256 + wave * 64;
  #pragma unroll
  for (int mt = 0; mt < 4; ++mt) {
    int job = jobbase + mt * 16 + n15;
    int b = job >> 5, c = job & 31;
    const unsigned short* zp = g_zbh + ((long)(b * HD + h)) * LL + c * 64;
    const unsigned short* gp = g_Gb + ((long)job * HD + h) * 64;
    bf16x8 a0 = *(const bf16x8*)(zp + kg * 8);
    bf16x8 a1 = *(const bf16x8*)(zp + 32 + kg * 8);
    bf16x8 a2 = *(const bf16x8*)(gp + kg * 8);
    bf16x8 a3 = *(const bf16x8*)(gp + 32 + kg * 8);
    f32x4 acc[4];
    #pragma unroll
    for (int j = 0; j < 4; ++j) {
      acc[j] = (f32x4){0.f, 0.f, 0.f, 0.f};
      acc[j] = __builtin_amdgcn_mfma_f32_16x16x32_bf16(a0, bf[j][0], acc[j], 0, 0, 0);
      acc[j] = __builtin_amdgcn_mfma_f32_16x16x32_bf16(a1, bf[j][1], acc[j], 0, 0, 0);
      acc[j] = __builtin_amdgcn_mfma_f32_16x16x32_bf16(a2, bf[j][2], acc[j], 0, 0, 0);
      acc[j] = __builtin_amdgcn_mfma_f32_16x16x32_bf16(a3, bf[j][3], acc[j], 0, 0, 0);
    }
    #pragma unroll
    for (int j = 0; j < 4; ++j)
      #pragma unroll
      for (int r = 0; r < 4; ++r) {
        int jobd = jobbase + mt * 16 + kg * 4 + r;
        int bd = jobd >> 5, cd = jobd & 31;
        g_ybh[((long)(bd * HD + h)) * LL + cd * 64 + j * 16 + n15] = f2bf(geluf(acc[j][r]));
      }
  }
}

// ---------- transpose y: [B][H][L] bf16 -> [B][L][H] bf16 ----------
__global__ __launch_bounds__(256) void k_transp() {
  __shared__ unsigned short T[64][65];
  int bid = blockIdx.x;
  int ht = bid & 3, lt = (bid >> 2) & 31, b = bid >> 7;
  int t = threadIdx.x;
  int r = t >> 4, c = t & 15;
  #pragma unroll
  for (int i = 0; i < 4; ++i) {
    int hh = r + i * 16;
    ushort4 v = *(const ushort4*)(g_ybh + ((long)(b * 256 + ht * 64 + hh)) * 2048 + lt * 64 + c * 4);
    T[hh][c * 4 + 0] = v.x; T[hh][c * 4 + 1] = v.y;
    T[hh][c * 4 + 2] = v.z; T[hh][c * 4 + 3] = v.w;
  }
  __syncthreads();
  #pragma unroll
  for (int i = 0; i < 4; ++i) {
    int ll = r + i * 16;
    ushort4 o;
    o.x = T[c * 4 + 0][ll]; o.y = T[c * 4 + 1][ll];
    o.z = T[c * 4 + 2][ll]; o.w = T[c * 4 + 3][ll];
    *(ushort4*)(g_yt + ((long)(b * 2048 + lt * 64 + ll)) * 256 + ht * 64 + c * 4) = o;
  }
}

// ---------- bf16 MFMA GEMM + fused GLU + residual ----------
__global__ __launch_bounds__(256) void k_gemmglu(int layer, const float* __restrict__ bias) {
  __shared__ __attribute__((aligned(16))) unsigned short As[128 * 32];
  __shared__ __attribute__((aligned(16))) unsigned short Bs[256 * 32];
  const int tid = threadIdx.x;
  const int wave = tid >> 6, lane = tid & 63;
  const int m0 = blockIdx.x * 128;
  const int gg = blockIdx.y;
  const int wm = wave & 1, wn = wave >> 1;
  const unsigned short* Ag = g_yt + (long)m0 * 256;
  const unsigned short* Wt = g_Wt + (long)layer * 131072;
  f32x4 acc[4][8];
  #pragma unroll
  for (int a = 0; a < 4; ++a)
    #pragma unroll
    for (int b2 = 0; b2 < 8; ++b2) acc[a][b2] = (f32x4){0.f, 0.f, 0.f, 0.f};
  for (int k0 = 0; k0 < 256; k0 += 32) {
    __syncthreads();
    #pragma unroll
    for (int it = 0; it < 2; ++it) {
      int slot = it * 256 + wave * 64 + lane;
      int m = slot >> 2, ko = (slot & 3) * 8;
      __builtin_amdgcn_global_load_lds(
        (const __attribute__((address_space(1))) unsigned int*)(Ag + (long)m * 256 + k0 + ko),
        (__attribute__((address_space(3))) unsigned int*)(As + (it * 256 + wave * 64) * 8),
        16, 0, 0);
    }
    #pragma unroll
    for (int it = 0; it < 4; ++it) {
      int slot = it * 256 + wave * 64 + lane;
      int np = slot >> 2, ko = (slot & 3) * 8;
      int n = gg * 128 + (np < 128 ? np : np + 128);
      __builtin_amdgcn_global_load_lds(
        (const __attribute__((address_space(1))) unsigned int*)(Wt + (long)n * 256 + k0 + ko),
        (__attribute__((address_space(3))) unsigned int*)(Bs + (it * 256 + wave * 64) * 8),
        16, 0, 0);
    }
    __syncthreads();
    bf16x8 af[4], bfa[4], bfg[4];
    const int q2 = (lane >> 4) * 8;
    #pragma unroll
    for (int mt = 0; mt < 4; ++mt)
      af[mt] = *(const bf16x8*)&As[(wm * 64 + mt * 16 + (lane & 15)) * 32 + q2];
    #pragma unroll
    for (int j = 0; j < 4; ++j)
      bfa[j] = *(const bf16x8*)&Bs[(wn * 64 + j * 16 + (lane & 15)) * 32 + q2];
    #pragma unroll
    for (int j = 0; j < 4; ++j)
      bfg[j] = *(const bf16x8*)&Bs[(128 + wn * 64 + j * 16 + (lane & 15)) * 32 + q2];
    #pragma unroll
    for (int mt = 0; mt < 4; ++mt)
      #pragma unroll
      for (int j = 0; j < 4; ++j) {
        acc[mt][j]     = __builtin_amdgcn_mfma_f32_16x16x32_bf16(af[mt], bfa[j], acc[mt][j], 0, 0, 0);
        acc[mt][4 + j] = __builtin_amdgcn_mfma_f32_16x16x32_bf16(af[mt], bfg[j], acc[mt][4 + j], 0, 0, 0);
      }
  }
  #pragma unroll
  for (int j = 0; j < 4; ++j) {
    int col = gg * 128 + wn * 64 + j * 16 + (lane & 15);
    float ba = bias[col], bg = bias[col + 256];
    #pragma unroll
    for (int mt = 0; mt < 4; ++mt) {
      #pragma unroll
      for (int r = 0; r < 4; ++r) {
        int row = m0 + wm * 64 + mt * 16 + (lane >> 4) * 4 + r;
        float a = acc[mt][j][r] + ba;
        float g = acc[mt][4 + j][r] + bg;
        float* xp = g_x + (long)row * 256 + col;
        *xp += a * sigf(g);
      }
    }
  }
}

// ---------- final LN + partial pool ----------
__global__ __launch_bounds__(256) void k_lnpool(const float* __restrict__ gam,
                                                const float* __restrict__ bet) {
  __shared__ float red[4][256];
  const int bid = blockIdx.x;
  const int b = bid >> 4, s = bid & 15;
  const int tid = threadIdx.x, w = tid >> 6, lane = tid & 63;
  float4 gv = *(const float4*)(gam + lane * 4);
  float4 bv = *(const float4*)(bet + lane * 4);
  float a0 = 0, a1 = 0, a2 = 0, a3 = 0;
  for (int r = 0; r < 32; ++r) {
    int l = s * 128 + w * 32 + r;
    float4 v = *(const float4*)(g_x + ((long)b * LL + l) * HD + lane * 4);
    float s1 = v.x + v.y + v.z + v.w;
    float s2 = v.x * v.x + v.y * v.y + v.z * v.z + v.w * v.w;
    #pragma unroll
    for (int off = 32; off; off >>= 1) { s1 += __shfl_xor(s1, off); s2 += __shfl_xor(s2, off); }
    float mu = s1 * (1.0f / HD);
    float rs = rsqrtf(s2 * (1.0f / HD) - mu * mu + 1e-5f);
    a0 += (v.x - mu) * rs * gv.x + bv.x;
    a1 += (v.y - mu) * rs * gv.y + bv.y;
    a2 += (v.z - mu) * rs * gv.z + bv.z;
    a3 += (v.w - mu) * rs * gv.w + bv.w;
  }
  red[w][lane * 4 + 0] = a0; red[w][lane * 4 + 1] = a1;
  red[w][lane * 4 + 2] = a2; red[w][lane * 4 + 3] = a3;
  __syncthreads();
  g_pp[(long)bid * HD + tid] = red[0][tid] + red[1][tid] + red[2][tid] + red[3][tid];
}

// ---------- classifier ----------
__global__ __launch_bounds__(256) void k_cls(const float* __restrict__ Wc,
                                             const float* __restrict__ bc,
                                             float* __restrict__ out) {
  __shared__ float pl[256];
  const int b = blockIdx.x, tid = threadIdx.x;
  float p = 0.f;
  #pragma unroll
  for (int s = 0; s < 16; ++s) p += g_pp[((long)b * 16 + s) * HD + tid];
  pl[tid] = p * (1.0f / LL);
  __syncthreads();
  if (tid < NCLS) {
    float acc = bc[tid];
    for (int h = 0; h < HD; ++h) acc += pl[h] * Wc[h * NCLS + tid];
    out[b * NCLS + tid] = acc;
  }
}

extern "C" void kernel_launch(void* const* d_in, const int* in_sizes, int n_in,
                              void* d_out, int out_size, void* d_ws, size_t ws_size,
                              hipStream_t stream) {
  (void)in_sizes; (void)n_in; (void)d_ws; (void)ws_size; (void)out_size;
  const float* x_in   = (const float*)d_in[0];
  const float* W_in   = (const float*)d_in[1];
  const float* b_in   = (const float*)d_in[2];
  const float* log_dt = (const float*)d_in[3];
  const float* A_re   = (const float*)d_in[4];
  const float* A_im   = (const float*)d_in[5];
  const float* B_re   = (const float*)d_in[6];
  const float* B_im   = (const float*)d_in[7];
  const float* C_re   = (const float*)d_in[8];
  const float* C_im   = (const float*)d_in[9];
  const float* Dd     = (const float*)d_in[10];
  const float* W_out  = (const float*)d_in[11];
  const float* b_out  = (const float*)d_in[12];
  const float* ln_s   = (const float*)d_in[13];
  const float* ln_b   = (const float*)d_in[14];
  const float* lnf_s  = (const float*)d_in[15];
  const float* lnf_b  = (const float*)d_in[16];
  const float* W_cls  = (const float*)d_in[17];
  const float* b_cl   = (const float*)d_in[18];
  float* out = (float*)d_out;

  k_precomp<<<192, 256, 0, stream>>>(log_dt, A_re, A_im, B_re, B_im, C_re, C_im);
  k_precompK<<<384, 256, 0, stream>>>();
  k_precompM<<<49152, 256, 0, stream>>>(Dd);
  k_precompA2<<<24576, 256, 0, stream>>>();
  k_prepW<<<768, 256, 0, stream>>>(W_out);
  k_gemmin<<<dim3(256, 2), 256, 0, stream>>>(x_in, W_in, b_in);
  for (int i = 0; i < NLAYERS; ++i) {
    k_ln<<<2048, 256, 0, stream>>>(ln_s + i * HD, ln_b + i * HD);
    k_phaseA<<<dim3(256, 2), 256, 0, stream>>>(i);
    k_phaseB<<<512, 256, 0, stream>>>(i);
    k_phaseC<<<dim3(256, 2), 256, 0, stream>>>(i);
    k_transp<<<2048, 256, 0, stream>>>();
    k_gemmglu<<<dim3(256, 2), 256, 0, stream>>>(i, b_out + i * 2 * HD);
  }
  k_lnpool<<<256, 256, 0, stream>>>(lnf_s, lnf_b);
  k_cls<<<16, 256, 0, stream>>>(W_cls, b_cl, out);
}

// Round 5
// 785.469 us; speedup vs baseline: 4.1991x; 1.0532x over previous
//
#include <hip/hip_runtime.h>
#include <math.h>

#define NLAYERS 6
#define HD 256
#define NS 32
#define NCLS 50
#define BB 16
#define LL 2048
#define TT 64
#define CC 32

typedef __attribute__((ext_vector_type(8))) short bf16x8;
typedef __attribute__((ext_vector_type(4))) float f32x4;

// ---- static device workspaces ----
__device__ __attribute__((aligned(16))) float g_x [8388608];   // [B][L][H] residual stream (fp32)
__device__ __attribute__((aligned(16))) float g_Vt[6389760];   // [l][h][n][65][2] : w^t, t=0..64
__device__ __attribute__((aligned(16))) float g_Kt[98304];     // [l][h][64] kernel taps
__device__ __attribute__((aligned(16))) float g_E0[98304];     // [l][h][n][2] : C*dB
__device__ __attribute__((aligned(16))) float g_pp[65536];     // [B][16][H] pool partials
__device__ __attribute__((aligned(16))) unsigned short g_zbh[8388608]; // z bf16 [B][H][L]
__device__ __attribute__((aligned(16))) unsigned short g_Mt [12582912];// [l][h][t=64][k=128] bf16 (TK;TC)^T, D folded
__device__ __attribute__((aligned(16))) unsigned short g_TAt[6291456]; // [l][h][p=64][t=64] bf16 TA^T
__device__ __attribute__((aligned(16))) unsigned short g_ybh[8388608]; // y bf16 [B][H][L]
__device__ __attribute__((aligned(16))) unsigned short g_yt [8388608]; // y bf16 [B][L][H]
__device__ __attribute__((aligned(16))) unsigned short g_Wt [786432];  // Wt bf16 [l][n=512][k=256]
__device__ __attribute__((aligned(16))) unsigned short g_xb [4194304]; // x_in bf16 [32768][128]
__device__ __attribute__((aligned(16))) unsigned short g_Wint[32768];  // W_in^T bf16 [n=256][k=128]

__device__ __forceinline__ float sigf(float x) { return 1.0f / (1.0f + __expf(-x)); }
__device__ __forceinline__ float geluf(float x) {
  float t = 0.7978845608028654f * (x + 0.044715f * x * x * x);
  float e = __expf(2.0f * t);
  float th = 1.0f - 2.0f / (e + 1.0f);
  return 0.5f * x * (1.0f + th);
}
__device__ __forceinline__ unsigned short f2bf(float f) {
  unsigned u = __float_as_uint(f);
  unsigned r = (u + 0x7FFFu + ((u >> 16) & 1u)) >> 16;
  return (unsigned short)r;
}

// ---------- precompute: w, E0 = C*dB, power table w^t ----------
__global__ void k_precomp(const float* __restrict__ log_dt,
                          const float* __restrict__ A_re, const float* __restrict__ A_im,
                          const float* __restrict__ B_re, const float* __restrict__ B_im,
                          const float* __restrict__ C_re, const float* __restrict__ C_im) {
  int id = blockIdx.x * 256 + threadIdx.x;
  if (id >= NLAYERS * HD * NS) return;
  int h = (id / NS) % HD;
  int i = id / (NS * HD);
  float dt = expf(log_dt[i * HD + h]);
  float ar = A_re[id], ai = A_im[id];
  float dr = dt * ar, di = dt * ai;
  float er = expf(dr);
  float wr = er * cosf(di), wi = er * sinf(di);
  float inv = 1.0f / (ar * ar + ai * ai);
  float mr = wr - 1.0f, mi = wi;
  float qr = (mr * ar + mi * ai) * inv;
  float qi = (mi * ar - mr * ai) * inv;
  float br = B_re[id], bi = B_im[id];
  float dbr = br * qr - bi * qi, dbi = br * qi + bi * qr;
  float cr = C_re[id], ci = C_im[id];
  g_E0[id * 2 + 0] = cr * dbr - ci * dbi;
  g_E0[id * 2 + 1] = cr * dbi + ci * dbr;
  float pr = 1.0f, pi = 0.0f;
  long base = (long)id * 65;
  for (int t = 0; t <= 64; ++t) {
    g_Vt[(base + t) * 2 + 0] = pr;
    g_Vt[(base + t) * 2 + 1] = pi;
    float nr = pr * wr - pi * wi;
    pi = pr * wi + pi * wr;
    pr = nr;
  }
}

__global__ void k_precompK() {
  int id = blockIdx.x * 256 + threadIdx.x;
  if (id >= NLAYERS * HD * TT) return;
  int t = id % TT;
  int lh = id / TT;
  float acc = 0.f;
  const float* e = g_E0 + (long)lh * NS * 2;
  const float* v = g_Vt + ((long)lh * NS * 65 + t) * 2;
  for (int n = 0; n < NS; ++n)
    acc += e[n * 2] * v[n * 130] - e[n * 2 + 1] * v[n * 130 + 1];
  g_Kt[id] = 2.0f * acc;
}

// Mt[l][h][t][k] bf16: k<64 -> TK[s=k][t] (+D at k==t); k>=64 -> TC[p=k-64][t]
__global__ void k_precompM(const float* __restrict__ Dd) {
  int id = blockIdx.x * 256 + threadIdx.x;     // 12582912
  int k = id & 127;
  int t = (id >> 7) & 63;
  int lh = id >> 13;
  float v;
  if (k < 64) {
    v = (t >= k) ? g_Kt[(long)lh * 64 + (t - k)] : 0.f;
    if (k == t) v += Dd[lh];
  } else {
    int p = k - 64, n = p >> 1;
    const float2 w = ((const float2*)g_Vt)[((long)lh * NS + n) * 65 + (t + 1)];
    v = (p & 1) ? (-2.f * w.y) : (2.f * w.x);
  }
  g_Mt[id] = f2bf(v);
}

// TAt[l][h][p][t] = TA[t][p] bf16
__global__ void k_precompA2() {
  int id = blockIdx.x * 256 + threadIdx.x;     // 6291456
  int t = id & 63;
  int p = (id >> 6) & 63;
  int lh = id >> 12;
  int n = p >> 1;
  const float2 w = ((const float2*)g_Vt)[((long)lh * NS + n) * 65 + (63 - t)];
  g_TAt[id] = f2bf((p & 1) ? w.y : w.x);
}

// ---------- W_out -> Wt bf16 [l][n][k] ----------
__global__ __launch_bounds__(256) void k_prepW(const float* __restrict__ W_out) {
  __shared__ float T[32][33];
  int bid = blockIdx.x;
  int nt = bid & 15, kt = (bid >> 4) & 7, l = bid >> 7;
  int t = threadIdx.x;
  int tr = t >> 3, tc = t & 7;
  const float* src = W_out + (long)l * 131072 + (long)(kt * 32) * 512 + nt * 32;
  float4 v = *(const float4*)(src + (long)tr * 512 + tc * 4);
  T[tr][tc * 4 + 0] = v.x; T[tr][tc * 4 + 1] = v.y;
  T[tr][tc * 4 + 2] = v.z; T[tr][tc * 4 + 3] = v.w;
  __syncthreads();
  ushort4 o;
  o.x = f2bf(T[tc * 4 + 0][tr]); o.y = f2bf(T[tc * 4 + 1][tr]);
  o.z = f2bf(T[tc * 4 + 2][tr]); o.w = f2bf(T[tc * 4 + 3][tr]);
  *(ushort4*)(g_Wt + ((long)l * 512 + nt * 32 + tr) * 256 + kt * 32 + tc * 4) = o;
}

// ---------- W_in [k=128][n=256] -> Wint bf16 [n][k] ----------
__global__ void k_prepWin(const float* __restrict__ W_in) {
  int k = blockIdx.x, n = threadIdx.x;
  g_Wint[n * 128 + k] = f2bf(W_in[k * 256 + n]);
}

// ---------- x_in fp32 -> bf16 ----------
__global__ void k_castin(const float* __restrict__ xin) {
  long base = ((long)blockIdx.x * 256 + threadIdx.x) * 8;
  float4 v0 = *(const float4*)(xin + base);
  float4 v1 = *(const float4*)(xin + base + 4);
  union { unsigned short u[8]; ulonglong2 v; } pk;
  pk.u[0] = f2bf(v0.x); pk.u[1] = f2bf(v0.y); pk.u[2] = f2bf(v0.z); pk.u[3] = f2bf(v0.w);
  pk.u[4] = f2bf(v1.x); pk.u[5] = f2bf(v1.y); pk.u[6] = f2bf(v1.z); pk.u[7] = f2bf(v1.w);
  *(ulonglong2*)(g_xb + base) = pk.v;
}

// ---------- input GEMM (bf16 MFMA): g_x[32768,256] = xb[32768,128]*Wint^T + b ----------
__global__ __launch_bounds__(256) void k_gemmin(const float* __restrict__ bias) {
  __shared__ __attribute__((aligned(16))) unsigned short As[128 * 32];
  __shared__ __attribute__((aligned(16))) unsigned short Bs[256 * 32];
  const int tid = threadIdx.x;
  const int wave = tid >> 6, lane = tid & 63;
  const int m0 = blockIdx.x * 128;
  const int wm = wave & 1, wn = wave >> 1;
  const int n15 = lane & 15, kg = lane >> 4, q2 = kg * 8;
  f32x4 acc[4][8];
  #pragma unroll
  for (int a = 0; a < 4; ++a)
    #pragma unroll
    for (int b2 = 0; b2 < 8; ++b2) acc[a][b2] = (f32x4){0.f, 0.f, 0.f, 0.f};
  for (int k0 = 0; k0 < 128; k0 += 32) {
    __syncthreads();
    #pragma unroll
    for (int it = 0; it < 2; ++it) {
      int slot = it * 256 + wave * 64 + lane;
      int m = slot >> 2, ko = (slot & 3) * 8;
      __builtin_amdgcn_global_load_lds(
        (const __attribute__((address_space(1))) unsigned int*)(g_xb + (long)(m0 + m) * 128 + k0 + ko),
        (__attribute__((address_space(3))) unsigned int*)(As + (it * 256 + wave * 64) * 8),
        16, 0, 0);
    }
    #pragma unroll
    for (int it = 0; it < 4; ++it) {
      int slot = it * 256 + wave * 64 + lane;
      int n = slot >> 2, ko = (slot & 3) * 8;
      __builtin_amdgcn_global_load_lds(
        (const __attribute__((address_space(1))) unsigned int*)(g_Wint + (long)n * 128 + k0 + ko),
        (__attribute__((address_space(3))) unsigned int*)(Bs + (it * 256 + wave * 64) * 8),
        16, 0, 0);
    }
    __syncthreads();
    bf16x8 af[4], bn[8];
    #pragma unroll
    for (int mt = 0; mt < 4; ++mt)
      af[mt] = *(const bf16x8*)&As[(wm * 64 + mt * 16 + n15) * 32 + q2];
    #pragma unroll
    for (int j = 0; j < 8; ++j)
      bn[j] = *(const bf16x8*)&Bs[(wn * 128 + j * 16 + n15) * 32 + q2];
    #pragma unroll
    for (int mt = 0; mt < 4; ++mt)
      #pragma unroll
      for (int j = 0; j < 8; ++j)
        acc[mt][j] = __builtin_amdgcn_mfma_f32_16x16x32_bf16(af[mt], bn[j], acc[mt][j], 0, 0, 0);
  }
  #pragma unroll
  for (int j = 0; j < 8; ++j) {
    int col = wn * 128 + j * 16 + n15;
    float bb = bias[col];
    #pragma unroll
    for (int mt = 0; mt < 4; ++mt)
      #pragma unroll
      for (int r = 0; r < 4; ++r) {
        int row = m0 + wm * 64 + mt * 16 + kg * 4 + r;
        g_x[(long)row * 256 + col] = acc[mt][j][r] + bb;
      }
  }
}

// ---------- LayerNorm over H -> z bf16 [B][H][L]; block owns 64 consecutive L ----------
__global__ __launch_bounds__(256) void k_ln(const float* __restrict__ gam,
                                            const float* __restrict__ bet) {
  __shared__ unsigned short S[64 * 264];       // [ll][h], pad 264
  const int bid = blockIdx.x;                  // 512: b = bid>>5, l0 = (bid&31)*64
  const int b = bid >> 5, l0 = (bid & 31) << 6;
  const int tid = threadIdx.x, w = tid >> 6, lane = tid & 63;
  float4 gv = *(const float4*)(gam + lane * 4);
  float4 bv = *(const float4*)(bet + lane * 4);
  for (int r = 0; r < 16; ++r) {
    int ll = w * 16 + r;
    float4 v = *(const float4*)(g_x + ((long)(b * LL + l0 + ll)) * HD + lane * 4);
    float s1 = v.x + v.y + v.z + v.w;
    float s2 = v.x * v.x + v.y * v.y + v.z * v.z + v.w * v.w;
    #pragma unroll
    for (int off = 32; off; off >>= 1) { s1 += __shfl_xor(s1, off); s2 += __shfl_xor(s2, off); }
    float mu = s1 * (1.0f / HD);
    float rs = rsqrtf(s2 * (1.0f / HD) - mu * mu + 1e-5f);
    ushort4 o;
    o.x = f2bf((v.x - mu) * rs * gv.x + bv.x);
    o.y = f2bf((v.y - mu) * rs * gv.y + bv.y);
    o.z = f2bf((v.z - mu) * rs * gv.z + bv.z);
    o.w = f2bf((v.w - mu) * rs * gv.w + bv.w);
    *(ushort4*)&S[ll * 264 + lane * 4] = o;
  }
  __syncthreads();
  unsigned short* zp = g_zbh + ((long)(b * HD + tid)) * LL + l0;   // full 128B line per thread
  #pragma unroll
  for (int seg = 0; seg < 8; ++seg) {
    union { unsigned short u[8]; ulonglong2 v; } pk;
    #pragma unroll
    for (int i = 0; i < 8; ++i) pk.u[i] = S[(seg * 8 + i) * 264 + tid];
    *(ulonglong2*)(zp + seg * 8) = pk.v;
  }
}

// ---------- fused SSM: phaseA (MFMA) + chunk scan + phaseC (MFMA), one block per (b,h) ----------
__global__ __launch_bounds__(256) void k_ssm(int layer) {
  __shared__ __attribute__((aligned(16))) unsigned short Zs[32 * 72];   // z [c][t]
  __shared__ __attribute__((aligned(16))) unsigned short Ts[64 * 72];   // TA^T [p][t]
  __shared__ __attribute__((aligned(16))) unsigned short Ms[64 * 136];  // Mt [t][k]
  __shared__ float Ss[32 * 68];                                          // S_end [c][p]
  __shared__ __attribute__((aligned(16))) unsigned short Gs[32 * 72];   // G [c][p]
  const int tid = threadIdx.x, wave = tid >> 6, lane = tid & 63;
  const int h = blockIdx.x >> 4, b = blockIdx.x & 15;   // same-h blocks adjacent (L2 table reuse)
  const long lh = (long)layer * HD + h;
  // stage z row (2048 bf16)
  {
    int c = tid >> 3, off = (tid & 7) * 8;
    *(ulonglong2*)&Zs[c * 72 + off] =
        *(const ulonglong2*)(g_zbh + ((long)(b * HD + h)) * LL + c * 64 + off);
  }
  // stage TA^T (64x64) and Mt (64x128)
  const unsigned short* Tg = g_TAt + lh * 4096;
  #pragma unroll
  for (int i = 0; i < 2; ++i) {
    int seg = tid + i * 256;
    int row = seg >> 3, sc = (seg & 7) * 8;
    *(ulonglong2*)&Ts[row * 72 + sc] = *(const ulonglong2*)(Tg + row * 64 + sc);
  }
  const unsigned short* Mg = g_Mt + lh * 8192;
  #pragma unroll
  for (int i = 0; i < 4; ++i) {
    int seg = tid + i * 256;
    int row = seg >> 4, sc = (seg & 15) * 8;
    *(ulonglong2*)&Ms[row * 136 + sc] = *(const ulonglong2*)(Mg + row * 128 + sc);
  }
  __syncthreads();
  const int n15 = lane & 15, kg = lane >> 4;
  const int mt = wave & 1;            // c-tile (16 rows)
  const int jb = (wave >> 1) * 2;     // 2 n-tiles per wave
  const int c = mt * 16 + n15;
  // phase A: S_end[c][p] = sum_t z[c][t] TA[t][p]
  {
    bf16x8 a0 = *(const bf16x8*)&Zs[c * 72 + kg * 8];
    bf16x8 a1 = *(const bf16x8*)&Zs[c * 72 + 32 + kg * 8];
    #pragma unroll
    for (int jj = 0; jj < 2; ++jj) {
      int j = jb + jj;
      bf16x8 b0 = *(const bf16x8*)&Ts[(j * 16 + n15) * 72 + kg * 8];
      bf16x8 b1 = *(const bf16x8*)&Ts[(j * 16 + n15) * 72 + 32 + kg * 8];
      f32x4 acc = (f32x4){0.f, 0.f, 0.f, 0.f};
      acc = __builtin_amdgcn_mfma_f32_16x16x32_bf16(a0, b0, acc, 0, 0, 0);
      acc = __builtin_amdgcn_mfma_f32_16x16x32_bf16(a1, b1, acc, 0, 0, 0);
      #pragma unroll
      for (int r = 0; r < 4; ++r)
        Ss[(mt * 16 + kg * 4 + r) * 68 + j * 16 + n15] = acc[r];
    }
  }
  __syncthreads();
  // chunk scan (wave 0, lanes 0..31): G[c] = E0 * S_prev; S_prev' = S_end + w^64 * S_prev
  if (wave == 0 && lane < 32) {
    int n = lane;
    long vb = (lh * NS + n) * 65;
    float wtr = g_Vt[vb * 2 + 128], wti = g_Vt[vb * 2 + 129];
    float e0r = g_E0[(lh * NS + n) * 2], e0i = g_E0[(lh * NS + n) * 2 + 1];
    float sr = 0.f, si = 0.f;
    for (int cc = 0; cc < CC; ++cc) {
      float er = Ss[cc * 68 + 2 * n], ei = Ss[cc * 68 + 2 * n + 1];
      Gs[cc * 72 + 2 * n]     = f2bf(e0r * sr - e0i * si);
      Gs[cc * 72 + 2 * n + 1] = f2bf(e0r * si + e0i * sr);
      float nr = er + wtr * sr - wti * si;
      si      = ei + wtr * si + wti * sr;
      sr = nr;
    }
  }
  __syncthreads();
  // phase C: Y[c][t] = sum_k [z|G][c][k] Mt[t][k]; gelu -> ybh
  {
    bf16x8 a0 = *(const bf16x8*)&Zs[c * 72 + kg * 8];
    bf16x8 a1 = *(const bf16x8*)&Zs[c * 72 + 32 + kg * 8];
    bf16x8 a2 = *(const bf16x8*)&Gs[c * 72 + kg * 8];
    bf16x8 a3 = *(const bf16x8*)&Gs[c * 72 + 32 + kg * 8];
    unsigned short* yrow = g_ybh + ((long)(b * HD + h)) * LL;
    #pragma unroll
    for (int jj = 0; jj < 2; ++jj) {
      int j = jb + jj;
      const unsigned short* mrow = &Ms[(j * 16 + n15) * 136];
      bf16x8 b0 = *(const bf16x8*)&mrow[kg * 8];
      bf16x8 b1 = *(const bf16x8*)&mrow[32 + kg * 8];
      bf16x8 b2 = *(const bf16x8*)&mrow[64 + kg * 8];
      bf16x8 b3 = *(const bf16x8*)&mrow[96 + kg * 8];
      f32x4 acc = (f32x4){0.f, 0.f, 0.f, 0.f};
      acc = __builtin_amdgcn_mfma_f32_16x16x32_bf16(a0, b0, acc, 0, 0, 0);
      acc = __builtin_amdgcn_mfma_f32_16x16x32_bf16(a1, b1, acc, 0, 0, 0);
      acc = __builtin_amdgcn_mfma_f32_16x16x32_bf16(a2, b2, acc, 0, 0, 0);
      acc = __builtin_amdgcn_mfma_f32_16x16x32_bf16(a3, b3, acc, 0, 0, 0);
      #pragma unroll
      for (int r = 0; r < 4; ++r)
        yrow[(mt * 16 + kg * 4 + r) * 64 + j * 16 + n15] = f2bf(geluf(acc[r]));
    }
  }
}

// ---------- transpose y: [B][H][L] bf16 -> [B][L][H] bf16 ----------
__global__ __launch_bounds__(256) void k_transp() {
  __shared__ unsigned short T[64][65];
  int bid = blockIdx.x;
  int ht = bid & 3, lt = (bid >> 2) & 31, b = bid >> 7;
  int t = threadIdx.x;
  int r = t >> 4, c = t & 15;
  #pragma unroll
  for (int i = 0; i < 4; ++i) {
    int hh = r + i * 16;
    ushort4 v = *(const ushort4*)(g_ybh + ((long)(b * 256 + ht * 64 + hh)) * 2048 + lt * 64 + c * 4);
    T[hh][c * 4 + 0] = v.x; T[hh][c * 4 + 1] = v.y;
    T[hh][c * 4 + 2] = v.z; T[hh][c * 4 + 3] = v.w;
  }
  __syncthreads();
  #pragma unroll
  for (int i = 0; i < 4; ++i) {
    int ll = r + i * 16;
    ushort4 o;
    o.x = T[c * 4 + 0][ll]; o.y = T[c * 4 + 1][ll];
    o.z = T[c * 4 + 2][ll]; o.w = T[c * 4 + 3][ll];
    *(ushort4*)(g_yt + ((long)(b * 2048 + lt * 64 + ll)) * 256 + ht * 64 + c * 4) = o;
  }
}

// ---------- bf16 MFMA GEMM + fused GLU + residual ----------
__global__ __launch_bounds__(256) void k_gemmglu(int layer, const float* __restrict__ bias) {
  __shared__ __attribute__((aligned(16))) unsigned short As[128 * 32];
  __shared__ __attribute__((aligned(16))) unsigned short Bs[256 * 32];
  const int tid = threadIdx.x;
  const int wave = tid >> 6, lane = tid & 63;
  const int m0 = blockIdx.x * 128;
  const int gg = blockIdx.y;
  const int wm = wave & 1, wn = wave >> 1;
  const unsigned short* Ag = g_yt + (long)m0 * 256;
  const unsigned short* Wt = g_Wt + (long)layer * 131072;
  f32x4 acc[4][8];
  #pragma unroll
  for (int a = 0; a < 4; ++a)
    #pragma unroll
    for (int b2 = 0; b2 < 8; ++b2) acc[a][b2] = (f32x4){0.f, 0.f, 0.f, 0.f};
  for (int k0 = 0; k0 < 256; k0 += 32) {
    __syncthreads();
    #pragma unroll
    for (int it = 0; it < 2; ++it) {
      int slot = it * 256 + wave * 64 + lane;
      int m = slot >> 2, ko = (slot & 3) * 8;
      __builtin_amdgcn_global_load_lds(
        (const __attribute__((address_space(1))) unsigned int*)(Ag + (long)m * 256 + k0 + ko),
        (__attribute__((address_space(3))) unsigned int*)(As + (it * 256 + wave * 64) * 8),
        16, 0, 0);
    }
    #pragma unroll
    for (int it = 0; it < 4; ++it) {
      int slot = it * 256 + wave * 64 + lane;
      int np = slot >> 2, ko = (slot & 3) * 8;
      int n = gg * 128 + (np < 128 ? np : np + 128);
      __builtin_amdgcn_global_load_lds(
        (const __attribute__((address_space(1))) unsigned int*)(Wt + (long)n * 256 + k0 + ko),
        (__attribute__((address_space(3))) unsigned int*)(Bs + (it * 256 + wave * 64) * 8),
        16, 0, 0);
    }
    __syncthreads();
    bf16x8 af[4], bfa[4], bfg[4];
    const int q2 = (lane >> 4) * 8;
    #pragma unroll
    for (int mt = 0; mt < 4; ++mt)
      af[mt] = *(const bf16x8*)&As[(wm * 64 + mt * 16 + (lane & 15)) * 32 + q2];
    #pragma unroll
    for (int j = 0; j < 4; ++j)
      bfa[j] = *(const bf16x8*)&Bs[(wn * 64 + j * 16 + (lane & 15)) * 32 + q2];
    #pragma unroll
    for (int j = 0; j < 4; ++j)
      bfg[j] = *(const bf16x8*)&Bs[(128 + wn * 64 + j * 16 + (lane & 15)) * 32 + q2];
    #pragma unroll
    for (int mt = 0; mt < 4; ++mt)
      #pragma unroll
      for (int j = 0; j < 4; ++j) {
        acc[mt][j]     = __builtin_amdgcn_mfma_f32_16x16x32_bf16(af[mt], bfa[j], acc[mt][j], 0, 0, 0);
        acc[mt][4 + j] = __builtin_amdgcn_mfma_f32_16x16x32_bf16(af[mt], bfg[j], acc[mt][4 + j], 0, 0, 0);
      }
  }
  #pragma unroll
  for (int j = 0; j < 4; ++j) {
    int col = gg * 128 + wn * 64 + j * 16 + (lane & 15);
    float ba = bias[col], bg = bias[col + 256];
    #pragma unroll
    for (int mt = 0; mt < 4; ++mt) {
      #pragma unroll
      for (int r = 0; r < 4; ++r) {
        int row = m0 + wm * 64 + mt * 16 + (lane >> 4) * 4 + r;
        float a = acc[mt][j][r] + ba;
        float g = acc[mt][4 + j][r] + bg;
        float* xp = g_x + (long)row * 256 + col;
        *xp += a * sigf(g);
      }
    }
  }
}

// ---------- final LN + partial pool ----------
__global__ __launch_bounds__(256) void k_lnpool(const float* __restrict__ gam,
                                                const float* __restrict__ bet) {
  __shared__ float red[4][256];
  const int bid = blockIdx.x;
  const int b = bid >> 4, s = bid & 15;
  const int tid = threadIdx.x, w = tid >> 6, lane = tid & 63;
  float4 gv = *(const float4*)(gam + lane * 4);
  float4 bv = *(const float4*)(bet + lane * 4);
  float a0 = 0, a1 = 0, a2 = 0, a3 = 0;
  for (int r = 0; r < 32; ++r) {
    int l = s * 128 + w * 32 + r;
    float4 v = *(const float4*)(g_x + ((long)b * LL + l) * HD + lane * 4);
    float s1 = v.x + v.y + v.z + v.w;
    float s2 = v.x * v.x + v.y * v.y + v.z * v.z + v.w * v.w;
    #pragma unroll
    for (int off = 32; off; off >>= 1) { s1 += __shfl_xor(s1, off); s2 += __shfl_xor(s2, off); }
    float mu = s1 * (1.0f / HD);
    float rs = rsqrtf(s2 * (1.0f / HD) - mu * mu + 1e-5f);
    a0 += (v.x - mu) * rs * gv.x + bv.x;
    a1 += (v.y - mu) * rs * gv.y + bv.y;
    a2 += (v.z - mu) * rs * gv.z + bv.z;
    a3 += (v.w - mu) * rs * gv.w + bv.w;
  }
  red[w][lane * 4 + 0] = a0; red[w][lane * 4 + 1] = a1;
  red[w][lane * 4 + 2] = a2; red[w][lane * 4 + 3] = a3;
  __syncthreads();
  g_pp[(long)bid * HD + tid] = red[0][tid] + red[1][tid] + red[2][tid] + red[3][tid];
}

// ---------- classifier ----------
__global__ __launch_bounds__(256) void k_cls(const float* __restrict__ Wc,
                                             const float* __restrict__ bc,
                                             float* __restrict__ out) {
  __shared__ float pl[256];
  const int b = blockIdx.x, tid = threadIdx.x;
  float p = 0.f;
  #pragma unroll
  for (int s = 0; s < 16; ++s) p += g_pp[((long)b * 16 + s) * HD + tid];
  pl[tid] = p * (1.0f / LL);
  __syncthreads();
  if (tid < NCLS) {
    float acc = bc[tid];
    for (int h = 0; h < HD; ++h) acc += pl[h] * Wc[h * NCLS + tid];
    out[b * NCLS + tid] = acc;
  }
}

extern "C" void kernel_launch(void* const* d_in, const int* in_sizes, int n_in,
                              void* d_out, int out_size, void* d_ws, size_t ws_size,
                              hipStream_t stream) {
  (void)in_sizes; (void)n_in; (void)d_ws; (void)ws_size; (void)out_size;
  const float* x_in   = (const float*)d_in[0];
  const float* W_in   = (const float*)d_in[1];
  const float* b_in   = (const float*)d_in[2];
  const float* log_dt = (const float*)d_in[3];
  const float* A_re   = (const float*)d_in[4];
  const float* A_im   = (const float*)d_in[5];
  const float* B_re   = (const float*)d_in[6];
  const float* B_im   = (const float*)d_in[7];
  const float* C_re   = (const float*)d_in[8];
  const float* C_im   = (const float*)d_in[9];
  const float* Dd     = (const float*)d_in[10];
  const float* W_out  = (const float*)d_in[11];
  const float* b_out  = (const float*)d_in[12];
  const float* ln_s   = (const float*)d_in[13];
  const float* ln_b   = (const float*)d_in[14];
  const float* lnf_s  = (const float*)d_in[15];
  const float* lnf_b  = (const float*)d_in[16];
  const float* W_cls  = (const float*)d_in[17];
  const float* b_cl   = (const float*)d_in[18];
  float* out = (float*)d_out;

  k_precomp<<<192, 256, 0, stream>>>(log_dt, A_re, A_im, B_re, B_im, C_re, C_im);
  k_precompK<<<384, 256, 0, stream>>>();
  k_precompM<<<49152, 256, 0, stream>>>(Dd);
  k_precompA2<<<24576, 256, 0, stream>>>();
  k_prepW<<<768, 256, 0, stream>>>(W_out);
  k_prepWin<<<128, 256, 0, stream>>>(W_in);
  k_castin<<<2048, 256, 0, stream>>>(x_in);
  k_gemmin<<<256, 256, 0, stream>>>(b_in);
  for (int i = 0; i < NLAYERS; ++i) {
    k_ln<<<512, 256, 0, stream>>>(ln_s + i * HD, ln_b + i * HD);
    k_ssm<<<4096, 256, 0, stream>>>(i);
    k_transp<<<2048, 256, 0, stream>>>();
    k_gemmglu<<<dim3(256, 2), 256, 0, stream>>>(i, b_out + i * 2 * HD);
  }
  k_lnpool<<<256, 256, 0, stream>>>(lnf_s, lnf_b);
  k_cls<<<16, 256, 0, stream>>>(W_cls, b_cl, out);
}

// Round 6
// 720.070 us; speedup vs baseline: 4.5805x; 1.0908x over previous
//
#include <hip/hip_runtime.h>
#include <math.h>

#define NLAYERS 6
#define HD 256
#define NS 32
#define NCLS 50
#define BB 16
#define LL 2048
#define TT 64
#define CC 32

typedef __attribute__((ext_vector_type(8))) short bf16x8;
typedef __attribute__((ext_vector_type(4))) float f32x4;

// ---- static device workspaces ----
__device__ __attribute__((aligned(16))) float g_x [8388608];   // [B][L][H] residual stream (fp32)
__device__ __attribute__((aligned(16))) float g_Vt[6389760];   // [l][h][n][65][2] : w^t, t=0..64
__device__ __attribute__((aligned(16))) float g_Kt[98304];     // [l][h][64] kernel taps
__device__ __attribute__((aligned(16))) float g_E0[98304];     // [l][h][n][2] : C*dB
__device__ __attribute__((aligned(16))) float g_pp[65536];     // [B][16][H] pool partials
__device__ __attribute__((aligned(16))) unsigned short g_zbh[8388608]; // z bf16 [B][H][L]
__device__ __attribute__((aligned(16))) unsigned short g_Mt [12582912];// [l][h][t=64][k=128] bf16 (TK;TC)^T, D folded
__device__ __attribute__((aligned(16))) unsigned short g_TAt[6291456]; // [l][h][p=64][t=64] bf16 TA^T
__device__ __attribute__((aligned(16))) unsigned short g_ybh[8388608]; // y bf16 [B][H][L]
__device__ __attribute__((aligned(16))) unsigned short g_yt [8388608]; // y bf16 [B][L][H]
__device__ __attribute__((aligned(16))) unsigned short g_Wt [786432];  // Wt bf16 [l][n=512][k=256]
__device__ __attribute__((aligned(16))) unsigned short g_xb [4194304]; // x_in bf16 [32768][128]
__device__ __attribute__((aligned(16))) unsigned short g_Wint[32768];  // W_in^T bf16 [n=256][k=128]

__device__ __forceinline__ float sigf(float x) { return 1.0f / (1.0f + __expf(-x)); }
__device__ __forceinline__ float geluf(float x) {
  float t = 0.7978845608028654f * (x + 0.044715f * x * x * x);
  float e = __expf(2.0f * t);
  float th = 1.0f - 2.0f / (e + 1.0f);
  return 0.5f * x * (1.0f + th);
}
__device__ __forceinline__ unsigned short f2bf(float f) {
  unsigned u = __float_as_uint(f);
  unsigned r = (u + 0x7FFFu + ((u >> 16) & 1u)) >> 16;
  return (unsigned short)r;
}

// ---------- precompute: w, E0 = C*dB, power table w^t ----------
__global__ void k_precomp(const float* __restrict__ log_dt,
                          const float* __restrict__ A_re, const float* __restrict__ A_im,
                          const float* __restrict__ B_re, const float* __restrict__ B_im,
                          const float* __restrict__ C_re, const float* __restrict__ C_im) {
  int id = blockIdx.x * 256 + threadIdx.x;
  if (id >= NLAYERS * HD * NS) return;
  int h = (id / NS) % HD;
  int i = id / (NS * HD);
  float dt = expf(log_dt[i * HD + h]);
  float ar = A_re[id], ai = A_im[id];
  float dr = dt * ar, di = dt * ai;
  float er = expf(dr);
  float wr = er * cosf(di), wi = er * sinf(di);
  float inv = 1.0f / (ar * ar + ai * ai);
  float mr = wr - 1.0f, mi = wi;
  float qr = (mr * ar + mi * ai) * inv;
  float qi = (mi * ar - mr * ai) * inv;
  float br = B_re[id], bi = B_im[id];
  float dbr = br * qr - bi * qi, dbi = br * qi + bi * qr;
  float cr = C_re[id], ci = C_im[id];
  g_E0[id * 2 + 0] = cr * dbr - ci * dbi;
  g_E0[id * 2 + 1] = cr * dbi + ci * dbr;
  float pr = 1.0f, pi = 0.0f;
  long base = (long)id * 65;
  for (int t = 0; t <= 64; ++t) {
    g_Vt[(base + t) * 2 + 0] = pr;
    g_Vt[(base + t) * 2 + 1] = pi;
    float nr = pr * wr - pi * wi;
    pi = pr * wi + pi * wr;
    pr = nr;
  }
}

__global__ void k_precompK() {
  int id = blockIdx.x * 256 + threadIdx.x;
  if (id >= NLAYERS * HD * TT) return;
  int t = id % TT;
  int lh = id / TT;
  float acc = 0.f;
  const float* e = g_E0 + (long)lh * NS * 2;
  const float* v = g_Vt + ((long)lh * NS * 65 + t) * 2;
  for (int n = 0; n < NS; ++n)
    acc += e[n * 2] * v[n * 130] - e[n * 2 + 1] * v[n * 130 + 1];
  g_Kt[id] = 2.0f * acc;
}

// Mt[l][h][t][k] bf16: k<64 -> TK[s=k][t] (+D at k==t); k>=64 -> TC[p=k-64][t]
__global__ void k_precompM(const float* __restrict__ Dd) {
  int id = blockIdx.x * 256 + threadIdx.x;     // 12582912
  int k = id & 127;
  int t = (id >> 7) & 63;
  int lh = id >> 13;
  float v;
  if (k < 64) {
    v = (t >= k) ? g_Kt[(long)lh * 64 + (t - k)] : 0.f;
    if (k == t) v += Dd[lh];
  } else {
    int p = k - 64, n = p >> 1;
    const float2 w = ((const float2*)g_Vt)[((long)lh * NS + n) * 65 + (t + 1)];
    v = (p & 1) ? (-2.f * w.y) : (2.f * w.x);
  }
  g_Mt[id] = f2bf(v);
}

// TAt[l][h][p][t] = TA[t][p] bf16
__global__ void k_precompA2() {
  int id = blockIdx.x * 256 + threadIdx.x;     // 6291456
  int t = id & 63;
  int p = (id >> 6) & 63;
  int lh = id >> 12;
  int n = p >> 1;
  const float2 w = ((const float2*)g_Vt)[((long)lh * NS + n) * 65 + (63 - t)];
  g_TAt[id] = f2bf((p & 1) ? w.y : w.x);
}

// ---------- W_out -> Wt bf16 [l][n][k] ----------
__global__ __launch_bounds__(256) void k_prepW(const float* __restrict__ W_out) {
  __shared__ float T[32][33];
  int bid = blockIdx.x;
  int nt = bid & 15, kt = (bid >> 4) & 7, l = bid >> 7;
  int t = threadIdx.x;
  int tr = t >> 3, tc = t & 7;
  const float* src = W_out + (long)l * 131072 + (long)(kt * 32) * 512 + nt * 32;
  float4 v = *(const float4*)(src + (long)tr * 512 + tc * 4);
  T[tr][tc * 4 + 0] = v.x; T[tr][tc * 4 + 1] = v.y;
  T[tr][tc * 4 + 2] = v.z; T[tr][tc * 4 + 3] = v.w;
  __syncthreads();
  ushort4 o;
  o.x = f2bf(T[tc * 4 + 0][tr]); o.y = f2bf(T[tc * 4 + 1][tr]);
  o.z = f2bf(T[tc * 4 + 2][tr]); o.w = f2bf(T[tc * 4 + 3][tr]);
  *(ushort4*)(g_Wt + ((long)l * 512 + nt * 32 + tr) * 256 + kt * 32 + tc * 4) = o;
}

// ---------- W_in [k=128][n=256] -> Wint bf16 [n][k] ----------
__global__ void k_prepWin(const float* __restrict__ W_in) {
  int k = blockIdx.x, n = threadIdx.x;
  g_Wint[n * 128 + k] = f2bf(W_in[k * 256 + n]);
}

// ---------- x_in fp32 -> bf16 ----------
__global__ void k_castin(const float* __restrict__ xin) {
  long base = ((long)blockIdx.x * 256 + threadIdx.x) * 8;
  float4 v0 = *(const float4*)(xin + base);
  float4 v1 = *(const float4*)(xin + base + 4);
  union { unsigned short u[8]; ulonglong2 v; } pk;
  pk.u[0] = f2bf(v0.x); pk.u[1] = f2bf(v0.y); pk.u[2] = f2bf(v0.z); pk.u[3] = f2bf(v0.w);
  pk.u[4] = f2bf(v1.x); pk.u[5] = f2bf(v1.y); pk.u[6] = f2bf(v1.z); pk.u[7] = f2bf(v1.w);
  *(ulonglong2*)(g_xb + base) = pk.v;
}

// ---------- input GEMM (bf16 MFMA): g_x[32768,256] = xb[32768,128]*Wint^T + b ----------
__global__ __launch_bounds__(256) void k_gemmin(const float* __restrict__ bias) {
  __shared__ __attribute__((aligned(16))) unsigned short As[128 * 32];
  __shared__ __attribute__((aligned(16))) unsigned short Bs[256 * 32];
  const int tid = threadIdx.x;
  const int wave = tid >> 6, lane = tid & 63;
  const int m0 = blockIdx.x * 128;
  const int wm = wave & 1, wn = wave >> 1;
  const int n15 = lane & 15, kg = lane >> 4, q2 = kg * 8;
  f32x4 acc[4][8];
  #pragma unroll
  for (int a = 0; a < 4; ++a)
    #pragma unroll
    for (int b2 = 0; b2 < 8; ++b2) acc[a][b2] = (f32x4){0.f, 0.f, 0.f, 0.f};
  for (int k0 = 0; k0 < 128; k0 += 32) {
    __syncthreads();
    #pragma unroll
    for (int it = 0; it < 2; ++it) {
      int slot = it * 256 + wave * 64 + lane;
      int m = slot >> 2, ko = (slot & 3) * 8;
      __builtin_amdgcn_global_load_lds(
        (const __attribute__((address_space(1))) unsigned int*)(g_xb + (long)(m0 + m) * 128 + k0 + ko),
        (__attribute__((address_space(3))) unsigned int*)(As + (it * 256 + wave * 64) * 8),
        16, 0, 0);
    }
    #pragma unroll
    for (int it = 0; it < 4; ++it) {
      int slot = it * 256 + wave * 64 + lane;
      int n = slot >> 2, ko = (slot & 3) * 8;
      __builtin_amdgcn_global_load_lds(
        (const __attribute__((address_space(1))) unsigned int*)(g_Wint + (long)n * 128 + k0 + ko),
        (__attribute__((address_space(3))) unsigned int*)(Bs + (it * 256 + wave * 64) * 8),
        16, 0, 0);
    }
    __syncthreads();
    bf16x8 af[4], bn[8];
    #pragma unroll
    for (int mt = 0; mt < 4; ++mt)
      af[mt] = *(const bf16x8*)&As[(wm * 64 + mt * 16 + n15) * 32 + q2];
    #pragma unroll
    for (int j = 0; j < 8; ++j)
      bn[j] = *(const bf16x8*)&Bs[(wn * 128 + j * 16 + n15) * 32 + q2];
    #pragma unroll
    for (int mt = 0; mt < 4; ++mt)
      #pragma unroll
      for (int j = 0; j < 8; ++j)
        acc[mt][j] = __builtin_amdgcn_mfma_f32_16x16x32_bf16(af[mt], bn[j], acc[mt][j], 0, 0, 0);
  }
  #pragma unroll
  for (int j = 0; j < 8; ++j) {
    int col = wn * 128 + j * 16 + n15;
    float bb = bias[col];
    #pragma unroll
    for (int mt = 0; mt < 4; ++mt)
      #pragma unroll
      for (int r = 0; r < 4; ++r) {
        int row = m0 + wm * 64 + mt * 16 + kg * 4 + r;
        g_x[(long)row * 256 + col] = acc[mt][j][r] + bb;
      }
  }
}

// ---------- LayerNorm over H -> z bf16 [B][H][L]; block owns 32 consecutive L ----------
__global__ __launch_bounds__(256) void k_ln(const float* __restrict__ gam,
                                            const float* __restrict__ bet) {
  __shared__ unsigned short S[32 * 264];       // [ll][h], pad 264
  const int bid = blockIdx.x;                  // 1024: b = bid>>6, l0 = (bid&63)*32
  const int b = bid >> 6, l0 = (bid & 63) << 5;
  const int tid = threadIdx.x, w = tid >> 6, lane = tid & 63;
  float4 gv = *(const float4*)(gam + lane * 4);
  float4 bv = *(const float4*)(bet + lane * 4);
  for (int r = 0; r < 8; ++r) {
    int ll = w * 8 + r;
    float4 v = *(const float4*)(g_x + ((long)(b * LL + l0 + ll)) * HD + lane * 4);
    float s1 = v.x + v.y + v.z + v.w;
    float s2 = v.x * v.x + v.y * v.y + v.z * v.z + v.w * v.w;
    #pragma unroll
    for (int off = 32; off; off >>= 1) { s1 += __shfl_xor(s1, off); s2 += __shfl_xor(s2, off); }
    float mu = s1 * (1.0f / HD);
    float rs = rsqrtf(s2 * (1.0f / HD) - mu * mu + 1e-5f);
    ushort4 o;
    o.x = f2bf((v.x - mu) * rs * gv.x + bv.x);
    o.y = f2bf((v.y - mu) * rs * gv.y + bv.y);
    o.z = f2bf((v.z - mu) * rs * gv.z + bv.z);
    o.w = f2bf((v.w - mu) * rs * gv.w + bv.w);
    *(ushort4*)&S[ll * 264 + lane * 4] = o;
  }
  __syncthreads();
  unsigned short* zp = g_zbh + ((long)(b * HD + tid)) * LL + l0;   // 64B per thread
  #pragma unroll
  for (int seg = 0; seg < 4; ++seg) {
    union { unsigned short u[8]; ulonglong2 v; } pk;
    #pragma unroll
    for (int i = 0; i < 8; ++i) pk.u[i] = S[(seg * 8 + i) * 264 + tid];
    *(ulonglong2*)(zp + seg * 8) = pk.v;
  }
}

// ---------- fused SSM: phaseA (MFMA) + chunk scan + phaseC (MFMA), one block per (b,h) ----------
__global__ __launch_bounds__(256) void k_ssm(int layer) {
  __shared__ __attribute__((aligned(16))) unsigned short Zs[32 * 72];   // z [c][t]
  __shared__ __attribute__((aligned(16))) unsigned short Ts[64 * 72];   // TA^T [p][t]
  __shared__ __attribute__((aligned(16))) unsigned short Ms[64 * 136];  // Mt [t][k]
  __shared__ float Ss[32 * 68];                                          // S_end [c][p]
  __shared__ __attribute__((aligned(16))) unsigned short Gs[32 * 72];   // G [c][p]
  const int tid = threadIdx.x, wave = tid >> 6, lane = tid & 63;
  const int h = blockIdx.x >> 4, b = blockIdx.x & 15;
  const long lh = (long)layer * HD + h;
  {
    int c = tid >> 3, off = (tid & 7) * 8;
    *(ulonglong2*)&Zs[c * 72 + off] =
        *(const ulonglong2*)(g_zbh + ((long)(b * HD + h)) * LL + c * 64 + off);
  }
  const unsigned short* Tg = g_TAt + lh * 4096;
  #pragma unroll
  for (int i = 0; i < 2; ++i) {
    int seg = tid + i * 256;
    int row = seg >> 3, sc = (seg & 7) * 8;
    *(ulonglong2*)&Ts[row * 72 + sc] = *(const ulonglong2*)(Tg + row * 64 + sc);
  }
  const unsigned short* Mg = g_Mt + lh * 8192;
  #pragma unroll
  for (int i = 0; i < 4; ++i) {
    int seg = tid + i * 256;
    int row = seg >> 4, sc = (seg & 15) * 8;
    *(ulonglong2*)&Ms[row * 136 + sc] = *(const ulonglong2*)(Mg + row * 128 + sc);
  }
  __syncthreads();
  const int n15 = lane & 15, kg = lane >> 4;
  const int mt = wave & 1;
  const int jb = (wave >> 1) * 2;
  const int c = mt * 16 + n15;
  {
    bf16x8 a0 = *(const bf16x8*)&Zs[c * 72 + kg * 8];
    bf16x8 a1 = *(const bf16x8*)&Zs[c * 72 + 32 + kg * 8];
    #pragma unroll
    for (int jj = 0; jj < 2; ++jj) {
      int j = jb + jj;
      bf16x8 b0 = *(const bf16x8*)&Ts[(j * 16 + n15) * 72 + kg * 8];
      bf16x8 b1 = *(const bf16x8*)&Ts[(j * 16 + n15) * 72 + 32 + kg * 8];
      f32x4 acc = (f32x4){0.f, 0.f, 0.f, 0.f};
      acc = __builtin_amdgcn_mfma_f32_16x16x32_bf16(a0, b0, acc, 0, 0, 0);
      acc = __builtin_amdgcn_mfma_f32_16x16x32_bf16(a1, b1, acc, 0, 0, 0);
      #pragma unroll
      for (int r = 0; r < 4; ++r)
        Ss[(mt * 16 + kg * 4 + r) * 68 + j * 16 + n15] = acc[r];
    }
  }
  __syncthreads();
  if (wave == 0 && lane < 32) {
    int n = lane;
    long vb = (lh * NS + n) * 65;
    float wtr = g_Vt[vb * 2 + 128], wti = g_Vt[vb * 2 + 129];
    float e0r = g_E0[(lh * NS + n) * 2], e0i = g_E0[(lh * NS + n) * 2 + 1];
    float sr = 0.f, si = 0.f;
    for (int cc = 0; cc < CC; ++cc) {
      float er = Ss[cc * 68 + 2 * n], ei = Ss[cc * 68 + 2 * n + 1];
      Gs[cc * 72 + 2 * n]     = f2bf(e0r * sr - e0i * si);
      Gs[cc * 72 + 2 * n + 1] = f2bf(e0r * si + e0i * sr);
      float nr = er + wtr * sr - wti * si;
      si      = ei + wtr * si + wti * sr;
      sr = nr;
    }
  }
  __syncthreads();
  {
    bf16x8 a0 = *(const bf16x8*)&Zs[c * 72 + kg * 8];
    bf16x8 a1 = *(const bf16x8*)&Zs[c * 72 + 32 + kg * 8];
    bf16x8 a2 = *(const bf16x8*)&Gs[c * 72 + kg * 8];
    bf16x8 a3 = *(const bf16x8*)&Gs[c * 72 + 32 + kg * 8];
    unsigned short* yrow = g_ybh + ((long)(b * HD + h)) * LL;
    #pragma unroll
    for (int jj = 0; jj < 2; ++jj) {
      int j = jb + jj;
      const unsigned short* mrow = &Ms[(j * 16 + n15) * 136];
      bf16x8 b0 = *(const bf16x8*)&mrow[kg * 8];
      bf16x8 b1 = *(const bf16x8*)&mrow[32 + kg * 8];
      bf16x8 b2 = *(const bf16x8*)&mrow[64 + kg * 8];
      bf16x8 b3 = *(const bf16x8*)&mrow[96 + kg * 8];
      f32x4 acc = (f32x4){0.f, 0.f, 0.f, 0.f};
      acc = __builtin_amdgcn_mfma_f32_16x16x32_bf16(a0, b0, acc, 0, 0, 0);
      acc = __builtin_amdgcn_mfma_f32_16x16x32_bf16(a1, b1, acc, 0, 0, 0);
      acc = __builtin_amdgcn_mfma_f32_16x16x32_bf16(a2, b2, acc, 0, 0, 0);
      acc = __builtin_amdgcn_mfma_f32_16x16x32_bf16(a3, b3, acc, 0, 0, 0);
      #pragma unroll
      for (int r = 0; r < 4; ++r)
        yrow[(mt * 16 + kg * 4 + r) * 64 + j * 16 + n15] = f2bf(geluf(acc[r]));
    }
  }
}

// ---------- transpose y: [B][H][L] bf16 -> [B][L][H] bf16 ----------
__global__ __launch_bounds__(256) void k_transp() {
  __shared__ unsigned short T[64][65];
  int bid = blockIdx.x;
  int ht = bid & 3, lt = (bid >> 2) & 31, b = bid >> 7;
  int t = threadIdx.x;
  int r = t >> 4, c = t & 15;
  #pragma unroll
  for (int i = 0; i < 4; ++i) {
    int hh = r + i * 16;
    ushort4 v = *(const ushort4*)(g_ybh + ((long)(b * 256 + ht * 64 + hh)) * 2048 + lt * 64 + c * 4);
    T[hh][c * 4 + 0] = v.x; T[hh][c * 4 + 1] = v.y;
    T[hh][c * 4 + 2] = v.z; T[hh][c * 4 + 3] = v.w;
  }
  __syncthreads();
  #pragma unroll
  for (int i = 0; i < 4; ++i) {
    int ll = r + i * 16;
    ushort4 o;
    o.x = T[c * 4 + 0][ll]; o.y = T[c * 4 + 1][ll];
    o.z = T[c * 4 + 2][ll]; o.w = T[c * 4 + 3][ll];
    *(ushort4*)(g_yt + ((long)(b * 2048 + lt * 64 + ll)) * 256 + ht * 64 + c * 4) = o;
  }
}

// ---------- bf16 MFMA GEMM + fused GLU + residual; 64-row tiles for occupancy ----------
__global__ __launch_bounds__(256, 4) void k_gemmglu(int layer, const float* __restrict__ bias) {
  __shared__ __attribute__((aligned(16))) unsigned short As[64 * 32];    // 4 KB
  __shared__ __attribute__((aligned(16))) unsigned short Bs[256 * 32];   // 16 KB
  const int tid = threadIdx.x;
  const int wave = tid >> 6, lane = tid & 63;
  const int m0 = blockIdx.x * 64;
  const int gg = blockIdx.y;
  const int wm = wave & 1, wn = wave >> 1;
  const int n15 = lane & 15, kg = lane >> 4, q2 = kg * 8;
  const unsigned short* Ag = g_yt + (long)m0 * 256;
  const unsigned short* Wt = g_Wt + (long)layer * 131072;
  f32x4 acc[2][8];
  #pragma unroll
  for (int a = 0; a < 2; ++a)
    #pragma unroll
    for (int b2 = 0; b2 < 8; ++b2) acc[a][b2] = (f32x4){0.f, 0.f, 0.f, 0.f};
  for (int k0 = 0; k0 < 256; k0 += 32) {
    __syncthreads();
    {
      int slot = wave * 64 + lane;          // 256 slots: m = slot>>2, ko = (slot&3)*8
      int m = slot >> 2, ko = (slot & 3) * 8;
      __builtin_amdgcn_global_load_lds(
        (const __attribute__((address_space(1))) unsigned int*)(Ag + (long)m * 256 + k0 + ko),
        (__attribute__((address_space(3))) unsigned int*)(As + (wave * 64) * 8),
        16, 0, 0);
    }
    #pragma unroll
    for (int it = 0; it < 4; ++it) {
      int slot = it * 256 + wave * 64 + lane;
      int np = slot >> 2, ko = (slot & 3) * 8;
      int n = gg * 128 + (np < 128 ? np : np + 128);
      __builtin_amdgcn_global_load_lds(
        (const __attribute__((address_space(1))) unsigned int*)(Wt + (long)n * 256 + k0 + ko),
        (__attribute__((address_space(3))) unsigned int*)(Bs + (it * 256 + wave * 64) * 8),
        16, 0, 0);
    }
    __syncthreads();
    bf16x8 af0 = *(const bf16x8*)&As[(wm * 32 + n15) * 32 + q2];
    bf16x8 af1 = *(const bf16x8*)&As[(wm * 32 + 16 + n15) * 32 + q2];
    #pragma unroll
    for (int j = 0; j < 4; ++j) {
      bf16x8 ba = *(const bf16x8*)&Bs[(wn * 64 + j * 16 + n15) * 32 + q2];
      acc[0][j] = __builtin_amdgcn_mfma_f32_16x16x32_bf16(af0, ba, acc[0][j], 0, 0, 0);
      acc[1][j] = __builtin_amdgcn_mfma_f32_16x16x32_bf16(af1, ba, acc[1][j], 0, 0, 0);
      bf16x8 bg = *(const bf16x8*)&Bs[(128 + wn * 64 + j * 16 + n15) * 32 + q2];
      acc[0][4 + j] = __builtin_amdgcn_mfma_f32_16x16x32_bf16(af0, bg, acc[0][4 + j], 0, 0, 0);
      acc[1][4 + j] = __builtin_amdgcn_mfma_f32_16x16x32_bf16(af1, bg, acc[1][4 + j], 0, 0, 0);
    }
  }
  #pragma unroll
  for (int j = 0; j < 4; ++j) {
    int col = gg * 128 + wn * 64 + j * 16 + n15;
    float ba = bias[col], bg = bias[col + 256];
    #pragma unroll
    for (int mt = 0; mt < 2; ++mt) {
      #pragma unroll
      for (int r = 0; r < 4; ++r) {
        int row = m0 + wm * 32 + mt * 16 + kg * 4 + r;
        float a = acc[mt][j][r] + ba;
        float g = acc[mt][4 + j][r] + bg;
        float* xp = g_x + (long)row * 256 + col;
        *xp += a * sigf(g);
      }
    }
  }
}

// ---------- final LN + partial pool ----------
__global__ __launch_bounds__(256) void k_lnpool(const float* __restrict__ gam,
                                                const float* __restrict__ bet) {
  __shared__ float red[4][256];
  const int bid = blockIdx.x;
  const int b = bid >> 4, s = bid & 15;
  const int tid = threadIdx.x, w = tid >> 6, lane = tid & 63;
  float4 gv = *(const float4*)(gam + lane * 4);
  float4 bv = *(const float4*)(bet + lane * 4);
  float a0 = 0, a1 = 0, a2 = 0, a3 = 0;
  for (int r = 0; r < 32; ++r) {
    int l = s * 128 + w * 32 + r;
    float4 v = *(const float4*)(g_x + ((long)b * LL + l) * HD + lane * 4);
    float s1 = v.x + v.y + v.z + v.w;
    float s2 = v.x * v.x + v.y * v.y + v.z * v.z + v.w * v.w;
    #pragma unroll
    for (int off = 32; off; off >>= 1) { s1 += __shfl_xor(s1, off); s2 += __shfl_xor(s2, off); }
    float mu = s1 * (1.0f / HD);
    float rs = rsqrtf(s2 * (1.0f / HD) - mu * mu + 1e-5f);
    a0 += (v.x - mu) * rs * gv.x + bv.x;
    a1 += (v.y - mu) * rs * gv.y + bv.y;
    a2 += (v.z - mu) * rs * gv.z + bv.z;
    a3 += (v.w - mu) * rs * gv.w + bv.w;
  }
  red[w][lane * 4 + 0] = a0; red[w][lane * 4 + 1] = a1;
  red[w][lane * 4 + 2] = a2; red[w][lane * 4 + 3] = a3;
  __syncthreads();
  g_pp[(long)bid * HD + tid] = red[0][tid] + red[1][tid] + red[2][tid] + red[3][tid];
}

// ---------- classifier ----------
__global__ __launch_bounds__(256) void k_cls(const float* __restrict__ Wc,
                                             const float* __restrict__ bc,
                                             float* __restrict__ out) {
  __shared__ float pl[256];
  const int b = blockIdx.x, tid = threadIdx.x;
  float p = 0.f;
  #pragma unroll
  for (int s = 0; s < 16; ++s) p += g_pp[((long)b * 16 + s) * HD + tid];
  pl[tid] = p * (1.0f / LL);
  __syncthreads();
  if (tid < NCLS) {
    float acc = bc[tid];
    for (int h = 0; h < HD; ++h) acc += pl[h] * Wc[h * NCLS + tid];
    out[b * NCLS + tid] = acc;
  }
}

extern "C" void kernel_launch(void* const* d_in, const int* in_sizes, int n_in,
                              void* d_out, int out_size, void* d_ws, size_t ws_size,
                              hipStream_t stream) {
  (void)in_sizes; (void)n_in; (void)d_ws; (void)ws_size; (void)out_size;
  const float* x_in   = (const float*)d_in[0];
  const float* W_in   = (const float*)d_in[1];
  const float* b_in   = (const float*)d_in[2];
  const float* log_dt = (const float*)d_in[3];
  const float* A_re   = (const float*)d_in[4];
  const float* A_im   = (const float*)d_in[5];
  const float* B_re   = (const float*)d_in[6];
  const float* B_im   = (const float*)d_in[7];
  const float* C_re   = (const float*)d_in[8];
  const float* C_im   = (const float*)d_in[9];
  const float* Dd     = (const float*)d_in[10];
  const float* W_out  = (const float*)d_in[11];
  const float* b_out  = (const float*)d_in[12];
  const float* ln_s   = (const float*)d_in[13];
  const float* ln_b   = (const float*)d_in[14];
  const float* lnf_s  = (const float*)d_in[15];
  const float* lnf_b  = (const float*)d_in[16];
  const float* W_cls  = (const float*)d_in[17];
  const float* b_cl   = (const float*)d_in[18];
  float* out = (float*)d_out;

  k_precomp<<<192, 256, 0, stream>>>(log_dt, A_re, A_im, B_re, B_im, C_re, C_im);
  k_precompK<<<384, 256, 0, stream>>>();
  k_precompM<<<49152, 256, 0, stream>>>(Dd);
  k_precompA2<<<24576, 256, 0, stream>>>();
  k_prepW<<<768, 256, 0, stream>>>(W_out);
  k_prepWin<<<128, 256, 0, stream>>>(W_in);
  k_castin<<<2048, 256, 0, stream>>>(x_in);
  k_gemmin<<<256, 256, 0, stream>>>(b_in);
  for (int i = 0; i < NLAYERS; ++i) {
    k_ln<<<1024, 256, 0, stream>>>(ln_s + i * HD, ln_b + i * HD);
    k_ssm<<<4096, 256, 0, stream>>>(i);
    k_transp<<<2048, 256, 0, stream>>>();
    k_gemmglu<<<dim3(512, 2), 256, 0, stream>>>(i, b_out + i * 2 * HD);
  }
  k_lnpool<<<256, 256, 0, stream>>>(lnf_s, lnf_b);
  k_cls<<<16, 256, 0, stream>>>(W_cls, b_cl, out);
}

// Round 7
// 710.370 us; speedup vs baseline: 4.6430x; 1.0137x over previous
//
#include <hip/hip_runtime.h>
#include <math.h>

#define NLAYERS 6
#define HD 256
#define NS 32
#define NCLS 50
#define BB 16
#define LL 2048
#define TT 64
#define CC 32

typedef __attribute__((ext_vector_type(8))) short bf16x8;
typedef __attribute__((ext_vector_type(4))) float f32x4;

// ---- static device workspaces ----
__device__ __attribute__((aligned(16))) float g_x [8388608];   // [B][L][H] residual stream (fp32)
__device__ __attribute__((aligned(16))) float g_Vt[6389760];   // [l][h][n][65][2] : w^t, t=0..64
__device__ __attribute__((aligned(16))) float g_Kt[98304];     // [l][h][64] kernel taps
__device__ __attribute__((aligned(16))) float g_E0[98304];     // [l][h][n][2] : C*dB
__device__ __attribute__((aligned(16))) float g_pp[65536];     // [B][16][H] pool partials
__device__ __attribute__((aligned(16))) unsigned short g_zbh[8388608]; // z bf16 [B][H][L]
__device__ __attribute__((aligned(16))) unsigned short g_Mt [12582912];// [l][h][t=64][k=128] bf16 (TK;TC)^T, D folded
__device__ __attribute__((aligned(16))) unsigned short g_TAt[6291456]; // [l][h][p=64][t=64] bf16 TA^T
__device__ __attribute__((aligned(16))) unsigned short g_ybh[8388608]; // y bf16 [B][H][L]
__device__ __attribute__((aligned(16))) unsigned short g_Wt [786432];  // Wt bf16 [l][n=512][k=256]
__device__ __attribute__((aligned(16))) unsigned short g_xb [4194304]; // x_in bf16 [32768][128]
__device__ __attribute__((aligned(16))) unsigned short g_Wint[32768];  // W_in^T bf16 [n=256][k=128]

__device__ __forceinline__ float sigf(float x) { return 1.0f / (1.0f + __expf(-x)); }
__device__ __forceinline__ float geluf(float x) {
  float t = 0.7978845608028654f * (x + 0.044715f * x * x * x);
  float e = __expf(2.0f * t);
  float th = 1.0f - 2.0f / (e + 1.0f);
  return 0.5f * x * (1.0f + th);
}
__device__ __forceinline__ unsigned short f2bf(float f) {
  unsigned u = __float_as_uint(f);
  unsigned r = (u + 0x7FFFu + ((u >> 16) & 1u)) >> 16;
  return (unsigned short)r;
}

// ---------- precompute: w, E0 = C*dB, power table w^t ----------
__global__ void k_precomp(const float* __restrict__ log_dt,
                          const float* __restrict__ A_re, const float* __restrict__ A_im,
                          const float* __restrict__ B_re, const float* __restrict__ B_im,
                          const float* __restrict__ C_re, const float* __restrict__ C_im) {
  int id = blockIdx.x * 256 + threadIdx.x;
  if (id >= NLAYERS * HD * NS) return;
  int h = (id / NS) % HD;
  int i = id / (NS * HD);
  float dt = expf(log_dt[i * HD + h]);
  float ar = A_re[id], ai = A_im[id];
  float dr = dt * ar, di = dt * ai;
  float er = expf(dr);
  float wr = er * cosf(di), wi = er * sinf(di);
  float inv = 1.0f / (ar * ar + ai * ai);
  float mr = wr - 1.0f, mi = wi;
  float qr = (mr * ar + mi * ai) * inv;
  float qi = (mi * ar - mr * ai) * inv;
  float br = B_re[id], bi = B_im[id];
  float dbr = br * qr - bi * qi, dbi = br * qi + bi * qr;
  float cr = C_re[id], ci = C_im[id];
  g_E0[id * 2 + 0] = cr * dbr - ci * dbi;
  g_E0[id * 2 + 1] = cr * dbi + ci * dbr;
  float pr = 1.0f, pi = 0.0f;
  long base = (long)id * 65;
  for (int t = 0; t <= 64; ++t) {
    g_Vt[(base + t) * 2 + 0] = pr;
    g_Vt[(base + t) * 2 + 1] = pi;
    float nr = pr * wr - pi * wi;
    pi = pr * wi + pi * wr;
    pr = nr;
  }
}

__global__ void k_precompK() {
  int id = blockIdx.x * 256 + threadIdx.x;
  if (id >= NLAYERS * HD * TT) return;
  int t = id % TT;
  int lh = id / TT;
  float acc = 0.f;
  const float* e = g_E0 + (long)lh * NS * 2;
  const float* v = g_Vt + ((long)lh * NS * 65 + t) * 2;
  for (int n = 0; n < NS; ++n)
    acc += e[n * 2] * v[n * 130] - e[n * 2 + 1] * v[n * 130 + 1];
  g_Kt[id] = 2.0f * acc;
}

// Mt[l][h][t][k] bf16: k<64 -> TK[s=k][t] (+D at k==t); k>=64 -> TC[p=k-64][t]
__global__ void k_precompM(const float* __restrict__ Dd) {
  int id = blockIdx.x * 256 + threadIdx.x;     // 12582912
  int k = id & 127;
  int t = (id >> 7) & 63;
  int lh = id >> 13;
  float v;
  if (k < 64) {
    v = (t >= k) ? g_Kt[(long)lh * 64 + (t - k)] : 0.f;
    if (k == t) v += Dd[lh];
  } else {
    int p = k - 64, n = p >> 1;
    const float2 w = ((const float2*)g_Vt)[((long)lh * NS + n) * 65 + (t + 1)];
    v = (p & 1) ? (-2.f * w.y) : (2.f * w.x);
  }
  g_Mt[id] = f2bf(v);
}

// TAt[l][h][p][t] = TA[t][p] bf16
__global__ void k_precompA2() {
  int id = blockIdx.x * 256 + threadIdx.x;     // 6291456
  int t = id & 63;
  int p = (id >> 6) & 63;
  int lh = id >> 12;
  int n = p >> 1;
  const float2 w = ((const float2*)g_Vt)[((long)lh * NS + n) * 65 + (63 - t)];
  g_TAt[id] = f2bf((p & 1) ? w.y : w.x);
}

// ---------- W_out -> Wt bf16 [l][n][k] ----------
__global__ __launch_bounds__(256) void k_prepW(const float* __restrict__ W_out) {
  __shared__ float T[32][33];
  int bid = blockIdx.x;
  int nt = bid & 15, kt = (bid >> 4) & 7, l = bid >> 7;
  int t = threadIdx.x;
  int tr = t >> 3, tc = t & 7;
  const float* src = W_out + (long)l * 131072 + (long)(kt * 32) * 512 + nt * 32;
  float4 v = *(const float4*)(src + (long)tr * 512 + tc * 4);
  T[tr][tc * 4 + 0] = v.x; T[tr][tc * 4 + 1] = v.y;
  T[tr][tc * 4 + 2] = v.z; T[tr][tc * 4 + 3] = v.w;
  __syncthreads();
  ushort4 o;
  o.x = f2bf(T[tc * 4 + 0][tr]); o.y = f2bf(T[tc * 4 + 1][tr]);
  o.z = f2bf(T[tc * 4 + 2][tr]); o.w = f2bf(T[tc * 4 + 3][tr]);
  *(ushort4*)(g_Wt + ((long)l * 512 + nt * 32 + tr) * 256 + kt * 32 + tc * 4) = o;
}

// ---------- W_in [k=128][n=256] -> Wint bf16 [n][k] ----------
__global__ void k_prepWin(const float* __restrict__ W_in) {
  int k = blockIdx.x, n = threadIdx.x;
  g_Wint[n * 128 + k] = f2bf(W_in[k * 256 + n]);
}

// ---------- x_in fp32 -> bf16 ----------
__global__ void k_castin(const float* __restrict__ xin) {
  long base = ((long)blockIdx.x * 256 + threadIdx.x) * 8;
  float4 v0 = *(const float4*)(xin + base);
  float4 v1 = *(const float4*)(xin + base + 4);
  union { unsigned short u[8]; ulonglong2 v; } pk;
  pk.u[0] = f2bf(v0.x); pk.u[1] = f2bf(v0.y); pk.u[2] = f2bf(v0.z); pk.u[3] = f2bf(v0.w);
  pk.u[4] = f2bf(v1.x); pk.u[5] = f2bf(v1.y); pk.u[6] = f2bf(v1.z); pk.u[7] = f2bf(v1.w);
  *(ulonglong2*)(g_xb + base) = pk.v;
}

// ---------- input GEMM (bf16 MFMA): g_x[32768,256] = xb[32768,128]*Wint^T + b ----------
__global__ __launch_bounds__(256) void k_gemmin(const float* __restrict__ bias) {
  __shared__ __attribute__((aligned(16))) unsigned short As[128 * 32];
  __shared__ __attribute__((aligned(16))) unsigned short Bs[256 * 32];
  const int tid = threadIdx.x;
  const int wave = tid >> 6, lane = tid & 63;
  const int m0 = blockIdx.x * 128;
  const int wm = wave & 1, wn = wave >> 1;
  const int n15 = lane & 15, kg = lane >> 4, q2 = kg * 8;
  f32x4 acc[4][8];
  #pragma unroll
  for (int a = 0; a < 4; ++a)
    #pragma unroll
    for (int b2 = 0; b2 < 8; ++b2) acc[a][b2] = (f32x4){0.f, 0.f, 0.f, 0.f};
  for (int k0 = 0; k0 < 128; k0 += 32) {
    __syncthreads();
    #pragma unroll
    for (int it = 0; it < 2; ++it) {
      int slot = it * 256 + wave * 64 + lane;
      int m = slot >> 2, ko = (slot & 3) * 8;
      __builtin_amdgcn_global_load_lds(
        (const __attribute__((address_space(1))) unsigned int*)(g_xb + (long)(m0 + m) * 128 + k0 + ko),
        (__attribute__((address_space(3))) unsigned int*)(As + (it * 256 + wave * 64) * 8),
        16, 0, 0);
    }
    #pragma unroll
    for (int it = 0; it < 4; ++it) {
      int slot = it * 256 + wave * 64 + lane;
      int n = slot >> 2, ko = (slot & 3) * 8;
      __builtin_amdgcn_global_load_lds(
        (const __attribute__((address_space(1))) unsigned int*)(g_Wint + (long)n * 128 + k0 + ko),
        (__attribute__((address_space(3))) unsigned int*)(Bs + (it * 256 + wave * 64) * 8),
        16, 0, 0);
    }
    __syncthreads();
    bf16x8 af[4], bn[8];
    #pragma unroll
    for (int mt = 0; mt < 4; ++mt)
      af[mt] = *(const bf16x8*)&As[(wm * 64 + mt * 16 + n15) * 32 + q2];
    #pragma unroll
    for (int j = 0; j < 8; ++j)
      bn[j] = *(const bf16x8*)&Bs[(wn * 128 + j * 16 + n15) * 32 + q2];
    #pragma unroll
    for (int mt = 0; mt < 4; ++mt)
      #pragma unroll
      for (int j = 0; j < 8; ++j)
        acc[mt][j] = __builtin_amdgcn_mfma_f32_16x16x32_bf16(af[mt], bn[j], acc[mt][j], 0, 0, 0);
  }
  #pragma unroll
  for (int j = 0; j < 8; ++j) {
    int col = wn * 128 + j * 16 + n15;
    float bb = bias[col];
    #pragma unroll
    for (int mt = 0; mt < 4; ++mt)
      #pragma unroll
      for (int r = 0; r < 4; ++r) {
        int row = m0 + wm * 64 + mt * 16 + kg * 4 + r;
        g_x[(long)row * 256 + col] = acc[mt][j][r] + bb;
      }
  }
}

// ---------- LayerNorm over H -> z bf16 [B][H][L]; only for layer 0 ----------
__global__ __launch_bounds__(256) void k_ln(const float* __restrict__ gam,
                                            const float* __restrict__ bet) {
  __shared__ unsigned short S[32 * 264];
  const int bid = blockIdx.x;                  // 1024
  const int b = bid >> 6, l0 = (bid & 63) << 5;
  const int tid = threadIdx.x, w = tid >> 6, lane = tid & 63;
  float4 gv = *(const float4*)(gam + lane * 4);
  float4 bv = *(const float4*)(bet + lane * 4);
  for (int r = 0; r < 8; ++r) {
    int ll = w * 8 + r;
    float4 v = *(const float4*)(g_x + ((long)(b * LL + l0 + ll)) * HD + lane * 4);
    float s1 = v.x + v.y + v.z + v.w;
    float s2 = v.x * v.x + v.y * v.y + v.z * v.z + v.w * v.w;
    #pragma unroll
    for (int off = 32; off; off >>= 1) { s1 += __shfl_xor(s1, off); s2 += __shfl_xor(s2, off); }
    float mu = s1 * (1.0f / HD);
    float rs = rsqrtf(s2 * (1.0f / HD) - mu * mu + 1e-5f);
    ushort4 o;
    o.x = f2bf((v.x - mu) * rs * gv.x + bv.x);
    o.y = f2bf((v.y - mu) * rs * gv.y + bv.y);
    o.z = f2bf((v.z - mu) * rs * gv.z + bv.z);
    o.w = f2bf((v.w - mu) * rs * gv.w + bv.w);
    *(ushort4*)&S[ll * 264 + lane * 4] = o;
  }
  __syncthreads();
  unsigned short* zp = g_zbh + ((long)(b * HD + tid)) * LL + l0;
  #pragma unroll
  for (int seg = 0; seg < 4; ++seg) {
    union { unsigned short u[8]; ulonglong2 v; } pk;
    #pragma unroll
    for (int i = 0; i < 8; ++i) pk.u[i] = S[(seg * 8 + i) * 264 + tid];
    *(ulonglong2*)(zp + seg * 8) = pk.v;
  }
}

// ---------- fused SSM: phaseA (MFMA) + chunk scan + phaseC (MFMA), one block per (b,h) ----------
__global__ __launch_bounds__(256) void k_ssm(int layer) {
  __shared__ __attribute__((aligned(16))) unsigned short Zs[32 * 72];   // z [c][t]
  __shared__ __attribute__((aligned(16))) unsigned short Ts[64 * 72];   // TA^T [p][t]
  __shared__ __attribute__((aligned(16))) unsigned short Ms[64 * 136];  // Mt [t][k]
  __shared__ float Ss[32 * 68];                                          // S_end [c][p]
  __shared__ __attribute__((aligned(16))) unsigned short Gs[32 * 72];   // G [c][p]
  const int tid = threadIdx.x, wave = tid >> 6, lane = tid & 63;
  const int h = blockIdx.x >> 4, b = blockIdx.x & 15;
  const long lh = (long)layer * HD + h;
  {
    int c = tid >> 3, off = (tid & 7) * 8;
    *(ulonglong2*)&Zs[c * 72 + off] =
        *(const ulonglong2*)(g_zbh + ((long)(b * HD + h)) * LL + c * 64 + off);
  }
  const unsigned short* Tg = g_TAt + lh * 4096;
  #pragma unroll
  for (int i = 0; i < 2; ++i) {
    int seg = tid + i * 256;
    int row = seg >> 3, sc = (seg & 7) * 8;
    *(ulonglong2*)&Ts[row * 72 + sc] = *(const ulonglong2*)(Tg + row * 64 + sc);
  }
  const unsigned short* Mg = g_Mt + lh * 8192;
  #pragma unroll
  for (int i = 0; i < 4; ++i) {
    int seg = tid + i * 256;
    int row = seg >> 4, sc = (seg & 15) * 8;
    *(ulonglong2*)&Ms[row * 136 + sc] = *(const ulonglong2*)(Mg + row * 128 + sc);
  }
  __syncthreads();
  const int n15 = lane & 15, kg = lane >> 4;
  const int mt = wave & 1;
  const int jb = (wave >> 1) * 2;
  const int c = mt * 16 + n15;
  {
    bf16x8 a0 = *(const bf16x8*)&Zs[c * 72 + kg * 8];
    bf16x8 a1 = *(const bf16x8*)&Zs[c * 72 + 32 + kg * 8];
    #pragma unroll
    for (int jj = 0; jj < 2; ++jj) {
      int j = jb + jj;
      bf16x8 b0 = *(const bf16x8*)&Ts[(j * 16 + n15) * 72 + kg * 8];
      bf16x8 b1 = *(const bf16x8*)&Ts[(j * 16 + n15) * 72 + 32 + kg * 8];
      f32x4 acc = (f32x4){0.f, 0.f, 0.f, 0.f};
      acc = __builtin_amdgcn_mfma_f32_16x16x32_bf16(a0, b0, acc, 0, 0, 0);
      acc = __builtin_amdgcn_mfma_f32_16x16x32_bf16(a1, b1, acc, 0, 0, 0);
      #pragma unroll
      for (int r = 0; r < 4; ++r)
        Ss[(mt * 16 + kg * 4 + r) * 68 + j * 16 + n15] = acc[r];
    }
  }
  __syncthreads();
  if (wave == 0 && lane < 32) {
    int n = lane;
    long vb = (lh * NS + n) * 65;
    float wtr = g_Vt[vb * 2 + 128], wti = g_Vt[vb * 2 + 129];
    float e0r = g_E0[(lh * NS + n) * 2], e0i = g_E0[(lh * NS + n) * 2 + 1];
    float sr = 0.f, si = 0.f;
    for (int cc = 0; cc < CC; ++cc) {
      float er = Ss[cc * 68 + 2 * n], ei = Ss[cc * 68 + 2 * n + 1];
      Gs[cc * 72 + 2 * n]     = f2bf(e0r * sr - e0i * si);
      Gs[cc * 72 + 2 * n + 1] = f2bf(e0r * si + e0i * sr);
      float nr = er + wtr * sr - wti * si;
      si      = ei + wtr * si + wti * sr;
      sr = nr;
    }
  }
  __syncthreads();
  {
    bf16x8 a0 = *(const bf16x8*)&Zs[c * 72 + kg * 8];
    bf16x8 a1 = *(const bf16x8*)&Zs[c * 72 + 32 + kg * 8];
    bf16x8 a2 = *(const bf16x8*)&Gs[c * 72 + kg * 8];
    bf16x8 a3 = *(const bf16x8*)&Gs[c * 72 + 32 + kg * 8];
    unsigned short* yrow = g_ybh + ((long)(b * HD + h)) * LL;
    #pragma unroll
    for (int jj = 0; jj < 2; ++jj) {
      int j = jb + jj;
      const unsigned short* mrow = &Ms[(j * 16 + n15) * 136];
      bf16x8 b0 = *(const bf16x8*)&mrow[kg * 8];
      bf16x8 b1 = *(const bf16x8*)&mrow[32 + kg * 8];
      bf16x8 b2 = *(const bf16x8*)&mrow[64 + kg * 8];
      bf16x8 b3 = *(const bf16x8*)&mrow[96 + kg * 8];
      f32x4 acc = (f32x4){0.f, 0.f, 0.f, 0.f};
      acc = __builtin_amdgcn_mfma_f32_16x16x32_bf16(a0, b0, acc, 0, 0, 0);
      acc = __builtin_amdgcn_mfma_f32_16x16x32_bf16(a1, b1, acc, 0, 0, 0);
      acc = __builtin_amdgcn_mfma_f32_16x16x32_bf16(a2, b2, acc, 0, 0, 0);
      acc = __builtin_amdgcn_mfma_f32_16x16x32_bf16(a3, b3, acc, 0, 0, 0);
      #pragma unroll
      for (int r = 0; r < 4; ++r)
        yrow[(mt * 16 + kg * 4 + r) * 64 + j * 16 + n15] = f2bf(geluf(acc[r]));
    }
  }
}

// ---------- fused: GEMM(yT * W) + GLU + residual + next-layer LN -> z ----------
// block: 32 rows (l) x 512 v-cols; A staged from ybh [B][H][L] via LDS transpose.
__global__ __launch_bounds__(256, 4) void k_gemmglu(int layer, const float* __restrict__ bias,
                                                    const float* __restrict__ gam,
                                                    const float* __restrict__ bet,
                                                    int writez) {
  __shared__ __attribute__((aligned(16))) unsigned short As[32 * 40];   // 2.5 KB [l][k]
  __shared__ __attribute__((aligned(16))) float UU[8448];               // 33 KB: Bs | Xs
  __shared__ float Rs1[32][4], Rs2[32][4], muS[32], rsS[32];
  unsigned short* Bs = (unsigned short*)UU;                             // [n=512][k=32]
  float* Xs = UU;                                                       // [col=256][rl=32] pitch 33
  const int tid = threadIdx.x, wave = tid >> 6, lane = tid & 63;
  const int n15 = lane & 15, kg = lane >> 4, q2 = kg * 8;
  const int row0 = blockIdx.x * 32;            // global row = b*2048 + l
  const int b = row0 >> 11, l0 = row0 & 2047;
  const unsigned short* Wt = g_Wt + (long)layer * 131072;
  const unsigned short* ybase = g_ybh + (long)b * HD * LL + l0;
  const int hl = tid >> 3, sg = tid & 7;       // A-staging: h-row, l-seg
  f32x4 acc[2][8];
  #pragma unroll
  for (int a = 0; a < 2; ++a)
    #pragma unroll
    for (int b2 = 0; b2 < 8; ++b2) acc[a][b2] = (f32x4){0.f, 0.f, 0.f, 0.f};
  for (int k0 = 0; k0 < 256; k0 += 32) {
    __syncthreads();
    // A: ybh[b][k0+hl][l0+sg*4 ..+4] -> As[l][h] (transpose)
    ushort4 av = *(const ushort4*)(ybase + (long)(k0 + hl) * LL + sg * 4);
    As[(sg * 4 + 0) * 40 + hl] = av.x;
    As[(sg * 4 + 1) * 40 + hl] = av.y;
    As[(sg * 4 + 2) * 40 + hl] = av.z;
    As[(sg * 4 + 3) * 40 + hl] = av.w;
    // B: all 512 n-rows, 32 k
    #pragma unroll
    for (int it = 0; it < 8; ++it) {
      int slot = it * 256 + wave * 64 + lane;  // n = slot>>2, ko = (slot&3)*8
      int n = slot >> 2, ko = (slot & 3) * 8;
      __builtin_amdgcn_global_load_lds(
        (const __attribute__((address_space(1))) unsigned int*)(Wt + (long)n * 256 + k0 + ko),
        (__attribute__((address_space(3))) unsigned int*)(Bs + (it * 256 + wave * 64) * 8),
        16, 0, 0);
    }
    __syncthreads();
    bf16x8 af0 = *(const bf16x8*)&As[(n15) * 40 + q2];
    bf16x8 af1 = *(const bf16x8*)&As[(16 + n15) * 40 + q2];
    #pragma unroll
    for (int j = 0; j < 4; ++j) {
      int nc = wave * 64 + j * 16 + n15;
      bf16x8 ba = *(const bf16x8*)&Bs[nc * 32 + q2];
      acc[0][j] = __builtin_amdgcn_mfma_f32_16x16x32_bf16(af0, ba, acc[0][j], 0, 0, 0);
      acc[1][j] = __builtin_amdgcn_mfma_f32_16x16x32_bf16(af1, ba, acc[1][j], 0, 0, 0);
      bf16x8 bg = *(const bf16x8*)&Bs[(nc + 256) * 32 + q2];
      acc[0][4 + j] = __builtin_amdgcn_mfma_f32_16x16x32_bf16(af0, bg, acc[0][4 + j], 0, 0, 0);
      acc[1][4 + j] = __builtin_amdgcn_mfma_f32_16x16x32_bf16(af1, bg, acc[1][4 + j], 0, 0, 0);
    }
  }
  __syncthreads();                  // Bs dead; Xs may be written now
  // epilogue: GLU + residual (+ stage xn, row sums)
  float s1l[2][4], s2l[2][4];
  #pragma unroll
  for (int mt = 0; mt < 2; ++mt)
    #pragma unroll
    for (int r = 0; r < 4; ++r) { s1l[mt][r] = 0.f; s2l[mt][r] = 0.f; }
  #pragma unroll
  for (int j = 0; j < 4; ++j) {
    int col = wave * 64 + j * 16 + n15;
    float ba = bias[col], bg = bias[col + 256];
    #pragma unroll
    for (int mt = 0; mt < 2; ++mt) {
      #pragma unroll
      for (int r = 0; r < 4; ++r) {
        int rl = mt * 16 + kg * 4 + r;
        long xi = (long)(row0 + rl) * 256 + col;
        float a = acc[mt][j][r] + ba;
        float g = acc[mt][4 + j][r] + bg;
        float xn = g_x[xi] + a * sigf(g);
        g_x[xi] = xn;
        if (writez) {
          Xs[col * 33 + rl] = xn;
          s1l[mt][r] += xn; s2l[mt][r] += xn * xn;
        }
      }
    }
  }
  if (!writez) return;
  // reduce over the 16-lane n15 group
  #pragma unroll
  for (int mt = 0; mt < 2; ++mt)
    #pragma unroll
    for (int r = 0; r < 4; ++r) {
      #pragma unroll
      for (int off = 1; off < 16; off <<= 1) {
        s1l[mt][r] += __shfl_xor(s1l[mt][r], off);
        s2l[mt][r] += __shfl_xor(s2l[mt][r], off);
      }
    }
  if (n15 == 0) {
    #pragma unroll
    for (int mt = 0; mt < 2; ++mt)
      #pragma unroll
      for (int r = 0; r < 4; ++r) {
        Rs1[mt * 16 + kg * 4 + r][wave] = s1l[mt][r];
        Rs2[mt * 16 + kg * 4 + r][wave] = s2l[mt][r];
      }
  }
  __syncthreads();
  if (tid < 32) {
    float s1 = Rs1[tid][0] + Rs1[tid][1] + Rs1[tid][2] + Rs1[tid][3];
    float s2 = Rs2[tid][0] + Rs2[tid][1] + Rs2[tid][2] + Rs2[tid][3];
    float mu = s1 * (1.0f / HD);
    float rs = rsqrtf(s2 * (1.0f / HD) - mu * mu + 1e-5f);
    muS[tid] = mu; rsS[tid] = rs;
  }
  __syncthreads();
  // z write: thread t owns h=t, 32 l's (64B contiguous)
  {
    int hh = tid;
    float gm = gam[hh], bt = bet[hh];
    const float* xrow = &Xs[hh * 33];
    union { unsigned short u[32]; ulonglong2 v4[4]; } pk;
    #pragma unroll
    for (int rl = 0; rl < 32; ++rl)
      pk.u[rl] = f2bf((xrow[rl] - muS[rl]) * rsS[rl] * gm + bt);
    unsigned short* zp = g_zbh + ((long)(b * HD + hh)) * LL + l0;
    #pragma unroll
    for (int q = 0; q < 4; ++q) *(ulonglong2*)(zp + q * 8) = pk.v4[q];
  }
}

// ---------- final LN + partial pool ----------
__global__ __launch_bounds__(256) void k_lnpool(const float* __restrict__ gam,
                                                const float* __restrict__ bet) {
  __shared__ float red[4][256];
  const int bid = blockIdx.x;
  const int b = bid >> 4, s = bid & 15;
  const int tid = threadIdx.x, w = tid >> 6, lane = tid & 63;
  float4 gv = *(const float4*)(gam + lane * 4);
  float4 bv = *(const float4*)(bet + lane * 4);
  float a0 = 0, a1 = 0, a2 = 0, a3 = 0;
  for (int r = 0; r < 32; ++r) {
    int l = s * 128 + w * 32 + r;
    float4 v = *(const float4*)(g_x + ((long)b * LL + l) * HD + lane * 4);
    float s1 = v.x + v.y + v.z + v.w;
    float s2 = v.x * v.x + v.y * v.y + v.z * v.z + v.w * v.w;
    #pragma unroll
    for (int off = 32; off; off >>= 1) { s1 += __shfl_xor(s1, off); s2 += __shfl_xor(s2, off); }
    float mu = s1 * (1.0f / HD);
    float rs = rsqrtf(s2 * (1.0f / HD) - mu * mu + 1e-5f);
    a0 += (v.x - mu) * rs * gv.x + bv.x;
    a1 += (v.y - mu) * rs * gv.y + bv.y;
    a2 += (v.z - mu) * rs * gv.z + bv.z;
    a3 += (v.w - mu) * rs * gv.w + bv.w;
  }
  red[w][lane * 4 + 0] = a0; red[w][lane * 4 + 1] = a1;
  red[w][lane * 4 + 2] = a2; red[w][lane * 4 + 3] = a3;
  __syncthreads();
  g_pp[(long)bid * HD + tid] = red[0][tid] + red[1][tid] + red[2][tid] + red[3][tid];
}

// ---------- classifier ----------
__global__ __launch_bounds__(256) void k_cls(const float* __restrict__ Wc,
                                             const float* __restrict__ bc,
                                             float* __restrict__ out) {
  __shared__ float pl[256];
  const int b = blockIdx.x, tid = threadIdx.x;
  float p = 0.f;
  #pragma unroll
  for (int s = 0; s < 16; ++s) p += g_pp[((long)b * 16 + s) * HD + tid];
  pl[tid] = p * (1.0f / LL);
  __syncthreads();
  if (tid < NCLS) {
    float acc = bc[tid];
    for (int h = 0; h < HD; ++h) acc += pl[h] * Wc[h * NCLS + tid];
    out[b * NCLS + tid] = acc;
  }
}

extern "C" void kernel_launch(void* const* d_in, const int* in_sizes, int n_in,
                              void* d_out, int out_size, void* d_ws, size_t ws_size,
                              hipStream_t stream) {
  (void)in_sizes; (void)n_in; (void)d_ws; (void)ws_size; (void)out_size;
  const float* x_in   = (const float*)d_in[0];
  const float* W_in   = (const float*)d_in[1];
  const float* b_in   = (const float*)d_in[2];
  const float* log_dt = (const float*)d_in[3];
  const float* A_re   = (const float*)d_in[4];
  const float* A_im   = (const float*)d_in[5];
  const float* B_re   = (const float*)d_in[6];
  const float* B_im   = (const float*)d_in[7];
  const float* C_re   = (const float*)d_in[8];
  const float* C_im   = (const float*)d_in[9];
  const float* Dd     = (const float*)d_in[10];
  const float* W_out  = (const float*)d_in[11];
  const float* b_out  = (const float*)d_in[12];
  const float* ln_s   = (const float*)d_in[13];
  const float* ln_b   = (const float*)d_in[14];
  const float* lnf_s  = (const float*)d_in[15];
  const float* lnf_b  = (const float*)d_in[16];
  const float* W_cls  = (const float*)d_in[17];
  const float* b_cl   = (const float*)d_in[18];
  float* out = (float*)d_out;

  k_precomp<<<192, 256, 0, stream>>>(log_dt, A_re, A_im, B_re, B_im, C_re, C_im);
  k_precompK<<<384, 256, 0, stream>>>();
  k_precompM<<<49152, 256, 0, stream>>>(Dd);
  k_precompA2<<<24576, 256, 0, stream>>>();
  k_prepW<<<768, 256, 0, stream>>>(W_out);
  k_prepWin<<<128, 256, 0, stream>>>(W_in);
  k_castin<<<2048, 256, 0, stream>>>(x_in);
  k_gemmin<<<256, 256, 0, stream>>>(b_in);
  k_ln<<<1024, 256, 0, stream>>>(ln_s, ln_b);           // layer-0 prenorm
  for (int i = 0; i < NLAYERS; ++i) {
    int nl = (i + 1 < NLAYERS) ? (i + 1) : 0;           // next layer's LN params (unused if writez=0)
    k_ssm<<<4096, 256, 0, stream>>>(i);
    k_gemmglu<<<1024, 256, 0, stream>>>(i, b_out + i * 2 * HD,
                                        ln_s + nl * HD, ln_b + nl * HD,
                                        (i + 1 < NLAYERS) ? 1 : 0);
  }
  k_lnpool<<<256, 256, 0, stream>>>(lnf_s, lnf_b);
  k_cls<<<16, 256, 0, stream>>>(W_cls, b_cl, out);
}

// Round 8
// 699.517 us; speedup vs baseline: 4.7151x; 1.0155x over previous
//
#include <hip/hip_runtime.h>
#include <math.h>

#define NLAYERS 6
#define HD 256
#define NS 32
#define NCLS 50
#define BB 16
#define LL 2048
#define TT 64
#define CC 32

typedef __attribute__((ext_vector_type(8))) short bf16x8;
typedef __attribute__((ext_vector_type(4))) float f32x4;

// ---- static device workspaces ----
__device__ __attribute__((aligned(16))) float g_x [8388608];   // [B][L][H] residual stream (fp32)
__device__ __attribute__((aligned(16))) float g_Vt[6389760];   // [l][h][n][65][2] : w^t, t=0..64
__device__ __attribute__((aligned(16))) float g_Kt[98304];     // [l][h][64] kernel taps
__device__ __attribute__((aligned(16))) float g_E0[98304];     // [l][h][n][2] : C*dB
__device__ __attribute__((aligned(16))) float g_pp[65536];     // [B][16][H] pool partials
__device__ __attribute__((aligned(16))) unsigned short g_zbh[8388608]; // z bf16 [B][H][L]
__device__ __attribute__((aligned(16))) unsigned short g_Mt [12582912];// [l][h][t=64][k=128] bf16 (TK;TC)^T, D folded
__device__ __attribute__((aligned(16))) unsigned short g_TAt[6291456]; // [l][h][p=64][t=64] bf16 TA^T
__device__ __attribute__((aligned(16))) unsigned short g_ybh[8388608]; // y bf16 [B][H][L]
__device__ __attribute__((aligned(16))) unsigned short g_Wt [786432];  // Wt bf16 [l][n=512][k=256]
__device__ __attribute__((aligned(16))) unsigned short g_xb [4194304]; // x_in bf16 [32768][128]
__device__ __attribute__((aligned(16))) unsigned short g_Wint[32768];  // W_in^T bf16 [n=256][k=128]

__device__ __forceinline__ float sigf(float x) { return 1.0f / (1.0f + __expf(-x)); }
__device__ __forceinline__ float geluf(float x) {
  float t = 0.7978845608028654f * (x + 0.044715f * x * x * x);
  float e = __expf(2.0f * t);
  float th = 1.0f - 2.0f / (e + 1.0f);
  return 0.5f * x * (1.0f + th);
}
__device__ __forceinline__ unsigned short f2bf(float f) {
  unsigned u = __float_as_uint(f);
  unsigned r = (u + 0x7FFFu + ((u >> 16) & 1u)) >> 16;
  return (unsigned short)r;
}
__device__ __forceinline__ float bf2f(unsigned short u) {
  return __uint_as_float(((unsigned)u) << 16);
}

// ---------- precompute: w, E0 = C*dB, power table w^t ----------
__global__ void k_precomp(const float* __restrict__ log_dt,
                          const float* __restrict__ A_re, const float* __restrict__ A_im,
                          const float* __restrict__ B_re, const float* __restrict__ B_im,
                          const float* __restrict__ C_re, const float* __restrict__ C_im) {
  int id = blockIdx.x * 256 + threadIdx.x;
  if (id >= NLAYERS * HD * NS) return;
  int h = (id / NS) % HD;
  int i = id / (NS * HD);
  float dt = expf(log_dt[i * HD + h]);
  float ar = A_re[id], ai = A_im[id];
  float dr = dt * ar, di = dt * ai;
  float er = expf(dr);
  float wr = er * cosf(di), wi = er * sinf(di);
  float inv = 1.0f / (ar * ar + ai * ai);
  float mr = wr - 1.0f, mi = wi;
  float qr = (mr * ar + mi * ai) * inv;
  float qi = (mi * ar - mr * ai) * inv;
  float br = B_re[id], bi = B_im[id];
  float dbr = br * qr - bi * qi, dbi = br * qi + bi * qr;
  float cr = C_re[id], ci = C_im[id];
  g_E0[id * 2 + 0] = cr * dbr - ci * dbi;
  g_E0[id * 2 + 1] = cr * dbi + ci * dbr;
  float pr = 1.0f, pi = 0.0f;
  long base = (long)id * 65;
  for (int t = 0; t <= 64; ++t) {
    g_Vt[(base + t) * 2 + 0] = pr;
    g_Vt[(base + t) * 2 + 1] = pi;
    float nr = pr * wr - pi * wi;
    pi = pr * wi + pi * wr;
    pr = nr;
  }
}

__global__ void k_precompK() {
  int id = blockIdx.x * 256 + threadIdx.x;
  if (id >= NLAYERS * HD * TT) return;
  int t = id % TT;
  int lh = id / TT;
  float acc = 0.f;
  const float* e = g_E0 + (long)lh * NS * 2;
  const float* v = g_Vt + ((long)lh * NS * 65 + t) * 2;
  for (int n = 0; n < NS; ++n)
    acc += e[n * 2] * v[n * 130] - e[n * 2 + 1] * v[n * 130 + 1];
  g_Kt[id] = 2.0f * acc;
}

// Mt[l][h][t][k] bf16: k<64 -> TK[s=k][t] (+D at k==t); k>=64 -> TC[p=k-64][t]
__global__ void k_precompM(const float* __restrict__ Dd) {
  int id = blockIdx.x * 256 + threadIdx.x;     // 12582912
  int k = id & 127;
  int t = (id >> 7) & 63;
  int lh = id >> 13;
  float v;
  if (k < 64) {
    v = (t >= k) ? g_Kt[(long)lh * 64 + (t - k)] : 0.f;
    if (k == t) v += Dd[lh];
  } else {
    int p = k - 64, n = p >> 1;
    const float2 w = ((const float2*)g_Vt)[((long)lh * NS + n) * 65 + (t + 1)];
    v = (p & 1) ? (-2.f * w.y) : (2.f * w.x);
  }
  g_Mt[id] = f2bf(v);
}

// TAt[l][h][p][t] = TA[t][p] bf16
__global__ void k_precompA2() {
  int id = blockIdx.x * 256 + threadIdx.x;     // 6291456
  int t = id & 63;
  int p = (id >> 6) & 63;
  int lh = id >> 12;
  int n = p >> 1;
  const float2 w = ((const float2*)g_Vt)[((long)lh * NS + n) * 65 + (63 - t)];
  g_TAt[id] = f2bf((p & 1) ? w.y : w.x);
}

// ---------- W_out -> Wt bf16 [l][n][k] ----------
__global__ __launch_bounds__(256) void k_prepW(const float* __restrict__ W_out) {
  __shared__ float T[32][33];
  int bid = blockIdx.x;
  int nt = bid & 15, kt = (bid >> 4) & 7, l = bid >> 7;
  int t = threadIdx.x;
  int tr = t >> 3, tc = t & 7;
  const float* src = W_out + (long)l * 131072 + (long)(kt * 32) * 512 + nt * 32;
  float4 v = *(const float4*)(src + (long)tr * 512 + tc * 4);
  T[tr][tc * 4 + 0] = v.x; T[tr][tc * 4 + 1] = v.y;
  T[tr][tc * 4 + 2] = v.z; T[tr][tc * 4 + 3] = v.w;
  __syncthreads();
  ushort4 o;
  o.x = f2bf(T[tc * 4 + 0][tr]); o.y = f2bf(T[tc * 4 + 1][tr]);
  o.z = f2bf(T[tc * 4 + 2][tr]); o.w = f2bf(T[tc * 4 + 3][tr]);
  *(ushort4*)(g_Wt + ((long)l * 512 + nt * 32 + tr) * 256 + kt * 32 + tc * 4) = o;
}

// ---------- W_in [k=128][n=256] -> Wint bf16 [n][k] ----------
__global__ void k_prepWin(const float* __restrict__ W_in) {
  int k = blockIdx.x, n = threadIdx.x;
  g_Wint[n * 128 + k] = f2bf(W_in[k * 256 + n]);
}

// ---------- x_in fp32 -> bf16 ----------
__global__ void k_castin(const float* __restrict__ xin) {
  long base = ((long)blockIdx.x * 256 + threadIdx.x) * 8;
  float4 v0 = *(const float4*)(xin + base);
  float4 v1 = *(const float4*)(xin + base + 4);
  union { unsigned short u[8]; ulonglong2 v; } pk;
  pk.u[0] = f2bf(v0.x); pk.u[1] = f2bf(v0.y); pk.u[2] = f2bf(v0.z); pk.u[3] = f2bf(v0.w);
  pk.u[4] = f2bf(v1.x); pk.u[5] = f2bf(v1.y); pk.u[6] = f2bf(v1.z); pk.u[7] = f2bf(v1.w);
  *(ulonglong2*)(g_xb + base) = pk.v;
}

// ---------- input GEMM (bf16 MFMA): g_x[32768,256] = xb[32768,128]*Wint^T + b ----------
__global__ __launch_bounds__(256) void k_gemmin(const float* __restrict__ bias) {
  __shared__ __attribute__((aligned(16))) unsigned short As[128 * 32];
  __shared__ __attribute__((aligned(16))) unsigned short Bs[256 * 32];
  const int tid = threadIdx.x;
  const int wave = tid >> 6, lane = tid & 63;
  const int m0 = blockIdx.x * 128;
  const int wm = wave & 1, wn = wave >> 1;
  const int n15 = lane & 15, kg = lane >> 4, q2 = kg * 8;
  f32x4 acc[4][8];
  #pragma unroll
  for (int a = 0; a < 4; ++a)
    #pragma unroll
    for (int b2 = 0; b2 < 8; ++b2) acc[a][b2] = (f32x4){0.f, 0.f, 0.f, 0.f};
  for (int k0 = 0; k0 < 128; k0 += 32) {
    __syncthreads();
    #pragma unroll
    for (int it = 0; it < 2; ++it) {
      int slot = it * 256 + wave * 64 + lane;
      int m = slot >> 2, ko = (slot & 3) * 8;
      __builtin_amdgcn_global_load_lds(
        (const __attribute__((address_space(1))) unsigned int*)(g_xb + (long)(m0 + m) * 128 + k0 + ko),
        (__attribute__((address_space(3))) unsigned int*)(As + (it * 256 + wave * 64) * 8),
        16, 0, 0);
    }
    #pragma unroll
    for (int it = 0; it < 4; ++it) {
      int slot = it * 256 + wave * 64 + lane;
      int n = slot >> 2, ko = (slot & 3) * 8;
      __builtin_amdgcn_global_load_lds(
        (const __attribute__((address_space(1))) unsigned int*)(g_Wint + (long)n * 128 + k0 + ko),
        (__attribute__((address_space(3))) unsigned int*)(Bs + (it * 256 + wave * 64) * 8),
        16, 0, 0);
    }
    __syncthreads();
    bf16x8 af[4], bn[8];
    #pragma unroll
    for (int mt = 0; mt < 4; ++mt)
      af[mt] = *(const bf16x8*)&As[(wm * 64 + mt * 16 + n15) * 32 + q2];
    #pragma unroll
    for (int j = 0; j < 8; ++j)
      bn[j] = *(const bf16x8*)&Bs[(wn * 128 + j * 16 + n15) * 32 + q2];
    #pragma unroll
    for (int mt = 0; mt < 4; ++mt)
      #pragma unroll
      for (int j = 0; j < 8; ++j)
        acc[mt][j] = __builtin_amdgcn_mfma_f32_16x16x32_bf16(af[mt], bn[j], acc[mt][j], 0, 0, 0);
  }
  #pragma unroll
  for (int j = 0; j < 8; ++j) {
    int col = wn * 128 + j * 16 + n15;
    float bb = bias[col];
    #pragma unroll
    for (int mt = 0; mt < 4; ++mt)
      #pragma unroll
      for (int r = 0; r < 4; ++r) {
        int row = m0 + wm * 64 + mt * 16 + kg * 4 + r;
        g_x[(long)row * 256 + col] = acc[mt][j][r] + bb;
      }
  }
}

// ---------- LayerNorm over H -> z bf16 [B][H][L]; only for layer 0 ----------
__global__ __launch_bounds__(256) void k_ln(const float* __restrict__ gam,
                                            const float* __restrict__ bet) {
  __shared__ unsigned short S[32 * 264];
  const int bid = blockIdx.x;                  // 1024
  const int b = bid >> 6, l0 = (bid & 63) << 5;
  const int tid = threadIdx.x, w = tid >> 6, lane = tid & 63;
  float4 gv = *(const float4*)(gam + lane * 4);
  float4 bv = *(const float4*)(bet + lane * 4);
  for (int r = 0; r < 8; ++r) {
    int ll = w * 8 + r;
    float4 v = *(const float4*)(g_x + ((long)(b * LL + l0 + ll)) * HD + lane * 4);
    float s1 = v.x + v.y + v.z + v.w;
    float s2 = v.x * v.x + v.y * v.y + v.z * v.z + v.w * v.w;
    #pragma unroll
    for (int off = 32; off; off >>= 1) { s1 += __shfl_xor(s1, off); s2 += __shfl_xor(s2, off); }
    float mu = s1 * (1.0f / HD);
    float rs = rsqrtf(s2 * (1.0f / HD) - mu * mu + 1e-5f);
    ushort4 o;
    o.x = f2bf((v.x - mu) * rs * gv.x + bv.x);
    o.y = f2bf((v.y - mu) * rs * gv.y + bv.y);
    o.z = f2bf((v.z - mu) * rs * gv.z + bv.z);
    o.w = f2bf((v.w - mu) * rs * gv.w + bv.w);
    *(ushort4*)&S[ll * 264 + lane * 4] = o;
  }
  __syncthreads();
  unsigned short* zp = g_zbh + ((long)(b * HD + tid)) * LL + l0;
  #pragma unroll
  for (int seg = 0; seg < 4; ++seg) {
    union { unsigned short u[8]; ulonglong2 v; } pk;
    #pragma unroll
    for (int i = 0; i < 8; ++i) pk.u[i] = S[(seg * 8 + i) * 264 + tid];
    *(ulonglong2*)(zp + seg * 8) = pk.v;
  }
}

// ---------- fused SSM: phaseA (MFMA) + chunk scan + phaseC (MFMA), one block per (b,h) ----------
// blockIdx: h = bid & 255, b = bid >> 8  -> all 16 b-blocks of an h share bid%8 (XCD) for table L2 reuse.
// Ss (fp32 S_end) aliases Ts (TA^T staging) -- Ts dead after phase-A fragment reads.
__global__ __launch_bounds__(256) void k_ssm(int layer) {
  __shared__ __attribute__((aligned(16))) unsigned short Zs[32 * 72];   // z [c][t]
  __shared__ __attribute__((aligned(16))) unsigned short Ts[64 * 72];   // TA^T [p][t] | Ss fp32 [c][p] pitch 68
  __shared__ __attribute__((aligned(16))) unsigned short Ms[64 * 136];  // Mt [t][k]
  __shared__ __attribute__((aligned(16))) unsigned short Gs[32 * 72];   // G [c][p]
  float* Ss = (float*)Ts;
  const int tid = threadIdx.x, wave = tid >> 6, lane = tid & 63;
  const int h = blockIdx.x & 255, b = blockIdx.x >> 8;
  const long lh = (long)layer * HD + h;
  {
    int c = tid >> 3, off = (tid & 7) * 8;
    *(ulonglong2*)&Zs[c * 72 + off] =
        *(const ulonglong2*)(g_zbh + ((long)(b * HD + h)) * LL + c * 64 + off);
  }
  const unsigned short* Tg = g_TAt + lh * 4096;
  #pragma unroll
  for (int i = 0; i < 2; ++i) {
    int seg = tid + i * 256;
    int row = seg >> 3, sc = (seg & 7) * 8;
    *(ulonglong2*)&Ts[row * 72 + sc] = *(const ulonglong2*)(Tg + row * 64 + sc);
  }
  const unsigned short* Mg = g_Mt + lh * 8192;
  #pragma unroll
  for (int i = 0; i < 4; ++i) {
    int seg = tid + i * 256;
    int row = seg >> 4, sc = (seg & 15) * 8;
    *(ulonglong2*)&Ms[row * 136 + sc] = *(const ulonglong2*)(Mg + row * 128 + sc);
  }
  __syncthreads();
  const int n15 = lane & 15, kg = lane >> 4;
  const int mt = wave & 1;
  const int jb = (wave >> 1) * 2;
  const int c = mt * 16 + n15;
  // phase A: read all Ts fragments first (Ss will overwrite Ts)
  {
    bf16x8 a0 = *(const bf16x8*)&Zs[c * 72 + kg * 8];
    bf16x8 a1 = *(const bf16x8*)&Zs[c * 72 + 32 + kg * 8];
    bf16x8 tb0[2], tb1[2];
    #pragma unroll
    for (int jj = 0; jj < 2; ++jj) {
      int j = jb + jj;
      tb0[jj] = *(const bf16x8*)&Ts[(j * 16 + n15) * 72 + kg * 8];
      tb1[jj] = *(const bf16x8*)&Ts[(j * 16 + n15) * 72 + 32 + kg * 8];
    }
    f32x4 accA[2];
    #pragma unroll
    for (int jj = 0; jj < 2; ++jj) {
      accA[jj] = (f32x4){0.f, 0.f, 0.f, 0.f};
      accA[jj] = __builtin_amdgcn_mfma_f32_16x16x32_bf16(a0, tb0[jj], accA[jj], 0, 0, 0);
      accA[jj] = __builtin_amdgcn_mfma_f32_16x16x32_bf16(a1, tb1[jj], accA[jj], 0, 0, 0);
    }
    __syncthreads();                     // all Ts reads done; safe to alias as Ss
    #pragma unroll
    for (int jj = 0; jj < 2; ++jj) {
      int j = jb + jj;
      #pragma unroll
      for (int r = 0; r < 4; ++r)
        Ss[(mt * 16 + kg * 4 + r) * 68 + j * 16 + n15] = accA[jj][r];
    }
  }
  __syncthreads();
  if (wave == 0 && lane < 32) {
    int n = lane;
    long vb = (lh * NS + n) * 65;
    float wtr = g_Vt[vb * 2 + 128], wti = g_Vt[vb * 2 + 129];
    float e0r = g_E0[(lh * NS + n) * 2], e0i = g_E0[(lh * NS + n) * 2 + 1];
    float sr = 0.f, si = 0.f;
    for (int cc = 0; cc < CC; ++cc) {
      float er = Ss[cc * 68 + 2 * n], ei = Ss[cc * 68 + 2 * n + 1];
      Gs[cc * 72 + 2 * n]     = f2bf(e0r * sr - e0i * si);
      Gs[cc * 72 + 2 * n + 1] = f2bf(e0r * si + e0i * sr);
      float nr = er + wtr * sr - wti * si;
      si      = ei + wtr * si + wti * sr;
      sr = nr;
    }
  }
  __syncthreads();
  {
    bf16x8 a0 = *(const bf16x8*)&Zs[c * 72 + kg * 8];
    bf16x8 a1 = *(const bf16x8*)&Zs[c * 72 + 32 + kg * 8];
    bf16x8 a2 = *(const bf16x8*)&Gs[c * 72 + kg * 8];
    bf16x8 a3 = *(const bf16x8*)&Gs[c * 72 + 32 + kg * 8];
    unsigned short* yrow = g_ybh + ((long)(b * HD + h)) * LL;
    #pragma unroll
    for (int jj = 0; jj < 2; ++jj) {
      int j = jb + jj;
      const unsigned short* mrow = &Ms[(j * 16 + n15) * 136];
      bf16x8 b0 = *(const bf16x8*)&mrow[kg * 8];
      bf16x8 b1 = *(const bf16x8*)&mrow[32 + kg * 8];
      bf16x8 b2 = *(const bf16x8*)&mrow[64 + kg * 8];
      bf16x8 b3 = *(const bf16x8*)&mrow[96 + kg * 8];
      f32x4 acc = (f32x4){0.f, 0.f, 0.f, 0.f};
      acc = __builtin_amdgcn_mfma_f32_16x16x32_bf16(a0, b0, acc, 0, 0, 0);
      acc = __builtin_amdgcn_mfma_f32_16x16x32_bf16(a1, b1, acc, 0, 0, 0);
      acc = __builtin_amdgcn_mfma_f32_16x16x32_bf16(a2, b2, acc, 0, 0, 0);
      acc = __builtin_amdgcn_mfma_f32_16x16x32_bf16(a3, b3, acc, 0, 0, 0);
      #pragma unroll
      for (int r = 0; r < 4; ++r)
        yrow[(mt * 16 + kg * 4 + r) * 64 + j * 16 + n15] = f2bf(geluf(acc[r]));
    }
  }
}

// ---------- fused: GEMM(yT * W) + GLU + residual + next-layer LN -> z ----------
// 32 l-rows x 512 cols per block; B-frags direct from L2-hot Wt; As double-buffered.
// XCD swizzle: adjacent l-tiles share bid%8 so ybh/z half-lines merge in L2.
__global__ __launch_bounds__(256, 4) void k_gemmglu(int layer, const float* __restrict__ bias,
                                                    const float* __restrict__ gam,
                                                    const float* __restrict__ bet,
                                                    int writez) {
  __shared__ __attribute__((aligned(16))) unsigned short As[2][32 * 40]; // 5 KB dbuf [l][k]
  __shared__ __attribute__((aligned(16))) unsigned short Xs[256 * 34];   // 17 KB bf16 xn [col][rl]
  __shared__ float Rs1[32][4], Rs2[32][4], muS[32], rsS[32];
  const int tid = threadIdx.x, wave = tid >> 6, lane = tid & 63;
  const int n15 = lane & 15, kg = lane >> 4, q2 = kg * 8;
  const int ltile = ((blockIdx.x & 7) << 7) | (blockIdx.x >> 3);
  const int row0 = ltile * 32;
  const int b = row0 >> 11, l0 = row0 & 2047;
  const unsigned short* Wt = g_Wt + (long)layer * 131072;
  const unsigned short* ybase = g_ybh + (long)b * HD * LL + l0;
  const int hl = tid >> 3, sg = tid & 7;       // A-staging: h-row, l-seg
  f32x4 acc[2][8];
  #pragma unroll
  for (int a = 0; a < 2; ++a)
    #pragma unroll
    for (int b2 = 0; b2 < 8; ++b2) acc[a][b2] = (f32x4){0.f, 0.f, 0.f, 0.f};
  // prologue: stage A(k0=0)
  {
    ushort4 av = *(const ushort4*)(ybase + (long)hl * LL + sg * 4);
    As[0][(sg * 4 + 0) * 40 + hl] = av.x;
    As[0][(sg * 4 + 1) * 40 + hl] = av.y;
    As[0][(sg * 4 + 2) * 40 + hl] = av.z;
    As[0][(sg * 4 + 3) * 40 + hl] = av.w;
  }
  __syncthreads();
  for (int k0 = 0; k0 < 256; k0 += 32) {
    const int cur = (k0 >> 5) & 1;
    const bool more = (k0 + 32) < 256;
    ushort4 avn;
    if (more) avn = *(const ushort4*)(ybase + (long)(k0 + 32 + hl) * LL + sg * 4);
    bf16x8 af0 = *(const bf16x8*)&As[cur][n15 * 40 + q2];
    bf16x8 af1 = *(const bf16x8*)&As[cur][(16 + n15) * 40 + q2];
    #pragma unroll
    for (int j = 0; j < 4; ++j) {
      int nc = wave * 64 + j * 16 + n15;
      bf16x8 ba = *(const bf16x8*)(Wt + (long)nc * 256 + k0 + q2);
      bf16x8 bg = *(const bf16x8*)(Wt + (long)(nc + 256) * 256 + k0 + q2);
      acc[0][j]     = __builtin_amdgcn_mfma_f32_16x16x32_bf16(af0, ba, acc[0][j], 0, 0, 0);
      acc[1][j]     = __builtin_amdgcn_mfma_f32_16x16x32_bf16(af1, ba, acc[1][j], 0, 0, 0);
      acc[0][4 + j] = __builtin_amdgcn_mfma_f32_16x16x32_bf16(af0, bg, acc[0][4 + j], 0, 0, 0);
      acc[1][4 + j] = __builtin_amdgcn_mfma_f32_16x16x32_bf16(af1, bg, acc[1][4 + j], 0, 0, 0);
    }
    if (more) {
      const int nxt = cur ^ 1;
      As[nxt][(sg * 4 + 0) * 40 + hl] = avn.x;
      As[nxt][(sg * 4 + 1) * 40 + hl] = avn.y;
      As[nxt][(sg * 4 + 2) * 40 + hl] = avn.z;
      As[nxt][(sg * 4 + 3) * 40 + hl] = avn.w;
    }
    __syncthreads();
  }
  // epilogue: GLU + residual (+ stage xn bf16, exact fp32 row sums)
  float s1l[2][4], s2l[2][4];
  #pragma unroll
  for (int mt = 0; mt < 2; ++mt)
    #pragma unroll
    for (int r = 0; r < 4; ++r) { s1l[mt][r] = 0.f; s2l[mt][r] = 0.f; }
  #pragma unroll
  for (int j = 0; j < 4; ++j) {
    int col = wave * 64 + j * 16 + n15;
    float ba = bias[col], bg = bias[col + 256];
    #pragma unroll
    for (int mt = 0; mt < 2; ++mt) {
      #pragma unroll
      for (int r = 0; r < 4; ++r) {
        int rl = mt * 16 + kg * 4 + r;
        long xi = (long)(row0 + rl) * 256 + col;
        float a = acc[mt][j][r] + ba;
        float g = acc[mt][4 + j][r] + bg;
        float xn = g_x[xi] + a * sigf(g);
        g_x[xi] = xn;
        if (writez) {
          Xs[col * 34 + rl] = f2bf(xn);
          s1l[mt][r] += xn; s2l[mt][r] += xn * xn;
        }
      }
    }
  }
  if (!writez) return;
  #pragma unroll
  for (int mt = 0; mt < 2; ++mt)
    #pragma unroll
    for (int r = 0; r < 4; ++r) {
      #pragma unroll
      for (int off = 1; off < 16; off <<= 1) {
        s1l[mt][r] += __shfl_xor(s1l[mt][r], off);
        s2l[mt][r] += __shfl_xor(s2l[mt][r], off);
      }
    }
  if (n15 == 0) {
    #pragma unroll
    for (int mt = 0; mt < 2; ++mt)
      #pragma unroll
      for (int r = 0; r < 4; ++r) {
        Rs1[mt * 16 + kg * 4 + r][wave] = s1l[mt][r];
        Rs2[mt * 16 + kg * 4 + r][wave] = s2l[mt][r];
      }
  }
  __syncthreads();
  if (tid < 32) {
    float s1 = Rs1[tid][0] + Rs1[tid][1] + Rs1[tid][2] + Rs1[tid][3];
    float s2 = Rs2[tid][0] + Rs2[tid][1] + Rs2[tid][2] + Rs2[tid][3];
    float mu = s1 * (1.0f / HD);
    float rs = rsqrtf(s2 * (1.0f / HD) - mu * mu + 1e-5f);
    muS[tid] = mu; rsS[tid] = rs;
  }
  __syncthreads();
  {
    int hh = tid;
    float gm = gam[hh], bt = bet[hh];
    const unsigned short* xrow = &Xs[hh * 34];
    union { unsigned short u[32]; ulonglong2 v4[4]; } pk;
    #pragma unroll
    for (int rl = 0; rl < 32; ++rl)
      pk.u[rl] = f2bf((bf2f(xrow[rl]) - muS[rl]) * rsS[rl] * gm + bt);
    unsigned short* zp = g_zbh + ((long)(b * HD + hh)) * LL + l0;
    #pragma unroll
    for (int q = 0; q < 4; ++q) *(ulonglong2*)(zp + q * 8) = pk.v4[q];
  }
}

// ---------- final LN + partial pool ----------
__global__ __launch_bounds__(256) void k_lnpool(const float* __restrict__ gam,
                                                const float* __restrict__ bet) {
  __shared__ float red[4][256];
  const int bid = blockIdx.x;
  const int b = bid >> 4, s = bid & 15;
  const int tid = threadIdx.x, w = tid >> 6, lane = tid & 63;
  float4 gv = *(const float4*)(gam + lane * 4);
  float4 bv = *(const float4*)(bet + lane * 4);
  float a0 = 0, a1 = 0, a2 = 0, a3 = 0;
  for (int r = 0; r < 32; ++r) {
    int l = s * 128 + w * 32 + r;
    float4 v = *(const float4*)(g_x + ((long)b * LL + l) * HD + lane * 4);
    float s1 = v.x + v.y + v.z + v.w;
    float s2 = v.x * v.x + v.y * v.y + v.z * v.z + v.w * v.w;
    #pragma unroll
    for (int off = 32; off; off >>= 1) { s1 += __shfl_xor(s1, off); s2 += __shfl_xor(s2, off); }
    float mu = s1 * (1.0f / HD);
    float rs = rsqrtf(s2 * (1.0f / HD) - mu * mu + 1e-5f);
    a0 += (v.x - mu) * rs * gv.x + bv.x;
    a1 += (v.y - mu) * rs * gv.y + bv.y;
    a2 += (v.z - mu) * rs * gv.z + bv.z;
    a3 += (v.w - mu) * rs * gv.w + bv.w;
  }
  red[w][lane * 4 + 0] = a0; red[w][lane * 4 + 1] = a1;
  red[w][lane * 4 + 2] = a2; red[w][lane * 4 + 3] = a3;
  __syncthreads();
  g_pp[(long)bid * HD + tid] = red[0][tid] + red[1][tid] + red[2][tid] + red[3][tid];
}

// ---------- classifier ----------
__global__ __launch_bounds__(256) void k_cls(const float* __restrict__ Wc,
                                             const float* __restrict__ bc,
                                             float* __restrict__ out) {
  __shared__ float pl[256];
  const int b = blockIdx.x, tid = threadIdx.x;
  float p = 0.f;
  #pragma unroll
  for (int s = 0; s < 16; ++s) p += g_pp[((long)b * 16 + s) * HD + tid];
  pl[tid] = p * (1.0f / LL);
  __syncthreads();
  if (tid < NCLS) {
    float acc = bc[tid];
    for (int h = 0; h < HD; ++h) acc += pl[h] * Wc[h * NCLS + tid];
    out[b * NCLS + tid] = acc;
  }
}

extern "C" void kernel_launch(void* const* d_in, const int* in_sizes, int n_in,
                              void* d_out, int out_size, void* d_ws, size_t ws_size,
                              hipStream_t stream) {
  (void)in_sizes; (void)n_in; (void)d_ws; (void)ws_size; (void)out_size;
  const float* x_in   = (const float*)d_in[0];
  const float* W_in   = (const float*)d_in[1];
  const float* b_in   = (const float*)d_in[2];
  const float* log_dt = (const float*)d_in[3];
  const float* A_re   = (const float*)d_in[4];
  const float* A_im   = (const float*)d_in[5];
  const float* B_re   = (const float*)d_in[6];
  const float* B_im   = (const float*)d_in[7];
  const float* C_re   = (const float*)d_in[8];
  const float* C_im   = (const float*)d_in[9];
  const float* Dd     = (const float*)d_in[10];
  const float* W_out  = (const float*)d_in[11];
  const float* b_out  = (const float*)d_in[12];
  const float* ln_s   = (const float*)d_in[13];
  const float* ln_b   = (const float*)d_in[14];
  const float* lnf_s  = (const float*)d_in[15];
  const float* lnf_b  = (const float*)d_in[16];
  const float* W_cls  = (const float*)d_in[17];
  const float* b_cl   = (const float*)d_in[18];
  float* out = (float*)d_out;

  k_precomp<<<192, 256, 0, stream>>>(log_dt, A_re, A_im, B_re, B_im, C_re, C_im);
  k_precompK<<<384, 256, 0, stream>>>();
  k_precompM<<<49152, 256, 0, stream>>>(Dd);
  k_precompA2<<<24576, 256, 0, stream>>>();
  k_prepW<<<768, 256, 0, stream>>>(W_out);
  k_prepWin<<<128, 256, 0, stream>>>(W_in);
  k_castin<<<2048, 256, 0, stream>>>(x_in);
  k_gemmin<<<256, 256, 0, stream>>>(b_in);
  k_ln<<<1024, 256, 0, stream>>>(ln_s, ln_b);           // layer-0 prenorm
  for (int i = 0; i < NLAYERS; ++i) {
    int nl = (i + 1 < NLAYERS) ? (i + 1) : 0;
    k_ssm<<<4096, 256, 0, stream>>>(i);
    k_gemmglu<<<1024, 256, 0, stream>>>(i, b_out + i * 2 * HD,
                                        ln_s + nl * HD, ln_b + nl * HD,
                                        (i + 1 < NLAYERS) ? 1 : 0);
  }
  k_lnpool<<<256, 256, 0, stream>>>(lnf_s, lnf_b);
  k_cls<<<16, 256, 0, stream>>>(W_cls, b_cl, out);
}